// Round 7
// baseline (617.058 us; speedup 1.0000x reference)
//
#include <hip/hip_runtime.h>
#include <hip/hip_bf16.h>
#include <math.h>

// SpKBGAT: N=50000, D=200, R=500, NHID=100, H=2, OD=200, E=150000, ENH=30000.
// R15: R14 kept (final_mfma deleted; entW fused; gather_l2 does +entW+l2norm)
// but R14 broke the projection kernels' software pipeline (stg loads moved
// inside the chunk loop -> serial 900cy/chunk; l2_proj 50->137us). Restore the
// R5-measured prefetch pipeline; l1_both computes entW as a SECOND PHASE (13
// tiles) over the same 32KB LDS buffer, reusing the hoisted A-row registers.
#define DD   200
#define NHID 100
#define OD   200
#define KP   224   // padded K (7 chunks of 32)
#define PBS  448   // row stride (bf16) for pB / x1A2 / entW: 896 B
                   // [0..199]: pB [k][h0,h1] pairs (l1) / x1A2 feats (l2)
                   // bytes 400..407: s2 floats;  shorts [224..423]: entW bf16
#define LDSW 40    // LDS row stride in shorts (80 B)

typedef __attribute__((ext_vector_type(8))) short short8;
typedef __attribute__((ext_vector_type(4))) float f32x4;

static inline int cdiv(int a, int b) { return (a + b - 1) / b; }

__device__ inline float toF(float x) { return x; }
__device__ inline float toF(__hip_bfloat16 x) { return __bfloat162float(x); }
__device__ inline void storeC(float v, float* p) { *p = v; }
__device__ inline void storeC(float v, __hip_bfloat16* p) { *p = __float2bfloat16(v); }
__device__ inline short bf16s(float f) {
    __hip_bfloat16 h = __float2bfloat16(f);
    short s; __builtin_memcpy(&s, &h, 2); return s;
}
__device__ inline float bfLo(unsigned u) { return __uint_as_float(u << 16); }
__device__ inline float bfHi(unsigned u) { return __uint_as_float(u & 0xFFFF0000u); }
__device__ inline float readlaneF(float v, int l) {
    return __uint_as_float((unsigned)__builtin_amdgcn_readlane((int)__float_as_uint(v), l));
}

// -------- per-row inverse L2 norm (f32), wave per row --------
__global__ __launch_bounds__(256)
void rownorm_inv_k(const float* __restrict__ in, float* __restrict__ sc, int M, int Dd)
{
    int wave = (blockIdx.x * blockDim.x + threadIdx.x) >> 6;
    int lane = threadIdx.x & 63;
    if (wave >= M) return;
    float ss = 0.f;
    for (int k = lane; k < Dd; k += 64) {
        float x = in[(size_t)wave * Dd + k];
        ss += x * x;
    }
    for (int o = 32; o > 0; o >>= 1) ss += __shfl_down(ss, o);
    if (lane == 0) sc[wave] = 1.f / fmaxf(sqrtf(ss), 1e-12f);
}

// -------- B-panel prep: bf16 [col][KP], zero-padded --------
__global__ void prep_bt_l1(const float* __restrict__ ah, __hip_bfloat16* __restrict__ Bt)
{
    int c = blockIdx.x, k = threadIdx.x;
    if (k >= KP) return;
    int seg = c / 100, idx = c - seg * 100;
    int h = seg & 1, off = (seg >> 1) * 200;
    float v = (k < 200) ? ah[(size_t)(h * 100 + idx) * 600 + off + k] : 0.f;
    Bt[(size_t)c * KP + k] = __float2bfloat16(v);
}
__global__ void prep_bt_l2(const float* __restrict__ ao, __hip_bfloat16* __restrict__ Bt)
{
    int c = blockIdx.x, k = threadIdx.x;
    if (k >= KP) return;
    int row = (c < 200) ? c : c - 200;
    int off = (c < 200) ? 0 : 200;
    float v = (k < 200) ? ao[(size_t)row * 600 + off + k] : 0.f;
    Bt[(size_t)c * KP + k] = __float2bfloat16(v);
}
__global__ void prep_bt_fin(const float* __restrict__ W, __hip_bfloat16* __restrict__ Bt)
{
    int c = blockIdx.x, k = threadIdx.x;
    if (k >= KP) return;
    float v = (c < 200 && k < 200) ? W[(size_t)k * 200 + c] : 0.f;
    Bt[(size_t)c * KP + k] = __float2bfloat16(v);
}

// -------- layer-1 fused, two-phase: 25 l1 tiles then 13 entW tiles --------
__global__ __launch_bounds__(256)
void l1_both_k(const float* __restrict__ ent, const float* __restrict__ nscale,
               const __hip_bfloat16* __restrict__ Bt,  // [608][KP] (l1 400 + W_ent 208)
               const float* __restrict__ a2h,          // [2][100]
               __hip_bfloat16* __restrict__ x1,        // [N][KP] (cols 0-199)
               __hip_bfloat16* __restrict__ pB,        // [N][PBS]: pB + s2 + entW
               float* __restrict__ s1,                 // [2][N]
               int M)
{
    __shared__ __align__(16) __hip_bfloat16 Bs[400 * LDSW];  // 32 KB
    int tid = threadIdx.x, wave = tid >> 6, lane = tid & 63;
    int quad = lane >> 4, l16 = lane & 15;
    int m0 = blockIdx.x * 64;
    int arow = m0 + wave * 16 + l16;
    bool rok = arow < M;
    float nsc = rok ? nscale[arow] : 0.f;
    const float* arp = ent + (size_t)arow * DD;

    // hoist the full A row-slice (used by BOTH phases)
    short8 abuf[7];
#pragma unroll
    for (int ch = 0; ch < 7; ch++) {
        int kb = ch * 32 + quad * 8;
        float av[8];
        if (rok && kb + 8 <= DD) {
            const float4* p = (const float4*)(arp + kb);
            float4 u0 = p[0], u1 = p[1];
            av[0] = u0.x; av[1] = u0.y; av[2] = u0.z; av[3] = u0.w;
            av[4] = u1.x; av[5] = u1.y; av[6] = u1.z; av[7] = u1.w;
        } else {
#pragma unroll
            for (int j = 0; j < 8; j++) av[j] = (rok && kb + j < DD) ? arp[kb + j] : 0.f;
        }
        short8 a;
#pragma unroll
        for (int j = 0; j < 8; j++) a[j] = bf16s(av[j] * nsc);
        abuf[ch] = a;
    }

    // ---- phase 1: 25 tiles over Bt rows [0,400) -- R5-measured pipeline ----
    f32x4 acc[25];
#pragma unroll
    for (int t = 0; t < 25; t++) acc[t] = (f32x4){0.f, 0.f, 0.f, 0.f};

    short8 stg[7];
#pragma unroll
    for (int i = 0; i < 7; i++) {
        int idx = tid + i * 256;
        if (idx < 1600) {
            int r = idx >> 2, c8 = idx & 3;
            stg[i] = *(const short8*)(Bt + (size_t)r * KP + c8 * 8);
        }
    }
    for (int ch = 0; ch < 7; ch++) {
#pragma unroll
        for (int i = 0; i < 7; i++) {
            int idx = tid + i * 256;
            if (idx < 1600) {
                int r = idx >> 2, c8 = idx & 3;
                *(short8*)(Bs + r * LDSW + c8 * 8) = stg[i];
            }
        }
        __syncthreads();
        if (ch < 6) {
            int kb2 = (ch + 1) * 32;
#pragma unroll
            for (int i = 0; i < 7; i++) {
                int idx = tid + i * 256;
                if (idx < 1600) {
                    int r = idx >> 2, c8 = idx & 3;
                    stg[i] = *(const short8*)(Bt + (size_t)r * KP + kb2 + c8 * 8);
                }
            }
        }
        const __hip_bfloat16* bp = Bs + (size_t)l16 * LDSW + quad * 8;
        short8 a = abuf[ch];
#pragma unroll
        for (int t = 0; t < 25; t++) {
            short8 b = *(const short8*)(bp + (size_t)t * 16 * LDSW);
            acc[t] = __builtin_amdgcn_mfma_f32_16x16x32_bf16(a, b, acc[t], 0, 0, 0);
        }
        __syncthreads();
    }

    // prefetch phase-2 chunk 0 NOW; latency hides under epilogue-1 stores
    short8 stg2[4];
#pragma unroll
    for (int i = 0; i < 4; i++) {
        int idx = tid + i * 256;
        if (idx < 832) {
            int r = idx >> 2, c8 = idx & 3;
            stg2[i] = *(const short8*)(Bt + (size_t)(400 + r) * KP + c8 * 8);
        }
    }

    // ---- epilogue 1: x1, pB feats, s1/s2 ----
    int orow = m0 + wave * 16 + quad * 4;
    float d0[4] = {0,0,0,0}, d1[4] = {0,0,0,0}, d2[4] = {0,0,0,0}, d3[4] = {0,0,0,0};
#pragma unroll
    for (int t = 0; t < 25; t++) {
        int c = t * 16 + l16;
        int seg = c / 100, idx = c - seg * 100;
        float w = a2h[(seg & 1) * 100 + idx];
#pragma unroll
        for (int i = 0; i < 4; i++) {
            float v = acc[t][i];
            float vw = v * w;
            if (seg == 0) d0[i] += vw;
            else if (seg == 1) d1[i] += vw;
            else if (seg == 2) d2[i] += vw;
            else d3[i] += vw;
            int gm = orow + i;
            if (gm < M) {
                if (seg < 2) x1[(size_t)gm * KP + c] = __float2bfloat16(v);
                else pB[(size_t)gm * PBS + idx * 2 + (seg - 2)] = __float2bfloat16(v);
            }
        }
    }
#pragma unroll
    for (int msk = 1; msk < 16; msk <<= 1)
#pragma unroll
        for (int i = 0; i < 4; i++) {
            d0[i] += __shfl_xor(d0[i], msk);
            d1[i] += __shfl_xor(d1[i], msk);
            d2[i] += __shfl_xor(d2[i], msk);
            d3[i] += __shfl_xor(d3[i], msk);
        }
    if (l16 == 0)
#pragma unroll
        for (int i = 0; i < 4; i++) {
            int gm = orow + i;
            if (gm < M) {
                s1[gm] = d0[i]; s1[M + gm] = d1[i];
                float2 sv; sv.x = d2[i]; sv.y = d3[i];
                *(float2*)((char*)pB + (size_t)gm * (PBS * 2) + 400) = sv;
            }
        }

    // ---- phase 2: 13 entW tiles over Bt rows [400,608) ----
    f32x4 acc2[13];
#pragma unroll
    for (int t = 0; t < 13; t++) acc2[t] = (f32x4){0.f, 0.f, 0.f, 0.f};

    for (int ch = 0; ch < 7; ch++) {
#pragma unroll
        for (int i = 0; i < 4; i++) {
            int idx = tid + i * 256;
            if (idx < 832) {
                int r = idx >> 2, c8 = idx & 3;
                *(short8*)(Bs + r * LDSW + c8 * 8) = stg2[i];
            }
        }
        __syncthreads();
        if (ch < 6) {
            int kb2 = (ch + 1) * 32;
#pragma unroll
            for (int i = 0; i < 4; i++) {
                int idx = tid + i * 256;
                if (idx < 832) {
                    int r = idx >> 2, c8 = idx & 3;
                    stg2[i] = *(const short8*)(Bt + (size_t)(400 + r) * KP + kb2 + c8 * 8);
                }
            }
        }
        const __hip_bfloat16* bp = Bs + (size_t)l16 * LDSW + quad * 8;
        short8 a = abuf[ch];
#pragma unroll
        for (int t = 0; t < 13; t++) {
            short8 b = *(const short8*)(bp + (size_t)t * 16 * LDSW);
            acc2[t] = __builtin_amdgcn_mfma_f32_16x16x32_bf16(a, b, acc2[t], 0, 0, 0);
        }
        __syncthreads();
    }
    // entW epilogue: bf16 into row pad shorts [224..423]
#pragma unroll
    for (int t = 0; t < 13; t++) {
        int c2 = t * 16 + l16;
#pragma unroll
        for (int i = 0; i < 4; i++) {
            int gm = orow + i;
            if (c2 < OD && gm < M)
                pB[(size_t)gm * PBS + 224 + c2] = __float2bfloat16(acc2[t][i]);
        }
    }
}

// -------- layer-2 fused: 25 tiles = x1A1 (f32 -> out_ent) | x1A2 (bf16) ----
__global__ __launch_bounds__(256)
void l2_proj_k(const __hip_bfloat16* __restrict__ x1,  // [N][KP]
               const __hip_bfloat16* __restrict__ Bt,  // [400][KP]
               const float* __restrict__ a2o,          // [200]
               float* __restrict__ x1A1,               // [N][200] (out_ent)
               __hip_bfloat16* __restrict__ x1A2,      // [N][PBS], s2 in pad
               float* __restrict__ s1, int M)
{
    __shared__ __align__(16) __hip_bfloat16 Bs[400 * LDSW];  // 32 KB
    int tid = threadIdx.x, wave = tid >> 6, lane = tid & 63;
    int quad = lane >> 4, l16 = lane & 15;
    int m0 = blockIdx.x * 64;
    int arow = m0 + wave * 16 + l16;
    bool rok = arow < M;
    const __hip_bfloat16* arp = x1 + (size_t)arow * KP;

    f32x4 acc[25];
#pragma unroll
    for (int t = 0; t < 25; t++) acc[t] = (f32x4){0.f, 0.f, 0.f, 0.f};

    short8 stg[7];
#pragma unroll
    for (int i = 0; i < 7; i++) {
        int idx = tid + i * 256;
        if (idx < 1600) {
            int r = idx >> 2, c8 = idx & 3;
            stg[i] = *(const short8*)(Bt + (size_t)r * KP + c8 * 8);
        }
    }

    for (int ch = 0; ch < 7; ch++) {
#pragma unroll
        for (int i = 0; i < 7; i++) {
            int idx = tid + i * 256;
            if (idx < 1600) {
                int r = idx >> 2, c8 = idx & 3;
                *(short8*)(Bs + r * LDSW + c8 * 8) = stg[i];
            }
        }
        __syncthreads();
        if (ch < 6) {
            int kb2 = (ch + 1) * 32;
#pragma unroll
            for (int i = 0; i < 7; i++) {
                int idx = tid + i * 256;
                if (idx < 1600) {
                    int r = idx >> 2, c8 = idx & 3;
                    stg[i] = *(const short8*)(Bt + (size_t)r * KP + kb2 + c8 * 8);
                }
            }
        }
        int kb = ch * 32 + quad * 8;
        short8 a = (short8){0,0,0,0,0,0,0,0};
        if (rok) a = *(const short8*)(arp + kb);
        const __hip_bfloat16* bp = Bs + (size_t)l16 * LDSW + quad * 8;
#pragma unroll
        for (int t = 0; t < 25; t++) {
            short8 b = *(const short8*)(bp + (size_t)t * 16 * LDSW);
            acc[t] = __builtin_amdgcn_mfma_f32_16x16x32_bf16(a, b, acc[t], 0, 0, 0);
        }
        __syncthreads();
    }

    int orow = m0 + wave * 16 + quad * 4;
    float dA[4] = {0,0,0,0}, dB[4] = {0,0,0,0};
#pragma unroll
    for (int t = 0; t < 25; t++) {
        int c = t * 16 + l16;
        bool first = c < 200;
        int cc = first ? c : c - 200;
        float w = a2o[cc];
#pragma unroll
        for (int i = 0; i < 4; i++) {
            float v = acc[t][i];
            int gm = orow + i;
            if (first) {
                dA[i] += v * w;
                if (gm < M) x1A1[(size_t)gm * OD + c] = v;
            } else {
                dB[i] += v * w;
                if (gm < M) x1A2[(size_t)gm * PBS + cc] = __float2bfloat16(v);
            }
        }
    }
#pragma unroll
    for (int msk = 1; msk < 16; msk <<= 1)
#pragma unroll
        for (int i = 0; i < 4; i++) {
            dA[i] += __shfl_xor(dA[i], msk);
            dB[i] += __shfl_xor(dB[i], msk);
        }
    if (l16 == 0)
#pragma unroll
        for (int i = 0; i < 4; i++) {
            int gm = orow + i;
            if (gm < M) {
                s1[gm] = dA[i];
                *(float*)((char*)x1A2 + (size_t)gm * (PBS * 2) + 400) = dB[i];
            }
        }
}

// -------- generic MFMA GEMM (small R-sized matmuls); cs/co = C col-stride --
#define KPAD 48
template<bool BTr, typename AT, typename CT>
__global__ __launch_bounds__(256)
void gemm_mfma_k(const AT* __restrict__ A, int lda, const float* __restrict__ ascale,
                 const float* __restrict__ B, int ldb, int colOff,
                 CT* __restrict__ C, int ldc, int cs, int co,
                 int M, int Nc, int K)
{
    __shared__ __align__(16) __hip_bfloat16 As[64][KPAD];
    __shared__ __align__(16) __hip_bfloat16 Bs[64][KPAD];
    int tid  = threadIdx.x;
    int wave = tid >> 6, lane = tid & 63;
    int quad = lane >> 4, l16 = lane & 15;
    int n0 = blockIdx.x * 64, m0 = blockIdx.y * 64;
    f32x4 acc[4];
#pragma unroll
    for (int t = 0; t < 4; t++) acc[t] = (f32x4){0.f, 0.f, 0.f, 0.f};

    for (int k0 = 0; k0 < K; k0 += 32) {
        {
            int m = tid >> 2, kc = (tid & 3) * 8;
            int gm = m0 + m;
            float scale = (ascale && gm < M) ? ascale[gm] : 1.f;
#pragma unroll
            for (int j = 0; j < 8; j++) {
                int gk = k0 + kc + j;
                float v = 0.f;
                if (gm < M && gk < K) v = toF(A[(size_t)gm * lda + gk]) * scale;
                As[m][kc + j] = __float2bfloat16(v);
            }
        }
        if (BTr) {
            int n = tid >> 2, kc = (tid & 3) * 8;
            int gn = n0 + n;
#pragma unroll
            for (int j = 0; j < 8; j++) {
                int gk = k0 + kc + j;
                float v = 0.f;
                if (gn < Nc && gk < K) v = B[(size_t)gn * ldb + colOff + gk];
                Bs[n][kc + j] = __float2bfloat16(v);
            }
        } else {
            int n = tid & 63, kq = tid >> 6;
            int gn = n0 + n;
#pragma unroll
            for (int j = 0; j < 8; j++) {
                int gk = k0 + kq * 8 + j;
                float v = 0.f;
                if (gn < Nc && gk < K) v = B[(size_t)gk * ldb + gn];
                Bs[n][kq * 8 + j] = __float2bfloat16(v);
            }
        }
        __syncthreads();
        short8 a = *(const short8*)&As[wave * 16 + l16][quad * 8];
#pragma unroll
        for (int t = 0; t < 4; t++) {
            short8 b = *(const short8*)&Bs[t * 16 + l16][quad * 8];
            acc[t] = __builtin_amdgcn_mfma_f32_16x16x32_bf16(a, b, acc[t], 0, 0, 0);
        }
        __syncthreads();
    }
#pragma unroll
    for (int t = 0; t < 4; t++) {
        int gn = n0 + t * 16 + l16;
        if (gn >= Nc) continue;
#pragma unroll
        for (int i = 0; i < 4; i++) {
            int gm = m0 + wave * 16 + quad * 4 + i;
            if (gm < M) storeC(acc[t][i], &C[(size_t)gm * ldc + (size_t)gn * cs + co]);
        }
    }
}

// -------- row-dot (srel); ks = k-stride in mat, os/oo = output stride ------
template<typename T>
__global__ __launch_bounds__(256)
void rowdot_k(const T* __restrict__ mat, int ld, int coff, int ks,
              const float* __restrict__ vec,
              float* __restrict__ outp, int os, int oo, int M, int Dd)
{
    int wave = (blockIdx.x * blockDim.x + threadIdx.x) >> 6;
    int lane = threadIdx.x & 63;
    if (wave >= M) return;
    float s = 0.f;
    for (int k = lane; k < Dd; k += 64)
        s += toF(mat[(size_t)wave * ld + coff + (size_t)k * ks]) * vec[k];
    for (int o = 32; o > 0; o >>= 1) s += __shfl_down(s, o);
    if (lane == 0) outp[wave * os + oo] = s;
}

// -------- CSR build --------
__device__ inline void decode_edge(const int* __restrict__ el, int E,
                                   const int* __restrict__ etype,
                                   const int* __restrict__ tin, int e,
                                   int& dst, int& src, int& r1, int& r2)
{
    if (e < E) { dst = el[e]; src = el[E + e]; r1 = etype[e]; r2 = -1; }
    else {
        int j = e - E;
        dst = tin[j * 4 + 3]; src = tin[j * 4 + 0];
        r1 = tin[j * 4 + 1];  r2 = tin[j * 4 + 2];
    }
}

__global__ void hist_k(const int* __restrict__ el, int E, const int* __restrict__ etype,
                       const int* __restrict__ tin, int Etot, int* __restrict__ cnt)
{
    int e = blockIdx.x * blockDim.x + threadIdx.x;
    if (e >= Etot) return;
    int dst, src, r1, r2; decode_edge(el, E, etype, tin, e, dst, src, r1, r2);
    atomicAdd(&cnt[dst], 1);
}

__global__ __launch_bounds__(1024)
void scan1_k(const int* __restrict__ cnt, int* __restrict__ start,
             int* __restrict__ aux, int n)
{
    __shared__ int tmp[1024];
    int i = blockIdx.x * 1024 + threadIdx.x;
    int v = (i < n) ? cnt[i] : 0;
    tmp[threadIdx.x] = v;
    __syncthreads();
    for (int o = 1; o < 1024; o <<= 1) {
        int t = (threadIdx.x >= (unsigned)o) ? tmp[threadIdx.x - o] : 0;
        __syncthreads();
        tmp[threadIdx.x] += t;
        __syncthreads();
    }
    if (i < n) start[i] = tmp[threadIdx.x] - v;
    if (threadIdx.x == 1023) aux[blockIdx.x] = tmp[1023];
}

__global__ void scan2_k(int* __restrict__ aux, int nb)
{
    if (threadIdx.x == 0 && blockIdx.x == 0) {
        int s = 0;
        for (int i = 0; i < nb; i++) { int v = aux[i]; aux[i] = s; s += v; }
    }
}

__global__ __launch_bounds__(1024)
void scan3_k(int* __restrict__ start, const int* __restrict__ aux, int n, int Etot)
{
    int i = blockIdx.x * 1024 + threadIdx.x;
    if (i < n) start[i] += aux[blockIdx.x];
    if (i == 0) start[n] = Etot;
}

// csr entry: .x = src, .y = r1 | (r2s<<16), r2s==0xFFFF means "no r2"
__global__ void fill_k(const int* __restrict__ el, int E, const int* __restrict__ etype,
                       const int* __restrict__ tin, int Etot,
                       const int* __restrict__ start, int* __restrict__ fill,
                       int2* __restrict__ csr)
{
    int e = blockIdx.x * blockDim.x + threadIdx.x;
    if (e >= Etot) return;
    int dst, src, r1, r2; decode_edge(el, E, etype, tin, e, dst, src, r1, r2);
    int p = start[dst] + atomicAdd(&fill[dst], 1);
    unsigned r2s = (r2 >= 0) ? (unsigned)r2 : 0xFFFFu;
    csr[p] = make_int2(src, (int)((r2s << 16) | (unsigned)r1));
}

// -------- layer-1 gather: wave/dst, two-phase (lane-parallel scalars) ------
__global__ __launch_bounds__(256)
void gather_l1_k(const int* __restrict__ start, const int2* __restrict__ csr,
                 const float* __restrict__ s1,        // [2][N] dst-side
                 const float* __restrict__ srel2,     // [R][2]
                 const __hip_bfloat16* __restrict__ pB,   // [N][PBS] interleaved
                 const float* __restrict__ rpf2,      // [R][100][2]
                 __hip_bfloat16* __restrict__ x1, int N)  // [N][KP]
{
    int n = (blockIdx.x * blockDim.x + threadIdx.x) >> 6;
    int lane = threadIdx.x & 63;
    if (n >= N) return;
    int b0 = __builtin_amdgcn_readfirstlane(start[n]);
    int b1 = __builtin_amdgcn_readfirstlane(start[n + 1]);
    float s1h0 = s1[n], s1h1 = s1[N + n];
    float rsl0 = 0.f, rsl1 = 0.f;        // per-lane partial rowsums
    float2 acc0 = {0.f, 0.f};            // k0: (h0, h1)
    float2 acc1 = {0.f, 0.f};            // k1
    int k0 = lane;
    bool k1ok = lane < 36;
    int k1c = k1ok ? (lane + 64) : 0;

    for (int c0 = b0; c0 < b1; c0 += 64) {
        int cnt = min(64, b1 - c0);
        // ---- phase A: lane e computes edge (c0+e)'s scalars; all loads in flight
        float w0 = 0.f, w1 = 0.f;
        int srcL = 0, eyL = 0;
        if (lane < cnt) {
            int2 eg = csr[c0 + lane];
            srcL = eg.x; eyL = eg.y;
            int r1 = eyL & 0xFFFF;
            unsigned r2u = (unsigned)eyL >> 16;
            float2 sA = *(const float2*)((const char*)pB + (size_t)(unsigned)srcL * (PBS * 2) + 400);
            float2 sr = *(const float2*)(srel2 + r1 * 2);
            float z0 = s1h0 + sA.x + sr.x;
            float z1 = s1h1 + sA.y + sr.y;
            if (r2u != 0xFFFFu) {
                float2 sr2v = *(const float2*)(srel2 + r2u * 2);
                z0 += sr2v.x; z1 += sr2v.y;
            }
            w0 = expf(-(z0 > 0.f ? z0 : 0.2f * z0));
            w1 = expf(-(z1 > 0.f ? z1 : 0.2f * z1));
            rsl0 += w0; rsl1 += w1;
        }
        // ---- phase B: per-edge feature FMA; 4-edge-batched pB loads
        for (int e0 = 0; e0 < cnt; e0 += 4) {
            int ec = min(4, cnt - e0);
            unsigned pw0[4], pw1[4];
#pragma unroll
            for (int u = 0; u < 4; u++) {
                if (u < ec) {
                    int s = __builtin_amdgcn_readlane(srcL, e0 + u);
                    const __hip_bfloat16* rA = pB + (size_t)(unsigned)s * PBS;
                    pw0[u] = *(const unsigned*)(rA + 2 * k0);
                    pw1[u] = *(const unsigned*)(rA + 2 * k1c);
                }
            }
#pragma unroll
            for (int u = 0; u < 4; u++) {
                if (u < ec) {
                    int ey = __builtin_amdgcn_readlane(eyL, e0 + u);
                    int r1 = ey & 0xFFFF;
                    unsigned r2u = (unsigned)ey >> 16;
                    float we0 = readlaneF(w0, e0 + u);
                    float we1 = readlaneF(w1, e0 + u);
                    const float2* q1 = (const float2*)(rpf2 + (unsigned)r1 * 200);
                    float2 q1a = q1[k0], q1b = q1[k1c];
                    float v00 = bfLo(pw0[u]) + q1a.x;
                    float v01 = bfHi(pw0[u]) + q1a.y;
                    float v10 = bfLo(pw1[u]) + q1b.x;
                    float v11 = bfHi(pw1[u]) + q1b.y;
                    if (r2u != 0xFFFFu) {
                        const float2* q2 = (const float2*)(rpf2 + r2u * 200);
                        float2 q2a = q2[k0], q2b = q2[k1c];
                        v00 += q2a.x; v01 += q2a.y;
                        v10 += q2b.x; v11 += q2b.y;
                    }
                    acc0.x += we0 * v00; acc0.y += we1 * v01;
                    acc1.x += we0 * v10; acc1.y += we1 * v11;
                }
            }
        }
    }

    // wave-reduce rowsums (butterfly -> all lanes)
#pragma unroll
    for (int o = 1; o < 64; o <<= 1) {
        rsl0 += __shfl_xor(rsl0, o);
        rsl1 += __shfl_xor(rsl1, o);
    }
    float i0 = rsl0 > 0.f ? 1.f / rsl0 : 0.f;
    float i1 = rsl1 > 0.f ? 1.f / rsl1 : 0.f;
    __hip_bfloat16* xr = x1 + (size_t)n * KP;
    float hp;
    hp = rsl0 > 0.f ? toF(xr[k0]) + acc0.x * i0 : 0.f;
    xr[k0] = __float2bfloat16(hp > 0.f ? hp : expf(hp) - 1.f);
    hp = rsl1 > 0.f ? toF(xr[100 + k0]) + acc0.y * i1 : 0.f;
    xr[100 + k0] = __float2bfloat16(hp > 0.f ? hp : expf(hp) - 1.f);
    if (k1ok) {
        int k1 = lane + 64;
        hp = rsl0 > 0.f ? toF(xr[k1]) + acc1.x * i0 : 0.f;
        xr[k1] = __float2bfloat16(hp > 0.f ? hp : expf(hp) - 1.f);
        hp = rsl1 > 0.f ? toF(xr[100 + k1]) + acc1.y * i1 : 0.f;
        xr[100 + k1] = __float2bfloat16(hp > 0.f ? hp : expf(hp) - 1.f);
    }
}

// -------- layer-2 gather: wave/dst, two-phase; fused +entW + l2norm -------
__global__ __launch_bounds__(256)
void gather_l2_k(const int* __restrict__ start, const int2* __restrict__ csr,
                 const float* __restrict__ s1,
                 const float* __restrict__ srel,          // [R]
                 const __hip_bfloat16* __restrict__ x1A2, // [N][PBS]: feats+s2+entW
                 const float* __restrict__ rpf,           // [R][200]
                 const float* __restrict__ maskf,
                 float* __restrict__ outent, int N)       // [N][200], holds x1A1
{
    int n = (blockIdx.x * blockDim.x + threadIdx.x) >> 6;
    int lane = threadIdx.x & 63;
    if (n >= N) return;
    int b0 = __builtin_amdgcn_readfirstlane(start[n]);
    int b1 = __builtin_amdgcn_readfirstlane(start[n + 1]);
    float s1n = s1[n];
    float rsl = 0.f;
    float2 a0 = {0.f, 0.f};   // k = 2*lane, 2*lane+1
    float2 a1 = {0.f, 0.f};   // k = 128+2*lane, +1 (lane<36)
    int j0 = 2 * lane;
    bool j1ok = lane < 36;
    int j1 = j1ok ? (128 + 2 * lane) : 0;

    for (int c0 = b0; c0 < b1; c0 += 64) {
        int cnt = min(64, b1 - c0);
        // ---- phase A: lane-parallel per-edge scalars
        float w = 0.f;
        int srcL = 0, eyL = 0;
        if (lane < cnt) {
            int2 eg = csr[c0 + lane];
            srcL = eg.x; eyL = eg.y;
            int r1 = eyL & 0xFFFF;
            unsigned r2u = (unsigned)eyL >> 16;
            float s2v = *(const float*)((const char*)x1A2 + (size_t)(unsigned)srcL * (PBS * 2) + 400);
            float sr = srel[r1];
            if (r2u != 0xFFFFu) sr += srel[r2u];
            float z = s1n + s2v + sr;
            w = expf(-(z > 0.f ? z : 0.2f * z));
            rsl += w;
        }
        // ---- phase B: per-edge feature FMA; 4-edge-batched feature loads
        for (int e0 = 0; e0 < cnt; e0 += 4) {
            int ec = min(4, cnt - e0);
            unsigned xw0[4], xw1[4];
#pragma unroll
            for (int u = 0; u < 4; u++) {
                if (u < ec) {
                    int s = __builtin_amdgcn_readlane(srcL, e0 + u);
                    const __hip_bfloat16* xs = x1A2 + (size_t)(unsigned)s * PBS;
                    xw0[u] = *(const unsigned*)(xs + j0);
                    xw1[u] = *(const unsigned*)(xs + j1);
                }
            }
#pragma unroll
            for (int u = 0; u < 4; u++) {
                if (u < ec) {
                    int ey = __builtin_amdgcn_readlane(eyL, e0 + u);
                    int r1 = ey & 0xFFFF;
                    unsigned r2u = (unsigned)ey >> 16;
                    float we = readlaneF(w, e0 + u);
                    const float* q1 = rpf + (unsigned)r1 * 200;
                    float2 q1a = *(const float2*)(q1 + j0);
                    float2 q1b = *(const float2*)(q1 + j1);
                    float v0x = bfLo(xw0[u]) + q1a.x;
                    float v0y = bfHi(xw0[u]) + q1a.y;
                    float v1x = bfLo(xw1[u]) + q1b.x;
                    float v1y = bfHi(xw1[u]) + q1b.y;
                    if (r2u != 0xFFFFu) {
                        const float* q2 = rpf + r2u * 200;
                        float2 q2a = *(const float2*)(q2 + j0);
                        float2 q2b = *(const float2*)(q2 + j1);
                        v0x += q2a.x; v0y += q2a.y;
                        v1x += q2b.x; v1y += q2b.y;
                    }
                    a0.x += we * v0x; a0.y += we * v0y;
                    a1.x += we * v1x; a1.y += we * v1y;
                }
            }
        }
    }

#pragma unroll
    for (int o = 1; o < 64; o <<= 1) rsl += __shfl_xor(rsl, o);
    float inv = rsl > 0.f ? 1.f / rsl : 0.f;
    float mk = maskf[n];
    float* orow = outent + (size_t)n * 200;
    const __hip_bfloat16* ew = x1A2 + (size_t)n * PBS + 224;  // own dst row's entW

    float2 o0 = *(const float2*)(orow + j0);
    unsigned e0b = *(const unsigned*)(ew + j0);
    float h0x = rsl > 0.f ? o0.x + a0.x * inv : 0.f;
    float h0y = rsl > 0.f ? o0.y + a0.y * inv : 0.f;
    float v0x = mk * (h0x > 0.f ? h0x : expf(h0x) - 1.f) + bfLo(e0b);
    float v0y = mk * (h0y > 0.f ? h0y : expf(h0y) - 1.f) + bfHi(e0b);
    float ssq = v0x * v0x + v0y * v0y;
    float v1x = 0.f, v1y = 0.f;
    if (j1ok) {
        float2 o1 = *(const float2*)(orow + j1);
        unsigned e1b = *(const unsigned*)(ew + j1);
        float h1x = rsl > 0.f ? o1.x + a1.x * inv : 0.f;
        float h1y = rsl > 0.f ? o1.y + a1.y * inv : 0.f;
        v1x = mk * (h1x > 0.f ? h1x : expf(h1x) - 1.f) + bfLo(e1b);
        v1y = mk * (h1y > 0.f ? h1y : expf(h1y) - 1.f) + bfHi(e1b);
        ssq += v1x * v1x + v1y * v1y;
    }
#pragma unroll
    for (int o = 1; o < 64; o <<= 1) ssq += __shfl_xor(ssq, o);
    float sc = 1.f / fmaxf(sqrtf(ssq), 1e-12f);
    float2 r0; r0.x = v0x * sc; r0.y = v0y * sc;
    *(float2*)(orow + j0) = r0;
    if (j1ok) {
        float2 r1; r1.x = v1x * sc; r1.y = v1y * sc;
        *(float2*)(orow + j1) = r1;
    }
}

__global__ void scatter_mask_k(const int* __restrict__ batch, int NB,
                               float* __restrict__ masko)
{
    int i = blockIdx.x * blockDim.x + threadIdx.x;
    if (i >= NB) return;
    masko[batch[i]] = 1.0f;
}

extern "C" void kernel_launch(void* const* d_in, const int* in_sizes, int n_in,
                              void* d_out, int out_size, void* d_ws, size_t ws_size,
                              hipStream_t stream)
{
    const float* ent      = (const float*)d_in[0];
    const float* rel      = (const float*)d_in[1];
    const float* W_ent    = (const float*)d_in[2];
    const float* W_gat    = (const float*)d_in[3];
    const float* a_heads  = (const float*)d_in[4];
    const float* a2_heads = (const float*)d_in[5];
    const float* a_out    = (const float*)d_in[6];
    const float* a2_out   = (const float*)d_in[7];
    const int* batch = (const int*)d_in[8];
    const int* el    = (const int*)d_in[9];
    const int* etype = (const int*)d_in[10];
    const int* tin   = (const int*)d_in[11];

    const int N   = in_sizes[0] / DD;   // 50000
    const int R   = in_sizes[1] / DD;   // 500
    const int NB  = in_sizes[8];        // 20000
    const int E   = in_sizes[9] / 2;    // 150000
    const int ENH = in_sizes[11] / 4;   // 30000
    const int Etot = E + ENH;

    // ---- workspace (~70 MB) ----
    char* ws = (char*)d_ws;
    size_t off = 0;
    auto take = [&](size_t bytes) { size_t o = off; off += (bytes + 255) & ~(size_t)255; return o; };
    size_t o_R1   = take((size_t)N * KP * 2);     // x1 bf16 [N][KP]
    size_t o_R2   = take((size_t)N * PBS * 2);    // pB/x1A2 [N][PBS] + s2 + entW
    size_t o_rpf  = take((size_t)2 * R * 100 * 4);// rpf2 [R][100][2] / layer2 rpf [R][200]
    size_t o_bt1  = take((size_t)400 * KP * 2);   // l1 panel (179200 B, 256-mult)
    size_t o_btf  = take((size_t)208 * KP * 2);   // W_ent panel: ADJACENT to bt1
    size_t o_bt2  = take((size_t)400 * KP * 2);
    size_t o_nsc  = take((size_t)N * 4);
    size_t o_s1   = take((size_t)2 * N * 4);      // aliased by cnt during CSR build
    size_t o_srel = take((size_t)2 * R * 4);      // [R][2] layer1 / [R] layer2
    size_t o_csr  = take((size_t)Etot * 8);
    size_t o_str  = take((size_t)(N + 1) * 4);
    size_t o_aux  = take((size_t)64 * 4);

    __hip_bfloat16* x1   = (__hip_bfloat16*)(ws + o_R1);
    __hip_bfloat16* pB   = (__hip_bfloat16*)(ws + o_R2);
    __hip_bfloat16* x1A2 = (__hip_bfloat16*)(ws + o_R2);
    float* rpf2   = (float*)(ws + o_rpf);
    __hip_bfloat16* bt1 = (__hip_bfloat16*)(ws + o_bt1);  // [608][KP] combined w/ btf
    __hip_bfloat16* btf = (__hip_bfloat16*)(ws + o_btf);
    __hip_bfloat16* bt2 = (__hip_bfloat16*)(ws + o_bt2);
    float* nscale = (float*)(ws + o_nsc);
    float* s1     = (float*)(ws + o_s1);
    float* srel2  = (float*)(ws + o_srel);
    int2*  csr    = (int2*)(ws + o_csr);
    int*   cnt    = (int*)(ws + o_s1);   // CSR-build scratch; dead before l1_both_k writes s1
    int*   startA = (int*)(ws + o_str);
    int*   aux    = (int*)(ws + o_aux);

    float* out       = (float*)d_out;
    float* out_ent   = out;                                     // [N,200]
    float* out_rel_o = out + (size_t)N * OD;                    // [500,200]
    float* out_mask  = out + (size_t)N * OD + (size_t)R * OD;   // [N]

    const int nblk = cdiv(N, 64);
    const int nbScan = cdiv(N, 1024);

    // A. prep: norms, B panels (bt1+btf contiguous -> 608-row combined panel)
    rownorm_inv_k<<<cdiv(N, 4), 256, 0, stream>>>(ent, nscale, N, DD);
    prep_bt_l1<<<400, 256, 0, stream>>>(a_heads, bt1);
    prep_bt_fin<<<208, 256, 0, stream>>>(W_ent, btf);
    prep_bt_l2<<<400, 256, 0, stream>>>(a_out, bt2);
    hipMemsetAsync(x1, 0, (size_t)N * KP * 2, stream);
    gemm_mfma_k<false, float, float><<<dim3(cdiv(OD, 64), cdiv(R, 64)), 256, 0, stream>>>(
        rel, DD, nullptr, W_gat, OD, 0, out_rel_o, OD, 1, 0, R, OD, DD);

    // A2. CSR build (dst-grouped edge lists)
    hipMemsetAsync(cnt, 0, (size_t)N * 4, stream);
    hist_k<<<cdiv(Etot, 256), 256, 0, stream>>>(el, E, etype, tin, Etot, cnt);
    scan1_k<<<nbScan, 1024, 0, stream>>>(cnt, startA, aux, N);
    scan2_k<<<1, 64, 0, stream>>>(aux, nbScan);
    scan3_k<<<nbScan, 1024, 0, stream>>>(startA, aux, N, Etot);
    hipMemsetAsync(cnt, 0, (size_t)N * 4, stream);
    fill_k<<<cdiv(Etot, 256), 256, 0, stream>>>(el, E, etype, tin, Etot, startA, cnt, csr);

    // B. layer-1 projections (both heads + entW phase-2) + rel side + gather
    l1_both_k<<<nblk, 256, 0, stream>>>(ent, nscale, bt1, a2_heads, x1, pB, s1, N);
    for (int h = 0; h < 2; h++) {
        const float* ah  = a_heads + (size_t)h * NHID * 600;
        const float* a2h = a2_heads + (size_t)h * NHID;
        gemm_mfma_k<true, float, float><<<dim3(cdiv(NHID, 64), cdiv(R, 64)), 256, 0, stream>>>(
            rel, DD, nullptr, ah, 600, 400, rpf2, 200, 2, h, R, NHID, DD);
        rowdot_k<float><<<cdiv(R, 4), 256, 0, stream>>>(
            rpf2, 200, h, 2, a2h, srel2, 2, h, R, NHID);
    }
    gather_l1_k<<<cdiv(N, 4), 256, 0, stream>>>(
        startA, csr, s1, srel2, pB, rpf2, x1, N);
    // pB feats dead; R2 rows become x1A2 (entW at shorts 224.. survives).

    // C. layer-2 projection + rel side
    l2_proj_k<<<nblk, 256, 0, stream>>>(x1, bt2, a2_out, out_ent, x1A2, s1, N);
    gemm_mfma_k<true, float, float><<<dim3(cdiv(OD, 64), cdiv(R, 64)), 256, 0, stream>>>(
        out_rel_o, OD, nullptr, a_out, 600, 400, rpf2, OD, 1, 0, R, OD, OD);
    rowdot_k<float><<<cdiv(R, 4), 256, 0, stream>>>(rpf2, OD, 0, 1, a2_out, srel2, 1, 0, R, OD);

    // D. mask; layer-2 gather (fused combine + entW + l2norm -> final out_ent)
    hipMemsetAsync(out_mask, 0, (size_t)N * 4, stream);
    scatter_mask_k<<<cdiv(NB, 256), 256, 0, stream>>>(batch, NB, out_mask);
    gather_l2_k<<<cdiv(N, 4), 256, 0, stream>>>(
        startA, csr, s1, srel2, x1A2, rpf2, out_mask, out_ent, N);
}

// Round 8
// 507.920 us; speedup vs baseline: 1.2149x; 1.2149x over previous
//
#include <hip/hip_runtime.h>
#include <hip/hip_bf16.h>
#include <math.h>

// SpKBGAT: N=50000, D=200, R=500, NHID=100, H=2, OD=200, E=150000, ENH=30000.
// R16: R15's l1_both_k hit guide rule #20 -- abuf[7] indexed by the runtime
// chunk var went to SCRATCH (VGPR 164, occ 9%, 220us). Fix: drop the hoist;
// BOTH phases load the A row-slice inside the chunk loop (R10-measured 55us
// structure; phase-2 reload is L1/L2-hot). Keep: entW fusion (no final_mfma),
// PBS=448 rows, gather_l2 +entW+l2norm epilogue, R15's restored l2_proj.
#define DD   200
#define NHID 100
#define OD   200
#define KP   224   // padded K (7 chunks of 32)
#define PBS  448   // row stride (bf16) for pB / x1A2 / entW: 896 B
                   // [0..199]: pB [k][h0,h1] pairs (l1) / x1A2 feats (l2)
                   // bytes 400..407: s2 floats;  shorts [224..423]: entW bf16
#define LDSW 40    // LDS row stride in shorts (80 B)

typedef __attribute__((ext_vector_type(8))) short short8;
typedef __attribute__((ext_vector_type(4))) float f32x4;

static inline int cdiv(int a, int b) { return (a + b - 1) / b; }

__device__ inline float toF(float x) { return x; }
__device__ inline float toF(__hip_bfloat16 x) { return __bfloat162float(x); }
__device__ inline void storeC(float v, float* p) { *p = v; }
__device__ inline void storeC(float v, __hip_bfloat16* p) { *p = __float2bfloat16(v); }
__device__ inline short bf16s(float f) {
    __hip_bfloat16 h = __float2bfloat16(f);
    short s; __builtin_memcpy(&s, &h, 2); return s;
}
__device__ inline float bfLo(unsigned u) { return __uint_as_float(u << 16); }
__device__ inline float bfHi(unsigned u) { return __uint_as_float(u & 0xFFFF0000u); }
__device__ inline float readlaneF(float v, int l) {
    return __uint_as_float((unsigned)__builtin_amdgcn_readlane((int)__float_as_uint(v), l));
}

// -------- per-row inverse L2 norm (f32), wave per row --------
__global__ __launch_bounds__(256)
void rownorm_inv_k(const float* __restrict__ in, float* __restrict__ sc, int M, int Dd)
{
    int wave = (blockIdx.x * blockDim.x + threadIdx.x) >> 6;
    int lane = threadIdx.x & 63;
    if (wave >= M) return;
    float ss = 0.f;
    for (int k = lane; k < Dd; k += 64) {
        float x = in[(size_t)wave * Dd + k];
        ss += x * x;
    }
    for (int o = 32; o > 0; o >>= 1) ss += __shfl_down(ss, o);
    if (lane == 0) sc[wave] = 1.f / fmaxf(sqrtf(ss), 1e-12f);
}

// -------- B-panel prep: bf16 [col][KP], zero-padded --------
__global__ void prep_bt_l1(const float* __restrict__ ah, __hip_bfloat16* __restrict__ Bt)
{
    int c = blockIdx.x, k = threadIdx.x;
    if (k >= KP) return;
    int seg = c / 100, idx = c - seg * 100;
    int h = seg & 1, off = (seg >> 1) * 200;
    float v = (k < 200) ? ah[(size_t)(h * 100 + idx) * 600 + off + k] : 0.f;
    Bt[(size_t)c * KP + k] = __float2bfloat16(v);
}
__global__ void prep_bt_l2(const float* __restrict__ ao, __hip_bfloat16* __restrict__ Bt)
{
    int c = blockIdx.x, k = threadIdx.x;
    if (k >= KP) return;
    int row = (c < 200) ? c : c - 200;
    int off = (c < 200) ? 0 : 200;
    float v = (k < 200) ? ao[(size_t)row * 600 + off + k] : 0.f;
    Bt[(size_t)c * KP + k] = __float2bfloat16(v);
}
__global__ void prep_bt_fin(const float* __restrict__ W, __hip_bfloat16* __restrict__ Bt)
{
    int c = blockIdx.x, k = threadIdx.x;
    if (k >= KP) return;
    float v = (c < 200 && k < 200) ? W[(size_t)k * 200 + c] : 0.f;
    Bt[(size_t)c * KP + k] = __float2bfloat16(v);
}

// -------- layer-1 fused, two-phase: 25 l1 tiles then 13 entW tiles --------
__global__ __launch_bounds__(256)
void l1_both_k(const float* __restrict__ ent, const float* __restrict__ nscale,
               const __hip_bfloat16* __restrict__ Bt,  // [608][KP] (l1 400 + W_ent 208)
               const float* __restrict__ a2h,          // [2][100]
               __hip_bfloat16* __restrict__ x1,        // [N][KP] (cols 0-199)
               __hip_bfloat16* __restrict__ pB,        // [N][PBS]: pB + s2 + entW
               float* __restrict__ s1,                 // [2][N]
               int M)
{
    __shared__ __align__(16) __hip_bfloat16 Bs[400 * LDSW];  // 32 KB
    int tid = threadIdx.x, wave = tid >> 6, lane = tid & 63;
    int quad = lane >> 4, l16 = lane & 15;
    int m0 = blockIdx.x * 64;
    int arow = m0 + wave * 16 + l16;
    bool rok = arow < M;
    float nsc = rok ? nscale[arow] : 0.f;
    const float* arp = ent + (size_t)arow * DD;

    // ---- phase 1: 25 tiles over Bt rows [0,400) -- R10-measured pipeline ----
    f32x4 acc[25];
#pragma unroll
    for (int t = 0; t < 25; t++) acc[t] = (f32x4){0.f, 0.f, 0.f, 0.f};

    short8 stg[7];
#pragma unroll
    for (int i = 0; i < 7; i++) {
        int idx = tid + i * 256;
        if (idx < 1600) {
            int r = idx >> 2, c8 = idx & 3;
            stg[i] = *(const short8*)(Bt + (size_t)r * KP + c8 * 8);
        }
    }
    for (int ch = 0; ch < 7; ch++) {
#pragma unroll
        for (int i = 0; i < 7; i++) {
            int idx = tid + i * 256;
            if (idx < 1600) {
                int r = idx >> 2, c8 = idx & 3;
                *(short8*)(Bs + r * LDSW + c8 * 8) = stg[i];
            }
        }
        __syncthreads();
        if (ch < 6) {
            int kb2 = (ch + 1) * 32;
#pragma unroll
            for (int i = 0; i < 7; i++) {
                int idx = tid + i * 256;
                if (idx < 1600) {
                    int r = idx >> 2, c8 = idx & 3;
                    stg[i] = *(const short8*)(Bt + (size_t)r * KP + kb2 + c8 * 8);
                }
            }
        }
        int kb = ch * 32 + quad * 8;
        float av[8];
        if (rok && kb + 8 <= DD) {
            const float4* p = (const float4*)(arp + kb);
            float4 u0 = p[0], u1 = p[1];
            av[0] = u0.x; av[1] = u0.y; av[2] = u0.z; av[3] = u0.w;
            av[4] = u1.x; av[5] = u1.y; av[6] = u1.z; av[7] = u1.w;
        } else {
#pragma unroll
            for (int j = 0; j < 8; j++) av[j] = (rok && kb + j < DD) ? arp[kb + j] : 0.f;
        }
        short8 a;
#pragma unroll
        for (int j = 0; j < 8; j++) a[j] = bf16s(av[j] * nsc);
        const __hip_bfloat16* bp = Bs + (size_t)l16 * LDSW + quad * 8;
#pragma unroll
        for (int t = 0; t < 25; t++) {
            short8 b = *(const short8*)(bp + (size_t)t * 16 * LDSW);
            acc[t] = __builtin_amdgcn_mfma_f32_16x16x32_bf16(a, b, acc[t], 0, 0, 0);
        }
        __syncthreads();
    }

    // prefetch phase-2 chunk 0 NOW; latency hides under epilogue-1 stores
    short8 stg2[4];
#pragma unroll
    for (int i = 0; i < 4; i++) {
        int idx = tid + i * 256;
        if (idx < 832) {
            int r = idx >> 2, c8 = idx & 3;
            stg2[i] = *(const short8*)(Bt + (size_t)(400 + r) * KP + c8 * 8);
        }
    }

    // ---- epilogue 1: x1, pB feats, s1/s2 ----
    int orow = m0 + wave * 16 + quad * 4;
    float d0[4] = {0,0,0,0}, d1[4] = {0,0,0,0}, d2[4] = {0,0,0,0}, d3[4] = {0,0,0,0};
#pragma unroll
    for (int t = 0; t < 25; t++) {
        int c = t * 16 + l16;
        int seg = c / 100, idx = c - seg * 100;
        float w = a2h[(seg & 1) * 100 + idx];
#pragma unroll
        for (int i = 0; i < 4; i++) {
            float v = acc[t][i];
            float vw = v * w;
            if (seg == 0) d0[i] += vw;
            else if (seg == 1) d1[i] += vw;
            else if (seg == 2) d2[i] += vw;
            else d3[i] += vw;
            int gm = orow + i;
            if (gm < M) {
                if (seg < 2) x1[(size_t)gm * KP + c] = __float2bfloat16(v);
                else pB[(size_t)gm * PBS + idx * 2 + (seg - 2)] = __float2bfloat16(v);
            }
        }
    }
#pragma unroll
    for (int msk = 1; msk < 16; msk <<= 1)
#pragma unroll
        for (int i = 0; i < 4; i++) {
            d0[i] += __shfl_xor(d0[i], msk);
            d1[i] += __shfl_xor(d1[i], msk);
            d2[i] += __shfl_xor(d2[i], msk);
            d3[i] += __shfl_xor(d3[i], msk);
        }
    if (l16 == 0)
#pragma unroll
        for (int i = 0; i < 4; i++) {
            int gm = orow + i;
            if (gm < M) {
                s1[gm] = d0[i]; s1[M + gm] = d1[i];
                float2 sv; sv.x = d2[i]; sv.y = d3[i];
                *(float2*)((char*)pB + (size_t)gm * (PBS * 2) + 400) = sv;
            }
        }

    // ---- phase 2: 13 entW tiles over Bt rows [400,608) ----
    f32x4 acc2[13];
#pragma unroll
    for (int t = 0; t < 13; t++) acc2[t] = (f32x4){0.f, 0.f, 0.f, 0.f};

    for (int ch = 0; ch < 7; ch++) {
#pragma unroll
        for (int i = 0; i < 4; i++) {
            int idx = tid + i * 256;
            if (idx < 832) {
                int r = idx >> 2, c8 = idx & 3;
                *(short8*)(Bs + r * LDSW + c8 * 8) = stg2[i];
            }
        }
        __syncthreads();
        if (ch < 6) {
            int kb2 = (ch + 1) * 32;
#pragma unroll
            for (int i = 0; i < 4; i++) {
                int idx = tid + i * 256;
                if (idx < 832) {
                    int r = idx >> 2, c8 = idx & 3;
                    stg2[i] = *(const short8*)(Bt + (size_t)(400 + r) * KP + kb2 + c8 * 8);
                }
            }
        }
        // reload A slice (L1/L2-hot: same addresses as phase 1)
        int kb = ch * 32 + quad * 8;
        float av[8];
        if (rok && kb + 8 <= DD) {
            const float4* p = (const float4*)(arp + kb);
            float4 u0 = p[0], u1 = p[1];
            av[0] = u0.x; av[1] = u0.y; av[2] = u0.z; av[3] = u0.w;
            av[4] = u1.x; av[5] = u1.y; av[6] = u1.z; av[7] = u1.w;
        } else {
#pragma unroll
            for (int j = 0; j < 8; j++) av[j] = (rok && kb + j < DD) ? arp[kb + j] : 0.f;
        }
        short8 a;
#pragma unroll
        for (int j = 0; j < 8; j++) a[j] = bf16s(av[j] * nsc);
        const __hip_bfloat16* bp = Bs + (size_t)l16 * LDSW + quad * 8;
#pragma unroll
        for (int t = 0; t < 13; t++) {
            short8 b = *(const short8*)(bp + (size_t)t * 16 * LDSW);
            acc2[t] = __builtin_amdgcn_mfma_f32_16x16x32_bf16(a, b, acc2[t], 0, 0, 0);
        }
        __syncthreads();
    }
    // entW epilogue: bf16 into row pad shorts [224..423]
#pragma unroll
    for (int t = 0; t < 13; t++) {
        int c2 = t * 16 + l16;
#pragma unroll
        for (int i = 0; i < 4; i++) {
            int gm = orow + i;
            if (c2 < OD && gm < M)
                pB[(size_t)gm * PBS + 224 + c2] = __float2bfloat16(acc2[t][i]);
        }
    }
}

// -------- layer-2 fused: 25 tiles = x1A1 (f32 -> out_ent) | x1A2 (bf16) ----
__global__ __launch_bounds__(256)
void l2_proj_k(const __hip_bfloat16* __restrict__ x1,  // [N][KP]
               const __hip_bfloat16* __restrict__ Bt,  // [400][KP]
               const float* __restrict__ a2o,          // [200]
               float* __restrict__ x1A1,               // [N][200] (out_ent)
               __hip_bfloat16* __restrict__ x1A2,      // [N][PBS], s2 in pad
               float* __restrict__ s1, int M)
{
    __shared__ __align__(16) __hip_bfloat16 Bs[400 * LDSW];  // 32 KB
    int tid = threadIdx.x, wave = tid >> 6, lane = tid & 63;
    int quad = lane >> 4, l16 = lane & 15;
    int m0 = blockIdx.x * 64;
    int arow = m0 + wave * 16 + l16;
    bool rok = arow < M;
    const __hip_bfloat16* arp = x1 + (size_t)arow * KP;

    f32x4 acc[25];
#pragma unroll
    for (int t = 0; t < 25; t++) acc[t] = (f32x4){0.f, 0.f, 0.f, 0.f};

    short8 stg[7];
#pragma unroll
    for (int i = 0; i < 7; i++) {
        int idx = tid + i * 256;
        if (idx < 1600) {
            int r = idx >> 2, c8 = idx & 3;
            stg[i] = *(const short8*)(Bt + (size_t)r * KP + c8 * 8);
        }
    }

    for (int ch = 0; ch < 7; ch++) {
#pragma unroll
        for (int i = 0; i < 7; i++) {
            int idx = tid + i * 256;
            if (idx < 1600) {
                int r = idx >> 2, c8 = idx & 3;
                *(short8*)(Bs + r * LDSW + c8 * 8) = stg[i];
            }
        }
        __syncthreads();
        if (ch < 6) {
            int kb2 = (ch + 1) * 32;
#pragma unroll
            for (int i = 0; i < 7; i++) {
                int idx = tid + i * 256;
                if (idx < 1600) {
                    int r = idx >> 2, c8 = idx & 3;
                    stg[i] = *(const short8*)(Bt + (size_t)r * KP + kb2 + c8 * 8);
                }
            }
        }
        int kb = ch * 32 + quad * 8;
        short8 a = (short8){0,0,0,0,0,0,0,0};
        if (rok) a = *(const short8*)(arp + kb);
        const __hip_bfloat16* bp = Bs + (size_t)l16 * LDSW + quad * 8;
#pragma unroll
        for (int t = 0; t < 25; t++) {
            short8 b = *(const short8*)(bp + (size_t)t * 16 * LDSW);
            acc[t] = __builtin_amdgcn_mfma_f32_16x16x32_bf16(a, b, acc[t], 0, 0, 0);
        }
        __syncthreads();
    }

    int orow = m0 + wave * 16 + quad * 4;
    float dA[4] = {0,0,0,0}, dB[4] = {0,0,0,0};
#pragma unroll
    for (int t = 0; t < 25; t++) {
        int c = t * 16 + l16;
        bool first = c < 200;
        int cc = first ? c : c - 200;
        float w = a2o[cc];
#pragma unroll
        for (int i = 0; i < 4; i++) {
            float v = acc[t][i];
            int gm = orow + i;
            if (first) {
                dA[i] += v * w;
                if (gm < M) x1A1[(size_t)gm * OD + c] = v;
            } else {
                dB[i] += v * w;
                if (gm < M) x1A2[(size_t)gm * PBS + cc] = __float2bfloat16(v);
            }
        }
    }
#pragma unroll
    for (int msk = 1; msk < 16; msk <<= 1)
#pragma unroll
        for (int i = 0; i < 4; i++) {
            dA[i] += __shfl_xor(dA[i], msk);
            dB[i] += __shfl_xor(dB[i], msk);
        }
    if (l16 == 0)
#pragma unroll
        for (int i = 0; i < 4; i++) {
            int gm = orow + i;
            if (gm < M) {
                s1[gm] = dA[i];
                *(float*)((char*)x1A2 + (size_t)gm * (PBS * 2) + 400) = dB[i];
            }
        }
}

// -------- generic MFMA GEMM (small R-sized matmuls); cs/co = C col-stride --
#define KPAD 48
template<bool BTr, typename AT, typename CT>
__global__ __launch_bounds__(256)
void gemm_mfma_k(const AT* __restrict__ A, int lda, const float* __restrict__ ascale,
                 const float* __restrict__ B, int ldb, int colOff,
                 CT* __restrict__ C, int ldc, int cs, int co,
                 int M, int Nc, int K)
{
    __shared__ __align__(16) __hip_bfloat16 As[64][KPAD];
    __shared__ __align__(16) __hip_bfloat16 Bs[64][KPAD];
    int tid  = threadIdx.x;
    int wave = tid >> 6, lane = tid & 63;
    int quad = lane >> 4, l16 = lane & 15;
    int n0 = blockIdx.x * 64, m0 = blockIdx.y * 64;
    f32x4 acc[4];
#pragma unroll
    for (int t = 0; t < 4; t++) acc[t] = (f32x4){0.f, 0.f, 0.f, 0.f};

    for (int k0 = 0; k0 < K; k0 += 32) {
        {
            int m = tid >> 2, kc = (tid & 3) * 8;
            int gm = m0 + m;
            float scale = (ascale && gm < M) ? ascale[gm] : 1.f;
#pragma unroll
            for (int j = 0; j < 8; j++) {
                int gk = k0 + kc + j;
                float v = 0.f;
                if (gm < M && gk < K) v = toF(A[(size_t)gm * lda + gk]) * scale;
                As[m][kc + j] = __float2bfloat16(v);
            }
        }
        if (BTr) {
            int n = tid >> 2, kc = (tid & 3) * 8;
            int gn = n0 + n;
#pragma unroll
            for (int j = 0; j < 8; j++) {
                int gk = k0 + kc + j;
                float v = 0.f;
                if (gn < Nc && gk < K) v = B[(size_t)gn * ldb + colOff + gk];
                Bs[n][kc + j] = __float2bfloat16(v);
            }
        } else {
            int n = tid & 63, kq = tid >> 6;
            int gn = n0 + n;
#pragma unroll
            for (int j = 0; j < 8; j++) {
                int gk = k0 + kq * 8 + j;
                float v = 0.f;
                if (gn < Nc && gk < K) v = B[(size_t)gk * ldb + gn];
                Bs[n][kq * 8 + j] = __float2bfloat16(v);
            }
        }
        __syncthreads();
        short8 a = *(const short8*)&As[wave * 16 + l16][quad * 8];
#pragma unroll
        for (int t = 0; t < 4; t++) {
            short8 b = *(const short8*)&Bs[t * 16 + l16][quad * 8];
            acc[t] = __builtin_amdgcn_mfma_f32_16x16x32_bf16(a, b, acc[t], 0, 0, 0);
        }
        __syncthreads();
    }
#pragma unroll
    for (int t = 0; t < 4; t++) {
        int gn = n0 + t * 16 + l16;
        if (gn >= Nc) continue;
#pragma unroll
        for (int i = 0; i < 4; i++) {
            int gm = m0 + wave * 16 + quad * 4 + i;
            if (gm < M) storeC(acc[t][i], &C[(size_t)gm * ldc + (size_t)gn * cs + co]);
        }
    }
}

// -------- row-dot (srel); ks = k-stride in mat, os/oo = output stride ------
template<typename T>
__global__ __launch_bounds__(256)
void rowdot_k(const T* __restrict__ mat, int ld, int coff, int ks,
              const float* __restrict__ vec,
              float* __restrict__ outp, int os, int oo, int M, int Dd)
{
    int wave = (blockIdx.x * blockDim.x + threadIdx.x) >> 6;
    int lane = threadIdx.x & 63;
    if (wave >= M) return;
    float s = 0.f;
    for (int k = lane; k < Dd; k += 64)
        s += toF(mat[(size_t)wave * ld + coff + (size_t)k * ks]) * vec[k];
    for (int o = 32; o > 0; o >>= 1) s += __shfl_down(s, o);
    if (lane == 0) outp[wave * os + oo] = s;
}

// -------- CSR build --------
__device__ inline void decode_edge(const int* __restrict__ el, int E,
                                   const int* __restrict__ etype,
                                   const int* __restrict__ tin, int e,
                                   int& dst, int& src, int& r1, int& r2)
{
    if (e < E) { dst = el[e]; src = el[E + e]; r1 = etype[e]; r2 = -1; }
    else {
        int j = e - E;
        dst = tin[j * 4 + 3]; src = tin[j * 4 + 0];
        r1 = tin[j * 4 + 1];  r2 = tin[j * 4 + 2];
    }
}

__global__ void hist_k(const int* __restrict__ el, int E, const int* __restrict__ etype,
                       const int* __restrict__ tin, int Etot, int* __restrict__ cnt)
{
    int e = blockIdx.x * blockDim.x + threadIdx.x;
    if (e >= Etot) return;
    int dst, src, r1, r2; decode_edge(el, E, etype, tin, e, dst, src, r1, r2);
    atomicAdd(&cnt[dst], 1);
}

__global__ __launch_bounds__(1024)
void scan1_k(const int* __restrict__ cnt, int* __restrict__ start,
             int* __restrict__ aux, int n)
{
    __shared__ int tmp[1024];
    int i = blockIdx.x * 1024 + threadIdx.x;
    int v = (i < n) ? cnt[i] : 0;
    tmp[threadIdx.x] = v;
    __syncthreads();
    for (int o = 1; o < 1024; o <<= 1) {
        int t = (threadIdx.x >= (unsigned)o) ? tmp[threadIdx.x - o] : 0;
        __syncthreads();
        tmp[threadIdx.x] += t;
        __syncthreads();
    }
    if (i < n) start[i] = tmp[threadIdx.x] - v;
    if (threadIdx.x == 1023) aux[blockIdx.x] = tmp[1023];
}

__global__ void scan2_k(int* __restrict__ aux, int nb)
{
    if (threadIdx.x == 0 && blockIdx.x == 0) {
        int s = 0;
        for (int i = 0; i < nb; i++) { int v = aux[i]; aux[i] = s; s += v; }
    }
}

__global__ __launch_bounds__(1024)
void scan3_k(int* __restrict__ start, const int* __restrict__ aux, int n, int Etot)
{
    int i = blockIdx.x * 1024 + threadIdx.x;
    if (i < n) start[i] += aux[blockIdx.x];
    if (i == 0) start[n] = Etot;
}

// csr entry: .x = src, .y = r1 | (r2s<<16), r2s==0xFFFF means "no r2"
__global__ void fill_k(const int* __restrict__ el, int E, const int* __restrict__ etype,
                       const int* __restrict__ tin, int Etot,
                       const int* __restrict__ start, int* __restrict__ fill,
                       int2* __restrict__ csr)
{
    int e = blockIdx.x * blockDim.x + threadIdx.x;
    if (e >= Etot) return;
    int dst, src, r1, r2; decode_edge(el, E, etype, tin, e, dst, src, r1, r2);
    int p = start[dst] + atomicAdd(&fill[dst], 1);
    unsigned r2s = (r2 >= 0) ? (unsigned)r2 : 0xFFFFu;
    csr[p] = make_int2(src, (int)((r2s << 16) | (unsigned)r1));
}

// -------- layer-1 gather: wave/dst, two-phase (lane-parallel scalars) ------
__global__ __launch_bounds__(256)
void gather_l1_k(const int* __restrict__ start, const int2* __restrict__ csr,
                 const float* __restrict__ s1,        // [2][N] dst-side
                 const float* __restrict__ srel2,     // [R][2]
                 const __hip_bfloat16* __restrict__ pB,   // [N][PBS] interleaved
                 const float* __restrict__ rpf2,      // [R][100][2]
                 __hip_bfloat16* __restrict__ x1, int N)  // [N][KP]
{
    int n = (blockIdx.x * blockDim.x + threadIdx.x) >> 6;
    int lane = threadIdx.x & 63;
    if (n >= N) return;
    int b0 = __builtin_amdgcn_readfirstlane(start[n]);
    int b1 = __builtin_amdgcn_readfirstlane(start[n + 1]);
    float s1h0 = s1[n], s1h1 = s1[N + n];
    float rsl0 = 0.f, rsl1 = 0.f;        // per-lane partial rowsums
    float2 acc0 = {0.f, 0.f};            // k0: (h0, h1)
    float2 acc1 = {0.f, 0.f};            // k1
    int k0 = lane;
    bool k1ok = lane < 36;
    int k1c = k1ok ? (lane + 64) : 0;

    for (int c0 = b0; c0 < b1; c0 += 64) {
        int cnt = min(64, b1 - c0);
        // ---- phase A: lane e computes edge (c0+e)'s scalars; all loads in flight
        float w0 = 0.f, w1 = 0.f;
        int srcL = 0, eyL = 0;
        if (lane < cnt) {
            int2 eg = csr[c0 + lane];
            srcL = eg.x; eyL = eg.y;
            int r1 = eyL & 0xFFFF;
            unsigned r2u = (unsigned)eyL >> 16;
            float2 sA = *(const float2*)((const char*)pB + (size_t)(unsigned)srcL * (PBS * 2) + 400);
            float2 sr = *(const float2*)(srel2 + r1 * 2);
            float z0 = s1h0 + sA.x + sr.x;
            float z1 = s1h1 + sA.y + sr.y;
            if (r2u != 0xFFFFu) {
                float2 sr2v = *(const float2*)(srel2 + r2u * 2);
                z0 += sr2v.x; z1 += sr2v.y;
            }
            w0 = expf(-(z0 > 0.f ? z0 : 0.2f * z0));
            w1 = expf(-(z1 > 0.f ? z1 : 0.2f * z1));
            rsl0 += w0; rsl1 += w1;
        }
        // ---- phase B: per-edge feature FMA; 4-edge-batched pB loads
        for (int e0 = 0; e0 < cnt; e0 += 4) {
            int ec = min(4, cnt - e0);
            unsigned pw0[4], pw1[4];
#pragma unroll
            for (int u = 0; u < 4; u++) {
                if (u < ec) {
                    int s = __builtin_amdgcn_readlane(srcL, e0 + u);
                    const __hip_bfloat16* rA = pB + (size_t)(unsigned)s * PBS;
                    pw0[u] = *(const unsigned*)(rA + 2 * k0);
                    pw1[u] = *(const unsigned*)(rA + 2 * k1c);
                }
            }
#pragma unroll
            for (int u = 0; u < 4; u++) {
                if (u < ec) {
                    int ey = __builtin_amdgcn_readlane(eyL, e0 + u);
                    int r1 = ey & 0xFFFF;
                    unsigned r2u = (unsigned)ey >> 16;
                    float we0 = readlaneF(w0, e0 + u);
                    float we1 = readlaneF(w1, e0 + u);
                    const float2* q1 = (const float2*)(rpf2 + (unsigned)r1 * 200);
                    float2 q1a = q1[k0], q1b = q1[k1c];
                    float v00 = bfLo(pw0[u]) + q1a.x;
                    float v01 = bfHi(pw0[u]) + q1a.y;
                    float v10 = bfLo(pw1[u]) + q1b.x;
                    float v11 = bfHi(pw1[u]) + q1b.y;
                    if (r2u != 0xFFFFu) {
                        const float2* q2 = (const float2*)(rpf2 + r2u * 200);
                        float2 q2a = q2[k0], q2b = q2[k1c];
                        v00 += q2a.x; v01 += q2a.y;
                        v10 += q2b.x; v11 += q2b.y;
                    }
                    acc0.x += we0 * v00; acc0.y += we1 * v01;
                    acc1.x += we0 * v10; acc1.y += we1 * v11;
                }
            }
        }
    }

    // wave-reduce rowsums (butterfly -> all lanes)
#pragma unroll
    for (int o = 1; o < 64; o <<= 1) {
        rsl0 += __shfl_xor(rsl0, o);
        rsl1 += __shfl_xor(rsl1, o);
    }
    float i0 = rsl0 > 0.f ? 1.f / rsl0 : 0.f;
    float i1 = rsl1 > 0.f ? 1.f / rsl1 : 0.f;
    __hip_bfloat16* xr = x1 + (size_t)n * KP;
    float hp;
    hp = rsl0 > 0.f ? toF(xr[k0]) + acc0.x * i0 : 0.f;
    xr[k0] = __float2bfloat16(hp > 0.f ? hp : expf(hp) - 1.f);
    hp = rsl1 > 0.f ? toF(xr[100 + k0]) + acc0.y * i1 : 0.f;
    xr[100 + k0] = __float2bfloat16(hp > 0.f ? hp : expf(hp) - 1.f);
    if (k1ok) {
        int k1 = lane + 64;
        hp = rsl0 > 0.f ? toF(xr[k1]) + acc1.x * i0 : 0.f;
        xr[k1] = __float2bfloat16(hp > 0.f ? hp : expf(hp) - 1.f);
        hp = rsl1 > 0.f ? toF(xr[100 + k1]) + acc1.y * i1 : 0.f;
        xr[100 + k1] = __float2bfloat16(hp > 0.f ? hp : expf(hp) - 1.f);
    }
}

// -------- layer-2 gather: wave/dst, two-phase; fused +entW + l2norm -------
__global__ __launch_bounds__(256)
void gather_l2_k(const int* __restrict__ start, const int2* __restrict__ csr,
                 const float* __restrict__ s1,
                 const float* __restrict__ srel,          // [R]
                 const __hip_bfloat16* __restrict__ x1A2, // [N][PBS]: feats+s2+entW
                 const float* __restrict__ rpf,           // [R][200]
                 const float* __restrict__ maskf,
                 float* __restrict__ outent, int N)       // [N][200], holds x1A1
{
    int n = (blockIdx.x * blockDim.x + threadIdx.x) >> 6;
    int lane = threadIdx.x & 63;
    if (n >= N) return;
    int b0 = __builtin_amdgcn_readfirstlane(start[n]);
    int b1 = __builtin_amdgcn_readfirstlane(start[n + 1]);
    float s1n = s1[n];
    float rsl = 0.f;
    float2 a0 = {0.f, 0.f};   // k = 2*lane, 2*lane+1
    float2 a1 = {0.f, 0.f};   // k = 128+2*lane, +1 (lane<36)
    int j0 = 2 * lane;
    bool j1ok = lane < 36;
    int j1 = j1ok ? (128 + 2 * lane) : 0;

    for (int c0 = b0; c0 < b1; c0 += 64) {
        int cnt = min(64, b1 - c0);
        // ---- phase A: lane-parallel per-edge scalars
        float w = 0.f;
        int srcL = 0, eyL = 0;
        if (lane < cnt) {
            int2 eg = csr[c0 + lane];
            srcL = eg.x; eyL = eg.y;
            int r1 = eyL & 0xFFFF;
            unsigned r2u = (unsigned)eyL >> 16;
            float s2v = *(const float*)((const char*)x1A2 + (size_t)(unsigned)srcL * (PBS * 2) + 400);
            float sr = srel[r1];
            if (r2u != 0xFFFFu) sr += srel[r2u];
            float z = s1n + s2v + sr;
            w = expf(-(z > 0.f ? z : 0.2f * z));
            rsl += w;
        }
        // ---- phase B: per-edge feature FMA; 4-edge-batched feature loads
        for (int e0 = 0; e0 < cnt; e0 += 4) {
            int ec = min(4, cnt - e0);
            unsigned xw0[4], xw1[4];
#pragma unroll
            for (int u = 0; u < 4; u++) {
                if (u < ec) {
                    int s = __builtin_amdgcn_readlane(srcL, e0 + u);
                    const __hip_bfloat16* xs = x1A2 + (size_t)(unsigned)s * PBS;
                    xw0[u] = *(const unsigned*)(xs + j0);
                    xw1[u] = *(const unsigned*)(xs + j1);
                }
            }
#pragma unroll
            for (int u = 0; u < 4; u++) {
                if (u < ec) {
                    int ey = __builtin_amdgcn_readlane(eyL, e0 + u);
                    int r1 = ey & 0xFFFF;
                    unsigned r2u = (unsigned)ey >> 16;
                    float we = readlaneF(w, e0 + u);
                    const float* q1 = rpf + (unsigned)r1 * 200;
                    float2 q1a = *(const float2*)(q1 + j0);
                    float2 q1b = *(const float2*)(q1 + j1);
                    float v0x = bfLo(xw0[u]) + q1a.x;
                    float v0y = bfHi(xw0[u]) + q1a.y;
                    float v1x = bfLo(xw1[u]) + q1b.x;
                    float v1y = bfHi(xw1[u]) + q1b.y;
                    if (r2u != 0xFFFFu) {
                        const float* q2 = rpf + r2u * 200;
                        float2 q2a = *(const float2*)(q2 + j0);
                        float2 q2b = *(const float2*)(q2 + j1);
                        v0x += q2a.x; v0y += q2a.y;
                        v1x += q2b.x; v1y += q2b.y;
                    }
                    a0.x += we * v0x; a0.y += we * v0y;
                    a1.x += we * v1x; a1.y += we * v1y;
                }
            }
        }
    }

#pragma unroll
    for (int o = 1; o < 64; o <<= 1) rsl += __shfl_xor(rsl, o);
    float inv = rsl > 0.f ? 1.f / rsl : 0.f;
    float mk = maskf[n];
    float* orow = outent + (size_t)n * 200;
    const __hip_bfloat16* ew = x1A2 + (size_t)n * PBS + 224;  // own dst row's entW

    float2 o0 = *(const float2*)(orow + j0);
    unsigned e0b = *(const unsigned*)(ew + j0);
    float h0x = rsl > 0.f ? o0.x + a0.x * inv : 0.f;
    float h0y = rsl > 0.f ? o0.y + a0.y * inv : 0.f;
    float v0x = mk * (h0x > 0.f ? h0x : expf(h0x) - 1.f) + bfLo(e0b);
    float v0y = mk * (h0y > 0.f ? h0y : expf(h0y) - 1.f) + bfHi(e0b);
    float ssq = v0x * v0x + v0y * v0y;
    float v1x = 0.f, v1y = 0.f;
    if (j1ok) {
        float2 o1 = *(const float2*)(orow + j1);
        unsigned e1b = *(const unsigned*)(ew + j1);
        float h1x = rsl > 0.f ? o1.x + a1.x * inv : 0.f;
        float h1y = rsl > 0.f ? o1.y + a1.y * inv : 0.f;
        v1x = mk * (h1x > 0.f ? h1x : expf(h1x) - 1.f) + bfLo(e1b);
        v1y = mk * (h1y > 0.f ? h1y : expf(h1y) - 1.f) + bfHi(e1b);
        ssq += v1x * v1x + v1y * v1y;
    }
#pragma unroll
    for (int o = 1; o < 64; o <<= 1) ssq += __shfl_xor(ssq, o);
    float sc = 1.f / fmaxf(sqrtf(ssq), 1e-12f);
    float2 r0; r0.x = v0x * sc; r0.y = v0y * sc;
    *(float2*)(orow + j0) = r0;
    if (j1ok) {
        float2 r1; r1.x = v1x * sc; r1.y = v1y * sc;
        *(float2*)(orow + j1) = r1;
    }
}

__global__ void scatter_mask_k(const int* __restrict__ batch, int NB,
                               float* __restrict__ masko)
{
    int i = blockIdx.x * blockDim.x + threadIdx.x;
    if (i >= NB) return;
    masko[batch[i]] = 1.0f;
}

extern "C" void kernel_launch(void* const* d_in, const int* in_sizes, int n_in,
                              void* d_out, int out_size, void* d_ws, size_t ws_size,
                              hipStream_t stream)
{
    const float* ent      = (const float*)d_in[0];
    const float* rel      = (const float*)d_in[1];
    const float* W_ent    = (const float*)d_in[2];
    const float* W_gat    = (const float*)d_in[3];
    const float* a_heads  = (const float*)d_in[4];
    const float* a2_heads = (const float*)d_in[5];
    const float* a_out    = (const float*)d_in[6];
    const float* a2_out   = (const float*)d_in[7];
    const int* batch = (const int*)d_in[8];
    const int* el    = (const int*)d_in[9];
    const int* etype = (const int*)d_in[10];
    const int* tin   = (const int*)d_in[11];

    const int N   = in_sizes[0] / DD;   // 50000
    const int R   = in_sizes[1] / DD;   // 500
    const int NB  = in_sizes[8];        // 20000
    const int E   = in_sizes[9] / 2;    // 150000
    const int ENH = in_sizes[11] / 4;   // 30000
    const int Etot = E + ENH;

    // ---- workspace (~70 MB) ----
    char* ws = (char*)d_ws;
    size_t off = 0;
    auto take = [&](size_t bytes) { size_t o = off; off += (bytes + 255) & ~(size_t)255; return o; };
    size_t o_R1   = take((size_t)N * KP * 2);     // x1 bf16 [N][KP]
    size_t o_R2   = take((size_t)N * PBS * 2);    // pB/x1A2 [N][PBS] + s2 + entW
    size_t o_rpf  = take((size_t)2 * R * 100 * 4);// rpf2 [R][100][2] / layer2 rpf [R][200]
    size_t o_bt1  = take((size_t)400 * KP * 2);   // l1 panel (179200 B, 256-mult)
    size_t o_btf  = take((size_t)208 * KP * 2);   // W_ent panel: ADJACENT to bt1
    size_t o_bt2  = take((size_t)400 * KP * 2);
    size_t o_nsc  = take((size_t)N * 4);
    size_t o_s1   = take((size_t)2 * N * 4);      // aliased by cnt during CSR build
    size_t o_srel = take((size_t)2 * R * 4);      // [R][2] layer1 / [R] layer2
    size_t o_csr  = take((size_t)Etot * 8);
    size_t o_str  = take((size_t)(N + 1) * 4);
    size_t o_aux  = take((size_t)64 * 4);

    __hip_bfloat16* x1   = (__hip_bfloat16*)(ws + o_R1);
    __hip_bfloat16* pB   = (__hip_bfloat16*)(ws + o_R2);
    __hip_bfloat16* x1A2 = (__hip_bfloat16*)(ws + o_R2);
    float* rpf2   = (float*)(ws + o_rpf);
    __hip_bfloat16* bt1 = (__hip_bfloat16*)(ws + o_bt1);  // [608][KP] combined w/ btf
    __hip_bfloat16* btf = (__hip_bfloat16*)(ws + o_btf);
    __hip_bfloat16* bt2 = (__hip_bfloat16*)(ws + o_bt2);
    float* nscale = (float*)(ws + o_nsc);
    float* s1     = (float*)(ws + o_s1);
    float* srel2  = (float*)(ws + o_srel);
    int2*  csr    = (int2*)(ws + o_csr);
    int*   cnt    = (int*)(ws + o_s1);   // CSR-build scratch; dead before l1_both_k writes s1
    int*   startA = (int*)(ws + o_str);
    int*   aux    = (int*)(ws + o_aux);

    float* out       = (float*)d_out;
    float* out_ent   = out;                                     // [N,200]
    float* out_rel_o = out + (size_t)N * OD;                    // [500,200]
    float* out_mask  = out + (size_t)N * OD + (size_t)R * OD;   // [N]

    const int nblk = cdiv(N, 64);
    const int nbScan = cdiv(N, 1024);

    // A. prep: norms, B panels (bt1+btf contiguous -> 608-row combined panel)
    rownorm_inv_k<<<cdiv(N, 4), 256, 0, stream>>>(ent, nscale, N, DD);
    prep_bt_l1<<<400, 256, 0, stream>>>(a_heads, bt1);
    prep_bt_fin<<<208, 256, 0, stream>>>(W_ent, btf);
    prep_bt_l2<<<400, 256, 0, stream>>>(a_out, bt2);
    hipMemsetAsync(x1, 0, (size_t)N * KP * 2, stream);
    gemm_mfma_k<false, float, float><<<dim3(cdiv(OD, 64), cdiv(R, 64)), 256, 0, stream>>>(
        rel, DD, nullptr, W_gat, OD, 0, out_rel_o, OD, 1, 0, R, OD, DD);

    // A2. CSR build (dst-grouped edge lists)
    hipMemsetAsync(cnt, 0, (size_t)N * 4, stream);
    hist_k<<<cdiv(Etot, 256), 256, 0, stream>>>(el, E, etype, tin, Etot, cnt);
    scan1_k<<<nbScan, 1024, 0, stream>>>(cnt, startA, aux, N);
    scan2_k<<<1, 64, 0, stream>>>(aux, nbScan);
    scan3_k<<<nbScan, 1024, 0, stream>>>(startA, aux, N, Etot);
    hipMemsetAsync(cnt, 0, (size_t)N * 4, stream);
    fill_k<<<cdiv(Etot, 256), 256, 0, stream>>>(el, E, etype, tin, Etot, startA, cnt, csr);

    // B. layer-1 projections (both heads + entW phase-2) + rel side + gather
    l1_both_k<<<nblk, 256, 0, stream>>>(ent, nscale, bt1, a2_heads, x1, pB, s1, N);
    for (int h = 0; h < 2; h++) {
        const float* ah  = a_heads + (size_t)h * NHID * 600;
        const float* a2h = a2_heads + (size_t)h * NHID;
        gemm_mfma_k<true, float, float><<<dim3(cdiv(NHID, 64), cdiv(R, 64)), 256, 0, stream>>>(
            rel, DD, nullptr, ah, 600, 400, rpf2, 200, 2, h, R, NHID, DD);
        rowdot_k<float><<<cdiv(R, 4), 256, 0, stream>>>(
            rpf2, 200, h, 2, a2h, srel2, 2, h, R, NHID);
    }
    gather_l1_k<<<cdiv(N, 4), 256, 0, stream>>>(
        startA, csr, s1, srel2, pB, rpf2, x1, N);
    // pB feats dead; R2 rows become x1A2 (entW at shorts 224.. survives).

    // C. layer-2 projection + rel side
    l2_proj_k<<<nblk, 256, 0, stream>>>(x1, bt2, a2_out, out_ent, x1A2, s1, N);
    gemm_mfma_k<true, float, float><<<dim3(cdiv(OD, 64), cdiv(R, 64)), 256, 0, stream>>>(
        out_rel_o, OD, nullptr, a_out, 600, 400, rpf2, OD, 1, 0, R, OD, OD);
    rowdot_k<float><<<cdiv(R, 4), 256, 0, stream>>>(rpf2, OD, 0, 1, a2_out, srel2, 1, 0, R, OD);

    // D. mask; layer-2 gather (fused combine + entW + l2norm -> final out_ent)
    hipMemsetAsync(out_mask, 0, (size_t)N * 4, stream);
    scatter_mask_k<<<cdiv(NB, 256), 256, 0, stream>>>(batch, NB, out_mask);
    gather_l2_k<<<cdiv(N, 4), 256, 0, stream>>>(
        startA, csr, s1, srel2, x1A2, rpf2, out_mask, out_ent, N);
}

// Round 9
// 460.521 us; speedup vs baseline: 1.3399x; 1.1029x over previous
//
#include <hip/hip_runtime.h>
#include <hip/hip_bf16.h>
#include <math.h>

// SpKBGAT: N=50000, D=200, R=500, NHID=100, H=2, OD=200, E=150000, ENH=30000.
// R17: R16's serial phase-2 pushed l1_both past the VGPR=128 occupancy cliff
// (136 VGPR -> 3 waves/SIMD, occ 8.7%, 108us). Fix: PARALLEL phases via
// blockIdx.y -- y=0 blocks = 25-tile l1 path (R10's measured 55us shape,
// ~124 VGPR), y=1 blocks = lean 13-tile entW path (52-VGPR acc). Co-resident
// block types fill each other's latency bubbles; kernel VGPR = max(paths)<=128.
#define DD   200
#define NHID 100
#define OD   200
#define KP   224   // padded K (7 chunks of 32)
#define PBS  448   // row stride (bf16) for pB / x1A2 / entW: 896 B
                   // [0..199]: pB [k][h0,h1] pairs (l1) / x1A2 feats (l2)
                   // bytes 400..407: s2 floats;  shorts [224..423]: entW bf16
#define LDSW 40    // LDS row stride in shorts (80 B)

typedef __attribute__((ext_vector_type(8))) short short8;
typedef __attribute__((ext_vector_type(4))) float f32x4;

static inline int cdiv(int a, int b) { return (a + b - 1) / b; }

__device__ inline float toF(float x) { return x; }
__device__ inline float toF(__hip_bfloat16 x) { return __bfloat162float(x); }
__device__ inline void storeC(float v, float* p) { *p = v; }
__device__ inline void storeC(float v, __hip_bfloat16* p) { *p = __float2bfloat16(v); }
__device__ inline short bf16s(float f) {
    __hip_bfloat16 h = __float2bfloat16(f);
    short s; __builtin_memcpy(&s, &h, 2); return s;
}
__device__ inline float bfLo(unsigned u) { return __uint_as_float(u << 16); }
__device__ inline float bfHi(unsigned u) { return __uint_as_float(u & 0xFFFF0000u); }
__device__ inline float readlaneF(float v, int l) {
    return __uint_as_float((unsigned)__builtin_amdgcn_readlane((int)__float_as_uint(v), l));
}

// -------- per-row inverse L2 norm (f32), wave per row --------
__global__ __launch_bounds__(256)
void rownorm_inv_k(const float* __restrict__ in, float* __restrict__ sc, int M, int Dd)
{
    int wave = (blockIdx.x * blockDim.x + threadIdx.x) >> 6;
    int lane = threadIdx.x & 63;
    if (wave >= M) return;
    float ss = 0.f;
    for (int k = lane; k < Dd; k += 64) {
        float x = in[(size_t)wave * Dd + k];
        ss += x * x;
    }
    for (int o = 32; o > 0; o >>= 1) ss += __shfl_down(ss, o);
    if (lane == 0) sc[wave] = 1.f / fmaxf(sqrtf(ss), 1e-12f);
}

// -------- B-panel prep: bf16 [col][KP], zero-padded --------
__global__ void prep_bt_l1(const float* __restrict__ ah, __hip_bfloat16* __restrict__ Bt)
{
    int c = blockIdx.x, k = threadIdx.x;
    if (k >= KP) return;
    int seg = c / 100, idx = c - seg * 100;
    int h = seg & 1, off = (seg >> 1) * 200;
    float v = (k < 200) ? ah[(size_t)(h * 100 + idx) * 600 + off + k] : 0.f;
    Bt[(size_t)c * KP + k] = __float2bfloat16(v);
}
__global__ void prep_bt_l2(const float* __restrict__ ao, __hip_bfloat16* __restrict__ Bt)
{
    int c = blockIdx.x, k = threadIdx.x;
    if (k >= KP) return;
    int row = (c < 200) ? c : c - 200;
    int off = (c < 200) ? 0 : 200;
    float v = (k < 200) ? ao[(size_t)row * 600 + off + k] : 0.f;
    Bt[(size_t)c * KP + k] = __float2bfloat16(v);
}
__global__ void prep_bt_fin(const float* __restrict__ W, __hip_bfloat16* __restrict__ Bt)
{
    int c = blockIdx.x, k = threadIdx.x;
    if (k >= KP) return;
    float v = (c < 200 && k < 200) ? W[(size_t)k * 200 + c] : 0.f;
    Bt[(size_t)c * KP + k] = __float2bfloat16(v);
}

// -------- layer-1 fused: y=0 -> 25 l1 tiles; y=1 -> 13 entW tiles ---------
__global__ __launch_bounds__(256)
void l1_both_k(const float* __restrict__ ent, const float* __restrict__ nscale,
               const __hip_bfloat16* __restrict__ Bt,  // [608][KP] (l1 400 + W_ent 208)
               const float* __restrict__ a2h,          // [2][100]
               __hip_bfloat16* __restrict__ x1,        // [N][KP] (cols 0-199)
               __hip_bfloat16* __restrict__ pB,        // [N][PBS]: pB + s2 + entW
               float* __restrict__ s1,                 // [2][N]
               int M)
{
    __shared__ __align__(16) __hip_bfloat16 Bs[400 * LDSW];  // 32 KB
    int tid = threadIdx.x, wave = tid >> 6, lane = tid & 63;
    int quad = lane >> 4, l16 = lane & 15;
    int m0 = blockIdx.x * 64;
    int arow = m0 + wave * 16 + l16;
    bool rok = arow < M;
    float nsc = rok ? nscale[arow] : 0.f;
    const float* arp = ent + (size_t)arow * DD;
    int orow = m0 + wave * 16 + quad * 4;

    if (blockIdx.y == 0) {
        // ---- 25-tile l1 path (R10-measured pipeline) ----
        f32x4 acc[25];
#pragma unroll
        for (int t = 0; t < 25; t++) acc[t] = (f32x4){0.f, 0.f, 0.f, 0.f};

        short8 stg[7];
#pragma unroll
        for (int i = 0; i < 7; i++) {
            int idx = tid + i * 256;
            if (idx < 1600) {
                int r = idx >> 2, c8 = idx & 3;
                stg[i] = *(const short8*)(Bt + (size_t)r * KP + c8 * 8);
            }
        }
        for (int ch = 0; ch < 7; ch++) {
#pragma unroll
            for (int i = 0; i < 7; i++) {
                int idx = tid + i * 256;
                if (idx < 1600) {
                    int r = idx >> 2, c8 = idx & 3;
                    *(short8*)(Bs + r * LDSW + c8 * 8) = stg[i];
                }
            }
            __syncthreads();
            if (ch < 6) {
                int kb2 = (ch + 1) * 32;
#pragma unroll
                for (int i = 0; i < 7; i++) {
                    int idx = tid + i * 256;
                    if (idx < 1600) {
                        int r = idx >> 2, c8 = idx & 3;
                        stg[i] = *(const short8*)(Bt + (size_t)r * KP + kb2 + c8 * 8);
                    }
                }
            }
            int kb = ch * 32 + quad * 8;
            float av[8];
            if (rok && kb + 8 <= DD) {
                const float4* p = (const float4*)(arp + kb);
                float4 u0 = p[0], u1 = p[1];
                av[0] = u0.x; av[1] = u0.y; av[2] = u0.z; av[3] = u0.w;
                av[4] = u1.x; av[5] = u1.y; av[6] = u1.z; av[7] = u1.w;
            } else {
#pragma unroll
                for (int j = 0; j < 8; j++) av[j] = (rok && kb + j < DD) ? arp[kb + j] : 0.f;
            }
            short8 a;
#pragma unroll
            for (int j = 0; j < 8; j++) a[j] = bf16s(av[j] * nsc);
            const __hip_bfloat16* bp = Bs + (size_t)l16 * LDSW + quad * 8;
#pragma unroll
            for (int t = 0; t < 25; t++) {
                short8 b = *(const short8*)(bp + (size_t)t * 16 * LDSW);
                acc[t] = __builtin_amdgcn_mfma_f32_16x16x32_bf16(a, b, acc[t], 0, 0, 0);
            }
            __syncthreads();
        }

        float d0[4] = {0,0,0,0}, d1[4] = {0,0,0,0}, d2[4] = {0,0,0,0}, d3[4] = {0,0,0,0};
#pragma unroll
        for (int t = 0; t < 25; t++) {
            int c = t * 16 + l16;
            int seg = c / 100, idx = c - seg * 100;
            float w = a2h[(seg & 1) * 100 + idx];
#pragma unroll
            for (int i = 0; i < 4; i++) {
                float v = acc[t][i];
                float vw = v * w;
                if (seg == 0) d0[i] += vw;
                else if (seg == 1) d1[i] += vw;
                else if (seg == 2) d2[i] += vw;
                else d3[i] += vw;
                int gm = orow + i;
                if (gm < M) {
                    if (seg < 2) x1[(size_t)gm * KP + c] = __float2bfloat16(v);
                    else pB[(size_t)gm * PBS + idx * 2 + (seg - 2)] = __float2bfloat16(v);
                }
            }
        }
#pragma unroll
        for (int msk = 1; msk < 16; msk <<= 1)
#pragma unroll
            for (int i = 0; i < 4; i++) {
                d0[i] += __shfl_xor(d0[i], msk);
                d1[i] += __shfl_xor(d1[i], msk);
                d2[i] += __shfl_xor(d2[i], msk);
                d3[i] += __shfl_xor(d3[i], msk);
            }
        if (l16 == 0)
#pragma unroll
            for (int i = 0; i < 4; i++) {
                int gm = orow + i;
                if (gm < M) {
                    s1[gm] = d0[i]; s1[M + gm] = d1[i];
                    float2 sv; sv.x = d2[i]; sv.y = d3[i];
                    *(float2*)((char*)pB + (size_t)gm * (PBS * 2) + 400) = sv;
                }
            }
    } else {
        // ---- 13-tile entW path (lean: acc2[13], 16.6KB of the LDS buffer) ----
        f32x4 acc2[13];
#pragma unroll
        for (int t = 0; t < 13; t++) acc2[t] = (f32x4){0.f, 0.f, 0.f, 0.f};

        short8 stg2[4];
#pragma unroll
        for (int i = 0; i < 4; i++) {
            int idx = tid + i * 256;
            if (idx < 832) {
                int r = idx >> 2, c8 = idx & 3;
                stg2[i] = *(const short8*)(Bt + (size_t)(400 + r) * KP + c8 * 8);
            }
        }
        for (int ch = 0; ch < 7; ch++) {
#pragma unroll
            for (int i = 0; i < 4; i++) {
                int idx = tid + i * 256;
                if (idx < 832) {
                    int r = idx >> 2, c8 = idx & 3;
                    *(short8*)(Bs + r * LDSW + c8 * 8) = stg2[i];
                }
            }
            __syncthreads();
            if (ch < 6) {
                int kb2 = (ch + 1) * 32;
#pragma unroll
                for (int i = 0; i < 4; i++) {
                    int idx = tid + i * 256;
                    if (idx < 832) {
                        int r = idx >> 2, c8 = idx & 3;
                        stg2[i] = *(const short8*)(Bt + (size_t)(400 + r) * KP + kb2 + c8 * 8);
                    }
                }
            }
            int kb = ch * 32 + quad * 8;
            float av[8];
            if (rok && kb + 8 <= DD) {
                const float4* p = (const float4*)(arp + kb);
                float4 u0 = p[0], u1 = p[1];
                av[0] = u0.x; av[1] = u0.y; av[2] = u0.z; av[3] = u0.w;
                av[4] = u1.x; av[5] = u1.y; av[6] = u1.z; av[7] = u1.w;
            } else {
#pragma unroll
                for (int j = 0; j < 8; j++) av[j] = (rok && kb + j < DD) ? arp[kb + j] : 0.f;
            }
            short8 a;
#pragma unroll
            for (int j = 0; j < 8; j++) a[j] = bf16s(av[j] * nsc);
            const __hip_bfloat16* bp = Bs + (size_t)l16 * LDSW + quad * 8;
#pragma unroll
            for (int t = 0; t < 13; t++) {
                short8 b = *(const short8*)(bp + (size_t)t * 16 * LDSW);
                acc2[t] = __builtin_amdgcn_mfma_f32_16x16x32_bf16(a, b, acc2[t], 0, 0, 0);
            }
            __syncthreads();
        }
#pragma unroll
        for (int t = 0; t < 13; t++) {
            int c2 = t * 16 + l16;
#pragma unroll
            for (int i = 0; i < 4; i++) {
                int gm = orow + i;
                if (c2 < OD && gm < M)
                    pB[(size_t)gm * PBS + 224 + c2] = __float2bfloat16(acc2[t][i]);
            }
        }
    }
}

// -------- layer-2 fused: 25 tiles = x1A1 (f32 -> out_ent) | x1A2 (bf16) ----
__global__ __launch_bounds__(256)
void l2_proj_k(const __hip_bfloat16* __restrict__ x1,  // [N][KP]
               const __hip_bfloat16* __restrict__ Bt,  // [400][KP]
               const float* __restrict__ a2o,          // [200]
               float* __restrict__ x1A1,               // [N][200] (out_ent)
               __hip_bfloat16* __restrict__ x1A2,      // [N][PBS], s2 in pad
               float* __restrict__ s1, int M)
{
    __shared__ __align__(16) __hip_bfloat16 Bs[400 * LDSW];  // 32 KB
    int tid = threadIdx.x, wave = tid >> 6, lane = tid & 63;
    int quad = lane >> 4, l16 = lane & 15;
    int m0 = blockIdx.x * 64;
    int arow = m0 + wave * 16 + l16;
    bool rok = arow < M;
    const __hip_bfloat16* arp = x1 + (size_t)arow * KP;

    f32x4 acc[25];
#pragma unroll
    for (int t = 0; t < 25; t++) acc[t] = (f32x4){0.f, 0.f, 0.f, 0.f};

    short8 stg[7];
#pragma unroll
    for (int i = 0; i < 7; i++) {
        int idx = tid + i * 256;
        if (idx < 1600) {
            int r = idx >> 2, c8 = idx & 3;
            stg[i] = *(const short8*)(Bt + (size_t)r * KP + c8 * 8);
        }
    }

    for (int ch = 0; ch < 7; ch++) {
#pragma unroll
        for (int i = 0; i < 7; i++) {
            int idx = tid + i * 256;
            if (idx < 1600) {
                int r = idx >> 2, c8 = idx & 3;
                *(short8*)(Bs + r * LDSW + c8 * 8) = stg[i];
            }
        }
        __syncthreads();
        if (ch < 6) {
            int kb2 = (ch + 1) * 32;
#pragma unroll
            for (int i = 0; i < 7; i++) {
                int idx = tid + i * 256;
                if (idx < 1600) {
                    int r = idx >> 2, c8 = idx & 3;
                    stg[i] = *(const short8*)(Bt + (size_t)r * KP + kb2 + c8 * 8);
                }
            }
        }
        int kb = ch * 32 + quad * 8;
        short8 a = (short8){0,0,0,0,0,0,0,0};
        if (rok) a = *(const short8*)(arp + kb);
        const __hip_bfloat16* bp = Bs + (size_t)l16 * LDSW + quad * 8;
#pragma unroll
        for (int t = 0; t < 25; t++) {
            short8 b = *(const short8*)(bp + (size_t)t * 16 * LDSW);
            acc[t] = __builtin_amdgcn_mfma_f32_16x16x32_bf16(a, b, acc[t], 0, 0, 0);
        }
        __syncthreads();
    }

    int orow = m0 + wave * 16 + quad * 4;
    float dA[4] = {0,0,0,0}, dB[4] = {0,0,0,0};
#pragma unroll
    for (int t = 0; t < 25; t++) {
        int c = t * 16 + l16;
        bool first = c < 200;
        int cc = first ? c : c - 200;
        float w = a2o[cc];
#pragma unroll
        for (int i = 0; i < 4; i++) {
            float v = acc[t][i];
            int gm = orow + i;
            if (first) {
                dA[i] += v * w;
                if (gm < M) x1A1[(size_t)gm * OD + c] = v;
            } else {
                dB[i] += v * w;
                if (gm < M) x1A2[(size_t)gm * PBS + cc] = __float2bfloat16(v);
            }
        }
    }
#pragma unroll
    for (int msk = 1; msk < 16; msk <<= 1)
#pragma unroll
        for (int i = 0; i < 4; i++) {
            dA[i] += __shfl_xor(dA[i], msk);
            dB[i] += __shfl_xor(dB[i], msk);
        }
    if (l16 == 0)
#pragma unroll
        for (int i = 0; i < 4; i++) {
            int gm = orow + i;
            if (gm < M) {
                s1[gm] = dA[i];
                *(float*)((char*)x1A2 + (size_t)gm * (PBS * 2) + 400) = dB[i];
            }
        }
}

// -------- generic MFMA GEMM (small R-sized matmuls); cs/co = C col-stride --
#define KPAD 48
template<bool BTr, typename AT, typename CT>
__global__ __launch_bounds__(256)
void gemm_mfma_k(const AT* __restrict__ A, int lda, const float* __restrict__ ascale,
                 const float* __restrict__ B, int ldb, int colOff,
                 CT* __restrict__ C, int ldc, int cs, int co,
                 int M, int Nc, int K)
{
    __shared__ __align__(16) __hip_bfloat16 As[64][KPAD];
    __shared__ __align__(16) __hip_bfloat16 Bs[64][KPAD];
    int tid  = threadIdx.x;
    int wave = tid >> 6, lane = tid & 63;
    int quad = lane >> 4, l16 = lane & 15;
    int n0 = blockIdx.x * 64, m0 = blockIdx.y * 64;
    f32x4 acc[4];
#pragma unroll
    for (int t = 0; t < 4; t++) acc[t] = (f32x4){0.f, 0.f, 0.f, 0.f};

    for (int k0 = 0; k0 < K; k0 += 32) {
        {
            int m = tid >> 2, kc = (tid & 3) * 8;
            int gm = m0 + m;
            float scale = (ascale && gm < M) ? ascale[gm] : 1.f;
#pragma unroll
            for (int j = 0; j < 8; j++) {
                int gk = k0 + kc + j;
                float v = 0.f;
                if (gm < M && gk < K) v = toF(A[(size_t)gm * lda + gk]) * scale;
                As[m][kc + j] = __float2bfloat16(v);
            }
        }
        if (BTr) {
            int n = tid >> 2, kc = (tid & 3) * 8;
            int gn = n0 + n;
#pragma unroll
            for (int j = 0; j < 8; j++) {
                int gk = k0 + kc + j;
                float v = 0.f;
                if (gn < Nc && gk < K) v = B[(size_t)gn * ldb + colOff + gk];
                Bs[n][kc + j] = __float2bfloat16(v);
            }
        } else {
            int n = tid & 63, kq = tid >> 6;
            int gn = n0 + n;
#pragma unroll
            for (int j = 0; j < 8; j++) {
                int gk = k0 + kq * 8 + j;
                float v = 0.f;
                if (gn < Nc && gk < K) v = B[(size_t)gk * ldb + gn];
                Bs[n][kq * 8 + j] = __float2bfloat16(v);
            }
        }
        __syncthreads();
        short8 a = *(const short8*)&As[wave * 16 + l16][quad * 8];
#pragma unroll
        for (int t = 0; t < 4; t++) {
            short8 b = *(const short8*)&Bs[t * 16 + l16][quad * 8];
            acc[t] = __builtin_amdgcn_mfma_f32_16x16x32_bf16(a, b, acc[t], 0, 0, 0);
        }
        __syncthreads();
    }
#pragma unroll
    for (int t = 0; t < 4; t++) {
        int gn = n0 + t * 16 + l16;
        if (gn >= Nc) continue;
#pragma unroll
        for (int i = 0; i < 4; i++) {
            int gm = m0 + wave * 16 + quad * 4 + i;
            if (gm < M) storeC(acc[t][i], &C[(size_t)gm * ldc + (size_t)gn * cs + co]);
        }
    }
}

// -------- row-dot (srel); ks = k-stride in mat, os/oo = output stride ------
template<typename T>
__global__ __launch_bounds__(256)
void rowdot_k(const T* __restrict__ mat, int ld, int coff, int ks,
              const float* __restrict__ vec,
              float* __restrict__ outp, int os, int oo, int M, int Dd)
{
    int wave = (blockIdx.x * blockDim.x + threadIdx.x) >> 6;
    int lane = threadIdx.x & 63;
    if (wave >= M) return;
    float s = 0.f;
    for (int k = lane; k < Dd; k += 64)
        s += toF(mat[(size_t)wave * ld + coff + (size_t)k * ks]) * vec[k];
    for (int o = 32; o > 0; o >>= 1) s += __shfl_down(s, o);
    if (lane == 0) outp[wave * os + oo] = s;
}

// -------- CSR build --------
__device__ inline void decode_edge(const int* __restrict__ el, int E,
                                   const int* __restrict__ etype,
                                   const int* __restrict__ tin, int e,
                                   int& dst, int& src, int& r1, int& r2)
{
    if (e < E) { dst = el[e]; src = el[E + e]; r1 = etype[e]; r2 = -1; }
    else {
        int j = e - E;
        dst = tin[j * 4 + 3]; src = tin[j * 4 + 0];
        r1 = tin[j * 4 + 1];  r2 = tin[j * 4 + 2];
    }
}

__global__ void hist_k(const int* __restrict__ el, int E, const int* __restrict__ etype,
                       const int* __restrict__ tin, int Etot, int* __restrict__ cnt)
{
    int e = blockIdx.x * blockDim.x + threadIdx.x;
    if (e >= Etot) return;
    int dst, src, r1, r2; decode_edge(el, E, etype, tin, e, dst, src, r1, r2);
    atomicAdd(&cnt[dst], 1);
}

__global__ __launch_bounds__(1024)
void scan1_k(const int* __restrict__ cnt, int* __restrict__ start,
             int* __restrict__ aux, int n)
{
    __shared__ int tmp[1024];
    int i = blockIdx.x * 1024 + threadIdx.x;
    int v = (i < n) ? cnt[i] : 0;
    tmp[threadIdx.x] = v;
    __syncthreads();
    for (int o = 1; o < 1024; o <<= 1) {
        int t = (threadIdx.x >= (unsigned)o) ? tmp[threadIdx.x - o] : 0;
        __syncthreads();
        tmp[threadIdx.x] += t;
        __syncthreads();
    }
    if (i < n) start[i] = tmp[threadIdx.x] - v;
    if (threadIdx.x == 1023) aux[blockIdx.x] = tmp[1023];
}

__global__ void scan2_k(int* __restrict__ aux, int nb)
{
    if (threadIdx.x == 0 && blockIdx.x == 0) {
        int s = 0;
        for (int i = 0; i < nb; i++) { int v = aux[i]; aux[i] = s; s += v; }
    }
}

__global__ __launch_bounds__(1024)
void scan3_k(int* __restrict__ start, const int* __restrict__ aux, int n, int Etot)
{
    int i = blockIdx.x * 1024 + threadIdx.x;
    if (i < n) start[i] += aux[blockIdx.x];
    if (i == 0) start[n] = Etot;
}

// csr entry: .x = src, .y = r1 | (r2s<<16), r2s==0xFFFF means "no r2"
__global__ void fill_k(const int* __restrict__ el, int E, const int* __restrict__ etype,
                       const int* __restrict__ tin, int Etot,
                       const int* __restrict__ start, int* __restrict__ fill,
                       int2* __restrict__ csr)
{
    int e = blockIdx.x * blockDim.x + threadIdx.x;
    if (e >= Etot) return;
    int dst, src, r1, r2; decode_edge(el, E, etype, tin, e, dst, src, r1, r2);
    int p = start[dst] + atomicAdd(&fill[dst], 1);
    unsigned r2s = (r2 >= 0) ? (unsigned)r2 : 0xFFFFu;
    csr[p] = make_int2(src, (int)((r2s << 16) | (unsigned)r1));
}

// -------- layer-1 gather: wave/dst, two-phase (lane-parallel scalars) ------
__global__ __launch_bounds__(256)
void gather_l1_k(const int* __restrict__ start, const int2* __restrict__ csr,
                 const float* __restrict__ s1,        // [2][N] dst-side
                 const float* __restrict__ srel2,     // [R][2]
                 const __hip_bfloat16* __restrict__ pB,   // [N][PBS] interleaved
                 const float* __restrict__ rpf2,      // [R][100][2]
                 __hip_bfloat16* __restrict__ x1, int N)  // [N][KP]
{
    int n = (blockIdx.x * blockDim.x + threadIdx.x) >> 6;
    int lane = threadIdx.x & 63;
    if (n >= N) return;
    int b0 = __builtin_amdgcn_readfirstlane(start[n]);
    int b1 = __builtin_amdgcn_readfirstlane(start[n + 1]);
    float s1h0 = s1[n], s1h1 = s1[N + n];
    float rsl0 = 0.f, rsl1 = 0.f;        // per-lane partial rowsums
    float2 acc0 = {0.f, 0.f};            // k0: (h0, h1)
    float2 acc1 = {0.f, 0.f};            // k1
    int k0 = lane;
    bool k1ok = lane < 36;
    int k1c = k1ok ? (lane + 64) : 0;

    for (int c0 = b0; c0 < b1; c0 += 64) {
        int cnt = min(64, b1 - c0);
        // ---- phase A: lane e computes edge (c0+e)'s scalars; all loads in flight
        float w0 = 0.f, w1 = 0.f;
        int srcL = 0, eyL = 0;
        if (lane < cnt) {
            int2 eg = csr[c0 + lane];
            srcL = eg.x; eyL = eg.y;
            int r1 = eyL & 0xFFFF;
            unsigned r2u = (unsigned)eyL >> 16;
            float2 sA = *(const float2*)((const char*)pB + (size_t)(unsigned)srcL * (PBS * 2) + 400);
            float2 sr = *(const float2*)(srel2 + r1 * 2);
            float z0 = s1h0 + sA.x + sr.x;
            float z1 = s1h1 + sA.y + sr.y;
            if (r2u != 0xFFFFu) {
                float2 sr2v = *(const float2*)(srel2 + r2u * 2);
                z0 += sr2v.x; z1 += sr2v.y;
            }
            w0 = expf(-(z0 > 0.f ? z0 : 0.2f * z0));
            w1 = expf(-(z1 > 0.f ? z1 : 0.2f * z1));
            rsl0 += w0; rsl1 += w1;
        }
        // ---- phase B: per-edge feature FMA; 4-edge-batched pB loads
        for (int e0 = 0; e0 < cnt; e0 += 4) {
            int ec = min(4, cnt - e0);
            unsigned pw0[4], pw1[4];
#pragma unroll
            for (int u = 0; u < 4; u++) {
                if (u < ec) {
                    int s = __builtin_amdgcn_readlane(srcL, e0 + u);
                    const __hip_bfloat16* rA = pB + (size_t)(unsigned)s * PBS;
                    pw0[u] = *(const unsigned*)(rA + 2 * k0);
                    pw1[u] = *(const unsigned*)(rA + 2 * k1c);
                }
            }
#pragma unroll
            for (int u = 0; u < 4; u++) {
                if (u < ec) {
                    int ey = __builtin_amdgcn_readlane(eyL, e0 + u);
                    int r1 = ey & 0xFFFF;
                    unsigned r2u = (unsigned)ey >> 16;
                    float we0 = readlaneF(w0, e0 + u);
                    float we1 = readlaneF(w1, e0 + u);
                    const float2* q1 = (const float2*)(rpf2 + (unsigned)r1 * 200);
                    float2 q1a = q1[k0], q1b = q1[k1c];
                    float v00 = bfLo(pw0[u]) + q1a.x;
                    float v01 = bfHi(pw0[u]) + q1a.y;
                    float v10 = bfLo(pw1[u]) + q1b.x;
                    float v11 = bfHi(pw1[u]) + q1b.y;
                    if (r2u != 0xFFFFu) {
                        const float2* q2 = (const float2*)(rpf2 + r2u * 200);
                        float2 q2a = q2[k0], q2b = q2[k1c];
                        v00 += q2a.x; v01 += q2a.y;
                        v10 += q2b.x; v11 += q2b.y;
                    }
                    acc0.x += we0 * v00; acc0.y += we1 * v01;
                    acc1.x += we0 * v10; acc1.y += we1 * v11;
                }
            }
        }
    }

    // wave-reduce rowsums (butterfly -> all lanes)
#pragma unroll
    for (int o = 1; o < 64; o <<= 1) {
        rsl0 += __shfl_xor(rsl0, o);
        rsl1 += __shfl_xor(rsl1, o);
    }
    float i0 = rsl0 > 0.f ? 1.f / rsl0 : 0.f;
    float i1 = rsl1 > 0.f ? 1.f / rsl1 : 0.f;
    __hip_bfloat16* xr = x1 + (size_t)n * KP;
    float hp;
    hp = rsl0 > 0.f ? toF(xr[k0]) + acc0.x * i0 : 0.f;
    xr[k0] = __float2bfloat16(hp > 0.f ? hp : expf(hp) - 1.f);
    hp = rsl1 > 0.f ? toF(xr[100 + k0]) + acc0.y * i1 : 0.f;
    xr[100 + k0] = __float2bfloat16(hp > 0.f ? hp : expf(hp) - 1.f);
    if (k1ok) {
        int k1 = lane + 64;
        hp = rsl0 > 0.f ? toF(xr[k1]) + acc1.x * i0 : 0.f;
        xr[k1] = __float2bfloat16(hp > 0.f ? hp : expf(hp) - 1.f);
        hp = rsl1 > 0.f ? toF(xr[100 + k1]) + acc1.y * i1 : 0.f;
        xr[100 + k1] = __float2bfloat16(hp > 0.f ? hp : expf(hp) - 1.f);
    }
}

// -------- layer-2 gather: wave/dst, two-phase; fused +entW + l2norm -------
__global__ __launch_bounds__(256)
void gather_l2_k(const int* __restrict__ start, const int2* __restrict__ csr,
                 const float* __restrict__ s1,
                 const float* __restrict__ srel,          // [R]
                 const __hip_bfloat16* __restrict__ x1A2, // [N][PBS]: feats+s2+entW
                 const float* __restrict__ rpf,           // [R][200]
                 const float* __restrict__ maskf,
                 float* __restrict__ outent, int N)       // [N][200], holds x1A1
{
    int n = (blockIdx.x * blockDim.x + threadIdx.x) >> 6;
    int lane = threadIdx.x & 63;
    if (n >= N) return;
    int b0 = __builtin_amdgcn_readfirstlane(start[n]);
    int b1 = __builtin_amdgcn_readfirstlane(start[n + 1]);
    float s1n = s1[n];
    float rsl = 0.f;
    float2 a0 = {0.f, 0.f};   // k = 2*lane, 2*lane+1
    float2 a1 = {0.f, 0.f};   // k = 128+2*lane, +1 (lane<36)
    int j0 = 2 * lane;
    bool j1ok = lane < 36;
    int j1 = j1ok ? (128 + 2 * lane) : 0;

    for (int c0 = b0; c0 < b1; c0 += 64) {
        int cnt = min(64, b1 - c0);
        // ---- phase A: lane-parallel per-edge scalars
        float w = 0.f;
        int srcL = 0, eyL = 0;
        if (lane < cnt) {
            int2 eg = csr[c0 + lane];
            srcL = eg.x; eyL = eg.y;
            int r1 = eyL & 0xFFFF;
            unsigned r2u = (unsigned)eyL >> 16;
            float s2v = *(const float*)((const char*)x1A2 + (size_t)(unsigned)srcL * (PBS * 2) + 400);
            float sr = srel[r1];
            if (r2u != 0xFFFFu) sr += srel[r2u];
            float z = s1n + s2v + sr;
            w = expf(-(z > 0.f ? z : 0.2f * z));
            rsl += w;
        }
        // ---- phase B: per-edge feature FMA; 4-edge-batched feature loads
        for (int e0 = 0; e0 < cnt; e0 += 4) {
            int ec = min(4, cnt - e0);
            unsigned xw0[4], xw1[4];
#pragma unroll
            for (int u = 0; u < 4; u++) {
                if (u < ec) {
                    int s = __builtin_amdgcn_readlane(srcL, e0 + u);
                    const __hip_bfloat16* xs = x1A2 + (size_t)(unsigned)s * PBS;
                    xw0[u] = *(const unsigned*)(xs + j0);
                    xw1[u] = *(const unsigned*)(xs + j1);
                }
            }
#pragma unroll
            for (int u = 0; u < 4; u++) {
                if (u < ec) {
                    int ey = __builtin_amdgcn_readlane(eyL, e0 + u);
                    int r1 = ey & 0xFFFF;
                    unsigned r2u = (unsigned)ey >> 16;
                    float we = readlaneF(w, e0 + u);
                    const float* q1 = rpf + (unsigned)r1 * 200;
                    float2 q1a = *(const float2*)(q1 + j0);
                    float2 q1b = *(const float2*)(q1 + j1);
                    float v0x = bfLo(xw0[u]) + q1a.x;
                    float v0y = bfHi(xw0[u]) + q1a.y;
                    float v1x = bfLo(xw1[u]) + q1b.x;
                    float v1y = bfHi(xw1[u]) + q1b.y;
                    if (r2u != 0xFFFFu) {
                        const float* q2 = rpf + r2u * 200;
                        float2 q2a = *(const float2*)(q2 + j0);
                        float2 q2b = *(const float2*)(q2 + j1);
                        v0x += q2a.x; v0y += q2a.y;
                        v1x += q2b.x; v1y += q2b.y;
                    }
                    a0.x += we * v0x; a0.y += we * v0y;
                    a1.x += we * v1x; a1.y += we * v1y;
                }
            }
        }
    }

#pragma unroll
    for (int o = 1; o < 64; o <<= 1) rsl += __shfl_xor(rsl, o);
    float inv = rsl > 0.f ? 1.f / rsl : 0.f;
    float mk = maskf[n];
    float* orow = outent + (size_t)n * 200;
    const __hip_bfloat16* ew = x1A2 + (size_t)n * PBS + 224;  // own dst row's entW

    float2 o0 = *(const float2*)(orow + j0);
    unsigned e0b = *(const unsigned*)(ew + j0);
    float h0x = rsl > 0.f ? o0.x + a0.x * inv : 0.f;
    float h0y = rsl > 0.f ? o0.y + a0.y * inv : 0.f;
    float v0x = mk * (h0x > 0.f ? h0x : expf(h0x) - 1.f) + bfLo(e0b);
    float v0y = mk * (h0y > 0.f ? h0y : expf(h0y) - 1.f) + bfHi(e0b);
    float ssq = v0x * v0x + v0y * v0y;
    float v1x = 0.f, v1y = 0.f;
    if (j1ok) {
        float2 o1 = *(const float2*)(orow + j1);
        unsigned e1b = *(const unsigned*)(ew + j1);
        float h1x = rsl > 0.f ? o1.x + a1.x * inv : 0.f;
        float h1y = rsl > 0.f ? o1.y + a1.y * inv : 0.f;
        v1x = mk * (h1x > 0.f ? h1x : expf(h1x) - 1.f) + bfLo(e1b);
        v1y = mk * (h1y > 0.f ? h1y : expf(h1y) - 1.f) + bfHi(e1b);
        ssq += v1x * v1x + v1y * v1y;
    }
#pragma unroll
    for (int o = 1; o < 64; o <<= 1) ssq += __shfl_xor(ssq, o);
    float sc = 1.f / fmaxf(sqrtf(ssq), 1e-12f);
    float2 r0; r0.x = v0x * sc; r0.y = v0y * sc;
    *(float2*)(orow + j0) = r0;
    if (j1ok) {
        float2 r1; r1.x = v1x * sc; r1.y = v1y * sc;
        *(float2*)(orow + j1) = r1;
    }
}

__global__ void scatter_mask_k(const int* __restrict__ batch, int NB,
                               float* __restrict__ masko)
{
    int i = blockIdx.x * blockDim.x + threadIdx.x;
    if (i >= NB) return;
    masko[batch[i]] = 1.0f;
}

extern "C" void kernel_launch(void* const* d_in, const int* in_sizes, int n_in,
                              void* d_out, int out_size, void* d_ws, size_t ws_size,
                              hipStream_t stream)
{
    const float* ent      = (const float*)d_in[0];
    const float* rel      = (const float*)d_in[1];
    const float* W_ent    = (const float*)d_in[2];
    const float* W_gat    = (const float*)d_in[3];
    const float* a_heads  = (const float*)d_in[4];
    const float* a2_heads = (const float*)d_in[5];
    const float* a_out    = (const float*)d_in[6];
    const float* a2_out   = (const float*)d_in[7];
    const int* batch = (const int*)d_in[8];
    const int* el    = (const int*)d_in[9];
    const int* etype = (const int*)d_in[10];
    const int* tin   = (const int*)d_in[11];

    const int N   = in_sizes[0] / DD;   // 50000
    const int R   = in_sizes[1] / DD;   // 500
    const int NB  = in_sizes[8];        // 20000
    const int E   = in_sizes[9] / 2;    // 150000
    const int ENH = in_sizes[11] / 4;   // 30000
    const int Etot = E + ENH;

    // ---- workspace (~70 MB) ----
    char* ws = (char*)d_ws;
    size_t off = 0;
    auto take = [&](size_t bytes) { size_t o = off; off += (bytes + 255) & ~(size_t)255; return o; };
    size_t o_R1   = take((size_t)N * KP * 2);     // x1 bf16 [N][KP]
    size_t o_R2   = take((size_t)N * PBS * 2);    // pB/x1A2 [N][PBS] + s2 + entW
    size_t o_rpf  = take((size_t)2 * R * 100 * 4);// rpf2 [R][100][2] / layer2 rpf [R][200]
    size_t o_bt1  = take((size_t)400 * KP * 2);   // l1 panel (179200 B, 256-mult)
    size_t o_btf  = take((size_t)208 * KP * 2);   // W_ent panel: ADJACENT to bt1
    size_t o_bt2  = take((size_t)400 * KP * 2);
    size_t o_nsc  = take((size_t)N * 4);
    size_t o_s1   = take((size_t)2 * N * 4);      // aliased by cnt during CSR build
    size_t o_srel = take((size_t)2 * R * 4);      // [R][2] layer1 / [R] layer2
    size_t o_csr  = take((size_t)Etot * 8);
    size_t o_str  = take((size_t)(N + 1) * 4);
    size_t o_aux  = take((size_t)64 * 4);

    __hip_bfloat16* x1   = (__hip_bfloat16*)(ws + o_R1);
    __hip_bfloat16* pB   = (__hip_bfloat16*)(ws + o_R2);
    __hip_bfloat16* x1A2 = (__hip_bfloat16*)(ws + o_R2);
    float* rpf2   = (float*)(ws + o_rpf);
    __hip_bfloat16* bt1 = (__hip_bfloat16*)(ws + o_bt1);  // [608][KP] combined w/ btf
    __hip_bfloat16* btf = (__hip_bfloat16*)(ws + o_btf);
    __hip_bfloat16* bt2 = (__hip_bfloat16*)(ws + o_bt2);
    float* nscale = (float*)(ws + o_nsc);
    float* s1     = (float*)(ws + o_s1);
    float* srel2  = (float*)(ws + o_srel);
    int2*  csr    = (int2*)(ws + o_csr);
    int*   cnt    = (int*)(ws + o_s1);   // CSR-build scratch; dead before l1_both_k writes s1
    int*   startA = (int*)(ws + o_str);
    int*   aux    = (int*)(ws + o_aux);

    float* out       = (float*)d_out;
    float* out_ent   = out;                                     // [N,200]
    float* out_rel_o = out + (size_t)N * OD;                    // [500,200]
    float* out_mask  = out + (size_t)N * OD + (size_t)R * OD;   // [N]

    const int nblk = cdiv(N, 64);
    const int nbScan = cdiv(N, 1024);

    // A. prep: norms, B panels (bt1+btf contiguous -> 608-row combined panel)
    rownorm_inv_k<<<cdiv(N, 4), 256, 0, stream>>>(ent, nscale, N, DD);
    prep_bt_l1<<<400, 256, 0, stream>>>(a_heads, bt1);
    prep_bt_fin<<<208, 256, 0, stream>>>(W_ent, btf);
    prep_bt_l2<<<400, 256, 0, stream>>>(a_out, bt2);
    hipMemsetAsync(x1, 0, (size_t)N * KP * 2, stream);
    gemm_mfma_k<false, float, float><<<dim3(cdiv(OD, 64), cdiv(R, 64)), 256, 0, stream>>>(
        rel, DD, nullptr, W_gat, OD, 0, out_rel_o, OD, 1, 0, R, OD, DD);

    // A2. CSR build (dst-grouped edge lists)
    hipMemsetAsync(cnt, 0, (size_t)N * 4, stream);
    hist_k<<<cdiv(Etot, 256), 256, 0, stream>>>(el, E, etype, tin, Etot, cnt);
    scan1_k<<<nbScan, 1024, 0, stream>>>(cnt, startA, aux, N);
    scan2_k<<<1, 64, 0, stream>>>(aux, nbScan);
    scan3_k<<<nbScan, 1024, 0, stream>>>(startA, aux, N, Etot);
    hipMemsetAsync(cnt, 0, (size_t)N * 4, stream);
    fill_k<<<cdiv(Etot, 256), 256, 0, stream>>>(el, E, etype, tin, Etot, startA, cnt, csr);

    // B. layer-1 projections: y=0 blocks = l1 heads, y=1 blocks = entW
    l1_both_k<<<dim3(nblk, 2), 256, 0, stream>>>(ent, nscale, bt1, a2_heads, x1, pB, s1, N);
    for (int h = 0; h < 2; h++) {
        const float* ah  = a_heads + (size_t)h * NHID * 600;
        const float* a2h = a2_heads + (size_t)h * NHID;
        gemm_mfma_k<true, float, float><<<dim3(cdiv(NHID, 64), cdiv(R, 64)), 256, 0, stream>>>(
            rel, DD, nullptr, ah, 600, 400, rpf2, 200, 2, h, R, NHID, DD);
        rowdot_k<float><<<cdiv(R, 4), 256, 0, stream>>>(
            rpf2, 200, h, 2, a2h, srel2, 2, h, R, NHID);
    }
    gather_l1_k<<<cdiv(N, 4), 256, 0, stream>>>(
        startA, csr, s1, srel2, pB, rpf2, x1, N);
    // pB feats dead; R2 rows become x1A2 (entW at shorts 224.. survives).

    // C. layer-2 projection + rel side
    l2_proj_k<<<nblk, 256, 0, stream>>>(x1, bt2, a2_out, out_ent, x1A2, s1, N);
    gemm_mfma_k<true, float, float><<<dim3(cdiv(OD, 64), cdiv(R, 64)), 256, 0, stream>>>(
        out_rel_o, OD, nullptr, a_out, 600, 400, rpf2, OD, 1, 0, R, OD, OD);
    rowdot_k<float><<<cdiv(R, 4), 256, 0, stream>>>(rpf2, OD, 0, 1, a2_out, srel2, 1, 0, R, OD);

    // D. mask; layer-2 gather (fused combine + entW + l2norm -> final out_ent)
    hipMemsetAsync(out_mask, 0, (size_t)N * 4, stream);
    scatter_mask_k<<<cdiv(NB, 256), 256, 0, stream>>>(batch, NB, out_mask);
    gather_l2_k<<<cdiv(N, 4), 256, 0, stream>>>(
        startA, csr, s1, srel2, x1A2, rpf2, out_mask, out_ent, N);
}

// Round 10
// 450.722 us; speedup vs baseline: 1.3690x; 1.0217x over previous
//
#include <hip/hip_runtime.h>
#include <hip/hip_bf16.h>
#include <math.h>

// SpKBGAT: N=50000, D=200, R=500, NHID=100, H=2, OD=200, E=150000, ENH=30000.
// R18: R17's parallel-phase l1_both verified (66us, VGPR 116). This round:
// (1) l1_both/l2_proj widened to 512 threads / 128 rows -- per-block Bt
// staging amortized over 2x rows (occupancy-neutral: 2x8-wave blocks/CU =
// 16 waves/CU, same as 4x4); (2) A-row load issued at TOP of chunk iter
// (overlaps LDS-write+barrier), converted after; (3) x1 pad zeros written in
// l1_both epilogue -> 22.4MB memset deleted.
#define DD   200
#define NHID 100
#define OD   200
#define KP   224   // padded K (7 chunks of 32)
#define PBS  448   // row stride (bf16) for pB / x1A2 / entW: 896 B
                   // [0..199]: pB [k][h0,h1] pairs (l1) / x1A2 feats (l2)
                   // bytes 400..407: s2 floats;  shorts [224..423]: entW bf16
#define LDSW 40    // LDS row stride in shorts (80 B)

typedef __attribute__((ext_vector_type(8))) short short8;
typedef __attribute__((ext_vector_type(4))) float f32x4;

static inline int cdiv(int a, int b) { return (a + b - 1) / b; }

__device__ inline float toF(float x) { return x; }
__device__ inline float toF(__hip_bfloat16 x) { return __bfloat162float(x); }
__device__ inline void storeC(float v, float* p) { *p = v; }
__device__ inline void storeC(float v, __hip_bfloat16* p) { *p = __float2bfloat16(v); }
__device__ inline short bf16s(float f) {
    __hip_bfloat16 h = __float2bfloat16(f);
    short s; __builtin_memcpy(&s, &h, 2); return s;
}
__device__ inline float bfLo(unsigned u) { return __uint_as_float(u << 16); }
__device__ inline float bfHi(unsigned u) { return __uint_as_float(u & 0xFFFF0000u); }
__device__ inline float readlaneF(float v, int l) {
    return __uint_as_float((unsigned)__builtin_amdgcn_readlane((int)__float_as_uint(v), l));
}

// -------- per-row inverse L2 norm (f32), wave per row --------
__global__ __launch_bounds__(256)
void rownorm_inv_k(const float* __restrict__ in, float* __restrict__ sc, int M, int Dd)
{
    int wave = (blockIdx.x * blockDim.x + threadIdx.x) >> 6;
    int lane = threadIdx.x & 63;
    if (wave >= M) return;
    float ss = 0.f;
    for (int k = lane; k < Dd; k += 64) {
        float x = in[(size_t)wave * Dd + k];
        ss += x * x;
    }
    for (int o = 32; o > 0; o >>= 1) ss += __shfl_down(ss, o);
    if (lane == 0) sc[wave] = 1.f / fmaxf(sqrtf(ss), 1e-12f);
}

// -------- B-panel prep: bf16 [col][KP], zero-padded --------
__global__ void prep_bt_l1(const float* __restrict__ ah, __hip_bfloat16* __restrict__ Bt)
{
    int c = blockIdx.x, k = threadIdx.x;
    if (k >= KP) return;
    int seg = c / 100, idx = c - seg * 100;
    int h = seg & 1, off = (seg >> 1) * 200;
    float v = (k < 200) ? ah[(size_t)(h * 100 + idx) * 600 + off + k] : 0.f;
    Bt[(size_t)c * KP + k] = __float2bfloat16(v);
}
__global__ void prep_bt_l2(const float* __restrict__ ao, __hip_bfloat16* __restrict__ Bt)
{
    int c = blockIdx.x, k = threadIdx.x;
    if (k >= KP) return;
    int row = (c < 200) ? c : c - 200;
    int off = (c < 200) ? 0 : 200;
    float v = (k < 200) ? ao[(size_t)row * 600 + off + k] : 0.f;
    Bt[(size_t)c * KP + k] = __float2bfloat16(v);
}
__global__ void prep_bt_fin(const float* __restrict__ W, __hip_bfloat16* __restrict__ Bt)
{
    int c = blockIdx.x, k = threadIdx.x;
    if (k >= KP) return;
    float v = (c < 200 && k < 200) ? W[(size_t)k * 200 + c] : 0.f;
    Bt[(size_t)c * KP + k] = __float2bfloat16(v);
}

// ------ layer-1 fused: 512 thr / 128 rows; y=0 -> 25 l1 tiles; y=1 -> entW
__global__ __launch_bounds__(512)
void l1_both_k(const float* __restrict__ ent, const float* __restrict__ nscale,
               const __hip_bfloat16* __restrict__ Bt,  // [608][KP] (l1 400 + W_ent 208)
               const float* __restrict__ a2h,          // [2][100]
               __hip_bfloat16* __restrict__ x1,        // [N][KP] (cols 0-199 + pad)
               __hip_bfloat16* __restrict__ pB,        // [N][PBS]: pB + s2 + entW
               float* __restrict__ s1,                 // [2][N]
               int M)
{
    __shared__ __align__(16) __hip_bfloat16 Bs[400 * LDSW];  // 32 KB
    int tid = threadIdx.x, wave = tid >> 6, lane = tid & 63;
    int quad = lane >> 4, l16 = lane & 15;
    int m0 = blockIdx.x * 128;
    int arow = m0 + wave * 16 + l16;
    bool rok = arow < M;
    float nsc = rok ? nscale[arow] : 0.f;
    const float* arp = ent + (size_t)arow * DD;
    int orow = m0 + wave * 16 + quad * 4;

    if (blockIdx.y == 0) {
        // ---- 25-tile l1 path ----
        f32x4 acc[25];
#pragma unroll
        for (int t = 0; t < 25; t++) acc[t] = (f32x4){0.f, 0.f, 0.f, 0.f};

        short8 stg[4];
#pragma unroll
        for (int i = 0; i < 4; i++) {
            int idx = tid + i * 512;
            if (idx < 1600) {
                int r = idx >> 2, c8 = idx & 3;
                stg[i] = *(const short8*)(Bt + (size_t)r * KP + c8 * 8);
            }
        }
        for (int ch = 0; ch < 7; ch++) {
            // issue A-row slice load early: overlaps LDS-write + barrier
            int kb = ch * 32 + quad * 8;
            float av[8];
            if (rok && kb + 8 <= DD) {
                const float4* p = (const float4*)(arp + kb);
                float4 u0 = p[0], u1 = p[1];
                av[0] = u0.x; av[1] = u0.y; av[2] = u0.z; av[3] = u0.w;
                av[4] = u1.x; av[5] = u1.y; av[6] = u1.z; av[7] = u1.w;
            } else {
#pragma unroll
                for (int j = 0; j < 8; j++) av[j] = (rok && kb + j < DD) ? arp[kb + j] : 0.f;
            }
#pragma unroll
            for (int i = 0; i < 4; i++) {
                int idx = tid + i * 512;
                if (idx < 1600) {
                    int r = idx >> 2, c8 = idx & 3;
                    *(short8*)(Bs + r * LDSW + c8 * 8) = stg[i];
                }
            }
            __syncthreads();
            if (ch < 6) {
                int kb2 = (ch + 1) * 32;
#pragma unroll
                for (int i = 0; i < 4; i++) {
                    int idx = tid + i * 512;
                    if (idx < 1600) {
                        int r = idx >> 2, c8 = idx & 3;
                        stg[i] = *(const short8*)(Bt + (size_t)r * KP + kb2 + c8 * 8);
                    }
                }
            }
            short8 a;
#pragma unroll
            for (int j = 0; j < 8; j++) a[j] = bf16s(av[j] * nsc);
            const __hip_bfloat16* bp = Bs + (size_t)l16 * LDSW + quad * 8;
#pragma unroll
            for (int t = 0; t < 25; t++) {
                short8 b = *(const short8*)(bp + (size_t)t * 16 * LDSW);
                acc[t] = __builtin_amdgcn_mfma_f32_16x16x32_bf16(a, b, acc[t], 0, 0, 0);
            }
            __syncthreads();
        }

        float d0[4] = {0,0,0,0}, d1[4] = {0,0,0,0}, d2[4] = {0,0,0,0}, d3[4] = {0,0,0,0};
#pragma unroll
        for (int t = 0; t < 25; t++) {
            int c = t * 16 + l16;
            int seg = c / 100, idx = c - seg * 100;
            float w = a2h[(seg & 1) * 100 + idx];
#pragma unroll
            for (int i = 0; i < 4; i++) {
                float v = acc[t][i];
                float vw = v * w;
                if (seg == 0) d0[i] += vw;
                else if (seg == 1) d1[i] += vw;
                else if (seg == 2) d2[i] += vw;
                else d3[i] += vw;
                int gm = orow + i;
                if (gm < M) {
                    if (seg < 2) x1[(size_t)gm * KP + c] = __float2bfloat16(v);
                    else pB[(size_t)gm * PBS + idx * 2 + (seg - 2)] = __float2bfloat16(v);
                }
            }
        }
        // x1 pad zeros (cols 200-223): replaces the 22.4MB memset
        if (l16 < 12)
#pragma unroll
            for (int i = 0; i < 4; i++) {
                int gm = orow + i;
                if (gm < M) *(unsigned*)(x1 + (size_t)gm * KP + 200 + 2 * l16) = 0u;
            }
#pragma unroll
        for (int msk = 1; msk < 16; msk <<= 1)
#pragma unroll
            for (int i = 0; i < 4; i++) {
                d0[i] += __shfl_xor(d0[i], msk);
                d1[i] += __shfl_xor(d1[i], msk);
                d2[i] += __shfl_xor(d2[i], msk);
                d3[i] += __shfl_xor(d3[i], msk);
            }
        if (l16 == 0)
#pragma unroll
            for (int i = 0; i < 4; i++) {
                int gm = orow + i;
                if (gm < M) {
                    s1[gm] = d0[i]; s1[M + gm] = d1[i];
                    float2 sv; sv.x = d2[i]; sv.y = d3[i];
                    *(float2*)((char*)pB + (size_t)gm * (PBS * 2) + 400) = sv;
                }
            }
    } else {
        // ---- 13-tile entW path ----
        f32x4 acc2[13];
#pragma unroll
        for (int t = 0; t < 13; t++) acc2[t] = (f32x4){0.f, 0.f, 0.f, 0.f};

        short8 stg2[2];
#pragma unroll
        for (int i = 0; i < 2; i++) {
            int idx = tid + i * 512;
            if (idx < 832) {
                int r = idx >> 2, c8 = idx & 3;
                stg2[i] = *(const short8*)(Bt + (size_t)(400 + r) * KP + c8 * 8);
            }
        }
        for (int ch = 0; ch < 7; ch++) {
            int kb = ch * 32 + quad * 8;
            float av[8];
            if (rok && kb + 8 <= DD) {
                const float4* p = (const float4*)(arp + kb);
                float4 u0 = p[0], u1 = p[1];
                av[0] = u0.x; av[1] = u0.y; av[2] = u0.z; av[3] = u0.w;
                av[4] = u1.x; av[5] = u1.y; av[6] = u1.z; av[7] = u1.w;
            } else {
#pragma unroll
                for (int j = 0; j < 8; j++) av[j] = (rok && kb + j < DD) ? arp[kb + j] : 0.f;
            }
#pragma unroll
            for (int i = 0; i < 2; i++) {
                int idx = tid + i * 512;
                if (idx < 832) {
                    int r = idx >> 2, c8 = idx & 3;
                    *(short8*)(Bs + r * LDSW + c8 * 8) = stg2[i];
                }
            }
            __syncthreads();
            if (ch < 6) {
                int kb2 = (ch + 1) * 32;
#pragma unroll
                for (int i = 0; i < 2; i++) {
                    int idx = tid + i * 512;
                    if (idx < 832) {
                        int r = idx >> 2, c8 = idx & 3;
                        stg2[i] = *(const short8*)(Bt + (size_t)(400 + r) * KP + kb2 + c8 * 8);
                    }
                }
            }
            short8 a;
#pragma unroll
            for (int j = 0; j < 8; j++) a[j] = bf16s(av[j] * nsc);
            const __hip_bfloat16* bp = Bs + (size_t)l16 * LDSW + quad * 8;
#pragma unroll
            for (int t = 0; t < 13; t++) {
                short8 b = *(const short8*)(bp + (size_t)t * 16 * LDSW);
                acc2[t] = __builtin_amdgcn_mfma_f32_16x16x32_bf16(a, b, acc2[t], 0, 0, 0);
            }
            __syncthreads();
        }
#pragma unroll
        for (int t = 0; t < 13; t++) {
            int c2 = t * 16 + l16;
#pragma unroll
            for (int i = 0; i < 4; i++) {
                int gm = orow + i;
                if (c2 < OD && gm < M)
                    pB[(size_t)gm * PBS + 224 + c2] = __float2bfloat16(acc2[t][i]);
            }
        }
    }
}

// -------- layer-2 fused: 512 thr / 128 rows; 25 tiles ---------------------
__global__ __launch_bounds__(512)
void l2_proj_k(const __hip_bfloat16* __restrict__ x1,  // [N][KP]
               const __hip_bfloat16* __restrict__ Bt,  // [400][KP]
               const float* __restrict__ a2o,          // [200]
               float* __restrict__ x1A1,               // [N][200] (out_ent)
               __hip_bfloat16* __restrict__ x1A2,      // [N][PBS], s2 in pad
               float* __restrict__ s1, int M)
{
    __shared__ __align__(16) __hip_bfloat16 Bs[400 * LDSW];  // 32 KB
    int tid = threadIdx.x, wave = tid >> 6, lane = tid & 63;
    int quad = lane >> 4, l16 = lane & 15;
    int m0 = blockIdx.x * 128;
    int arow = m0 + wave * 16 + l16;
    bool rok = arow < M;
    const __hip_bfloat16* arp = x1 + (size_t)arow * KP;

    f32x4 acc[25];
#pragma unroll
    for (int t = 0; t < 25; t++) acc[t] = (f32x4){0.f, 0.f, 0.f, 0.f};

    short8 stg[4];
#pragma unroll
    for (int i = 0; i < 4; i++) {
        int idx = tid + i * 512;
        if (idx < 1600) {
            int r = idx >> 2, c8 = idx & 3;
            stg[i] = *(const short8*)(Bt + (size_t)r * KP + c8 * 8);
        }
    }

    for (int ch = 0; ch < 7; ch++) {
        // issue A load early
        short8 a = (short8){0,0,0,0,0,0,0,0};
        if (rok) a = *(const short8*)(arp + ch * 32 + quad * 8);
#pragma unroll
        for (int i = 0; i < 4; i++) {
            int idx = tid + i * 512;
            if (idx < 1600) {
                int r = idx >> 2, c8 = idx & 3;
                *(short8*)(Bs + r * LDSW + c8 * 8) = stg[i];
            }
        }
        __syncthreads();
        if (ch < 6) {
            int kb2 = (ch + 1) * 32;
#pragma unroll
            for (int i = 0; i < 4; i++) {
                int idx = tid + i * 512;
                if (idx < 1600) {
                    int r = idx >> 2, c8 = idx & 3;
                    stg[i] = *(const short8*)(Bt + (size_t)r * KP + kb2 + c8 * 8);
                }
            }
        }
        const __hip_bfloat16* bp = Bs + (size_t)l16 * LDSW + quad * 8;
#pragma unroll
        for (int t = 0; t < 25; t++) {
            short8 b = *(const short8*)(bp + (size_t)t * 16 * LDSW);
            acc[t] = __builtin_amdgcn_mfma_f32_16x16x32_bf16(a, b, acc[t], 0, 0, 0);
        }
        __syncthreads();
    }

    int orow = m0 + wave * 16 + quad * 4;
    float dA[4] = {0,0,0,0}, dB[4] = {0,0,0,0};
#pragma unroll
    for (int t = 0; t < 25; t++) {
        int c = t * 16 + l16;
        bool first = c < 200;
        int cc = first ? c : c - 200;
        float w = a2o[cc];
#pragma unroll
        for (int i = 0; i < 4; i++) {
            float v = acc[t][i];
            int gm = orow + i;
            if (first) {
                dA[i] += v * w;
                if (gm < M) x1A1[(size_t)gm * OD + c] = v;
            } else {
                dB[i] += v * w;
                if (gm < M) x1A2[(size_t)gm * PBS + cc] = __float2bfloat16(v);
            }
        }
    }
#pragma unroll
    for (int msk = 1; msk < 16; msk <<= 1)
#pragma unroll
        for (int i = 0; i < 4; i++) {
            dA[i] += __shfl_xor(dA[i], msk);
            dB[i] += __shfl_xor(dB[i], msk);
        }
    if (l16 == 0)
#pragma unroll
        for (int i = 0; i < 4; i++) {
            int gm = orow + i;
            if (gm < M) {
                s1[gm] = dA[i];
                *(float*)((char*)x1A2 + (size_t)gm * (PBS * 2) + 400) = dB[i];
            }
        }
}

// -------- generic MFMA GEMM (small R-sized matmuls); cs/co = C col-stride --
#define KPAD 48
template<bool BTr, typename AT, typename CT>
__global__ __launch_bounds__(256)
void gemm_mfma_k(const AT* __restrict__ A, int lda, const float* __restrict__ ascale,
                 const float* __restrict__ B, int ldb, int colOff,
                 CT* __restrict__ C, int ldc, int cs, int co,
                 int M, int Nc, int K)
{
    __shared__ __align__(16) __hip_bfloat16 As[64][KPAD];
    __shared__ __align__(16) __hip_bfloat16 Bs[64][KPAD];
    int tid  = threadIdx.x;
    int wave = tid >> 6, lane = tid & 63;
    int quad = lane >> 4, l16 = lane & 15;
    int n0 = blockIdx.x * 64, m0 = blockIdx.y * 64;
    f32x4 acc[4];
#pragma unroll
    for (int t = 0; t < 4; t++) acc[t] = (f32x4){0.f, 0.f, 0.f, 0.f};

    for (int k0 = 0; k0 < K; k0 += 32) {
        {
            int m = tid >> 2, kc = (tid & 3) * 8;
            int gm = m0 + m;
            float scale = (ascale && gm < M) ? ascale[gm] : 1.f;
#pragma unroll
            for (int j = 0; j < 8; j++) {
                int gk = k0 + kc + j;
                float v = 0.f;
                if (gm < M && gk < K) v = toF(A[(size_t)gm * lda + gk]) * scale;
                As[m][kc + j] = __float2bfloat16(v);
            }
        }
        if (BTr) {
            int n = tid >> 2, kc = (tid & 3) * 8;
            int gn = n0 + n;
#pragma unroll
            for (int j = 0; j < 8; j++) {
                int gk = k0 + kc + j;
                float v = 0.f;
                if (gn < Nc && gk < K) v = B[(size_t)gn * ldb + colOff + gk];
                Bs[n][kc + j] = __float2bfloat16(v);
            }
        } else {
            int n = tid & 63, kq = tid >> 6;
            int gn = n0 + n;
#pragma unroll
            for (int j = 0; j < 8; j++) {
                int gk = k0 + kq * 8 + j;
                float v = 0.f;
                if (gn < Nc && gk < K) v = B[(size_t)gk * ldb + gn];
                Bs[n][kq * 8 + j] = __float2bfloat16(v);
            }
        }
        __syncthreads();
        short8 a = *(const short8*)&As[wave * 16 + l16][quad * 8];
#pragma unroll
        for (int t = 0; t < 4; t++) {
            short8 b = *(const short8*)&Bs[t * 16 + l16][quad * 8];
            acc[t] = __builtin_amdgcn_mfma_f32_16x16x32_bf16(a, b, acc[t], 0, 0, 0);
        }
        __syncthreads();
    }
#pragma unroll
    for (int t = 0; t < 4; t++) {
        int gn = n0 + t * 16 + l16;
        if (gn >= Nc) continue;
#pragma unroll
        for (int i = 0; i < 4; i++) {
            int gm = m0 + wave * 16 + quad * 4 + i;
            if (gm < M) storeC(acc[t][i], &C[(size_t)gm * ldc + (size_t)gn * cs + co]);
        }
    }
}

// -------- row-dot (srel); ks = k-stride in mat, os/oo = output stride ------
template<typename T>
__global__ __launch_bounds__(256)
void rowdot_k(const T* __restrict__ mat, int ld, int coff, int ks,
              const float* __restrict__ vec,
              float* __restrict__ outp, int os, int oo, int M, int Dd)
{
    int wave = (blockIdx.x * blockDim.x + threadIdx.x) >> 6;
    int lane = threadIdx.x & 63;
    if (wave >= M) return;
    float s = 0.f;
    for (int k = lane; k < Dd; k += 64)
        s += toF(mat[(size_t)wave * ld + coff + (size_t)k * ks]) * vec[k];
    for (int o = 32; o > 0; o >>= 1) s += __shfl_down(s, o);
    if (lane == 0) outp[wave * os + oo] = s;
}

// -------- CSR build --------
__device__ inline void decode_edge(const int* __restrict__ el, int E,
                                   const int* __restrict__ etype,
                                   const int* __restrict__ tin, int e,
                                   int& dst, int& src, int& r1, int& r2)
{
    if (e < E) { dst = el[e]; src = el[E + e]; r1 = etype[e]; r2 = -1; }
    else {
        int j = e - E;
        dst = tin[j * 4 + 3]; src = tin[j * 4 + 0];
        r1 = tin[j * 4 + 1];  r2 = tin[j * 4 + 2];
    }
}

__global__ void hist_k(const int* __restrict__ el, int E, const int* __restrict__ etype,
                       const int* __restrict__ tin, int Etot, int* __restrict__ cnt)
{
    int e = blockIdx.x * blockDim.x + threadIdx.x;
    if (e >= Etot) return;
    int dst, src, r1, r2; decode_edge(el, E, etype, tin, e, dst, src, r1, r2);
    atomicAdd(&cnt[dst], 1);
}

__global__ __launch_bounds__(1024)
void scan1_k(const int* __restrict__ cnt, int* __restrict__ start,
             int* __restrict__ aux, int n)
{
    __shared__ int tmp[1024];
    int i = blockIdx.x * 1024 + threadIdx.x;
    int v = (i < n) ? cnt[i] : 0;
    tmp[threadIdx.x] = v;
    __syncthreads();
    for (int o = 1; o < 1024; o <<= 1) {
        int t = (threadIdx.x >= (unsigned)o) ? tmp[threadIdx.x - o] : 0;
        __syncthreads();
        tmp[threadIdx.x] += t;
        __syncthreads();
    }
    if (i < n) start[i] = tmp[threadIdx.x] - v;
    if (threadIdx.x == 1023) aux[blockIdx.x] = tmp[1023];
}

__global__ void scan2_k(int* __restrict__ aux, int nb)
{
    if (threadIdx.x == 0 && blockIdx.x == 0) {
        int s = 0;
        for (int i = 0; i < nb; i++) { int v = aux[i]; aux[i] = s; s += v; }
    }
}

__global__ __launch_bounds__(1024)
void scan3_k(int* __restrict__ start, const int* __restrict__ aux, int n, int Etot)
{
    int i = blockIdx.x * 1024 + threadIdx.x;
    if (i < n) start[i] += aux[blockIdx.x];
    if (i == 0) start[n] = Etot;
}

// csr entry: .x = src, .y = r1 | (r2s<<16), r2s==0xFFFF means "no r2"
__global__ void fill_k(const int* __restrict__ el, int E, const int* __restrict__ etype,
                       const int* __restrict__ tin, int Etot,
                       const int* __restrict__ start, int* __restrict__ fill,
                       int2* __restrict__ csr)
{
    int e = blockIdx.x * blockDim.x + threadIdx.x;
    if (e >= Etot) return;
    int dst, src, r1, r2; decode_edge(el, E, etype, tin, e, dst, src, r1, r2);
    int p = start[dst] + atomicAdd(&fill[dst], 1);
    unsigned r2s = (r2 >= 0) ? (unsigned)r2 : 0xFFFFu;
    csr[p] = make_int2(src, (int)((r2s << 16) | (unsigned)r1));
}

// -------- layer-1 gather: wave/dst, two-phase (lane-parallel scalars) ------
__global__ __launch_bounds__(256)
void gather_l1_k(const int* __restrict__ start, const int2* __restrict__ csr,
                 const float* __restrict__ s1,        // [2][N] dst-side
                 const float* __restrict__ srel2,     // [R][2]
                 const __hip_bfloat16* __restrict__ pB,   // [N][PBS] interleaved
                 const float* __restrict__ rpf2,      // [R][100][2]
                 __hip_bfloat16* __restrict__ x1, int N)  // [N][KP]
{
    int n = (blockIdx.x * blockDim.x + threadIdx.x) >> 6;
    int lane = threadIdx.x & 63;
    if (n >= N) return;
    int b0 = __builtin_amdgcn_readfirstlane(start[n]);
    int b1 = __builtin_amdgcn_readfirstlane(start[n + 1]);
    float s1h0 = s1[n], s1h1 = s1[N + n];
    float rsl0 = 0.f, rsl1 = 0.f;        // per-lane partial rowsums
    float2 acc0 = {0.f, 0.f};            // k0: (h0, h1)
    float2 acc1 = {0.f, 0.f};            // k1
    int k0 = lane;
    bool k1ok = lane < 36;
    int k1c = k1ok ? (lane + 64) : 0;

    for (int c0 = b0; c0 < b1; c0 += 64) {
        int cnt = min(64, b1 - c0);
        // ---- phase A: lane e computes edge (c0+e)'s scalars; all loads in flight
        float w0 = 0.f, w1 = 0.f;
        int srcL = 0, eyL = 0;
        if (lane < cnt) {
            int2 eg = csr[c0 + lane];
            srcL = eg.x; eyL = eg.y;
            int r1 = eyL & 0xFFFF;
            unsigned r2u = (unsigned)eyL >> 16;
            float2 sA = *(const float2*)((const char*)pB + (size_t)(unsigned)srcL * (PBS * 2) + 400);
            float2 sr = *(const float2*)(srel2 + r1 * 2);
            float z0 = s1h0 + sA.x + sr.x;
            float z1 = s1h1 + sA.y + sr.y;
            if (r2u != 0xFFFFu) {
                float2 sr2v = *(const float2*)(srel2 + r2u * 2);
                z0 += sr2v.x; z1 += sr2v.y;
            }
            w0 = expf(-(z0 > 0.f ? z0 : 0.2f * z0));
            w1 = expf(-(z1 > 0.f ? z1 : 0.2f * z1));
            rsl0 += w0; rsl1 += w1;
        }
        // ---- phase B: per-edge feature FMA; 4-edge-batched pB loads
        for (int e0 = 0; e0 < cnt; e0 += 4) {
            int ec = min(4, cnt - e0);
            unsigned pw0[4], pw1[4];
#pragma unroll
            for (int u = 0; u < 4; u++) {
                if (u < ec) {
                    int s = __builtin_amdgcn_readlane(srcL, e0 + u);
                    const __hip_bfloat16* rA = pB + (size_t)(unsigned)s * PBS;
                    pw0[u] = *(const unsigned*)(rA + 2 * k0);
                    pw1[u] = *(const unsigned*)(rA + 2 * k1c);
                }
            }
#pragma unroll
            for (int u = 0; u < 4; u++) {
                if (u < ec) {
                    int ey = __builtin_amdgcn_readlane(eyL, e0 + u);
                    int r1 = ey & 0xFFFF;
                    unsigned r2u = (unsigned)ey >> 16;
                    float we0 = readlaneF(w0, e0 + u);
                    float we1 = readlaneF(w1, e0 + u);
                    const float2* q1 = (const float2*)(rpf2 + (unsigned)r1 * 200);
                    float2 q1a = q1[k0], q1b = q1[k1c];
                    float v00 = bfLo(pw0[u]) + q1a.x;
                    float v01 = bfHi(pw0[u]) + q1a.y;
                    float v10 = bfLo(pw1[u]) + q1b.x;
                    float v11 = bfHi(pw1[u]) + q1b.y;
                    if (r2u != 0xFFFFu) {
                        const float2* q2 = (const float2*)(rpf2 + r2u * 200);
                        float2 q2a = q2[k0], q2b = q2[k1c];
                        v00 += q2a.x; v01 += q2a.y;
                        v10 += q2b.x; v11 += q2b.y;
                    }
                    acc0.x += we0 * v00; acc0.y += we1 * v01;
                    acc1.x += we0 * v10; acc1.y += we1 * v11;
                }
            }
        }
    }

    // wave-reduce rowsums (butterfly -> all lanes)
#pragma unroll
    for (int o = 1; o < 64; o <<= 1) {
        rsl0 += __shfl_xor(rsl0, o);
        rsl1 += __shfl_xor(rsl1, o);
    }
    float i0 = rsl0 > 0.f ? 1.f / rsl0 : 0.f;
    float i1 = rsl1 > 0.f ? 1.f / rsl1 : 0.f;
    __hip_bfloat16* xr = x1 + (size_t)n * KP;
    float hp;
    hp = rsl0 > 0.f ? toF(xr[k0]) + acc0.x * i0 : 0.f;
    xr[k0] = __float2bfloat16(hp > 0.f ? hp : expf(hp) - 1.f);
    hp = rsl1 > 0.f ? toF(xr[100 + k0]) + acc0.y * i1 : 0.f;
    xr[100 + k0] = __float2bfloat16(hp > 0.f ? hp : expf(hp) - 1.f);
    if (k1ok) {
        int k1 = lane + 64;
        hp = rsl0 > 0.f ? toF(xr[k1]) + acc1.x * i0 : 0.f;
        xr[k1] = __float2bfloat16(hp > 0.f ? hp : expf(hp) - 1.f);
        hp = rsl1 > 0.f ? toF(xr[100 + k1]) + acc1.y * i1 : 0.f;
        xr[100 + k1] = __float2bfloat16(hp > 0.f ? hp : expf(hp) - 1.f);
    }
}

// -------- layer-2 gather: wave/dst, two-phase; fused +entW + l2norm -------
__global__ __launch_bounds__(256)
void gather_l2_k(const int* __restrict__ start, const int2* __restrict__ csr,
                 const float* __restrict__ s1,
                 const float* __restrict__ srel,          // [R]
                 const __hip_bfloat16* __restrict__ x1A2, // [N][PBS]: feats+s2+entW
                 const float* __restrict__ rpf,           // [R][200]
                 const float* __restrict__ maskf,
                 float* __restrict__ outent, int N)       // [N][200], holds x1A1
{
    int n = (blockIdx.x * blockDim.x + threadIdx.x) >> 6;
    int lane = threadIdx.x & 63;
    if (n >= N) return;
    int b0 = __builtin_amdgcn_readfirstlane(start[n]);
    int b1 = __builtin_amdgcn_readfirstlane(start[n + 1]);
    float s1n = s1[n];
    float rsl = 0.f;
    float2 a0 = {0.f, 0.f};   // k = 2*lane, 2*lane+1
    float2 a1 = {0.f, 0.f};   // k = 128+2*lane, +1 (lane<36)
    int j0 = 2 * lane;
    bool j1ok = lane < 36;
    int j1 = j1ok ? (128 + 2 * lane) : 0;

    for (int c0 = b0; c0 < b1; c0 += 64) {
        int cnt = min(64, b1 - c0);
        // ---- phase A: lane-parallel per-edge scalars
        float w = 0.f;
        int srcL = 0, eyL = 0;
        if (lane < cnt) {
            int2 eg = csr[c0 + lane];
            srcL = eg.x; eyL = eg.y;
            int r1 = eyL & 0xFFFF;
            unsigned r2u = (unsigned)eyL >> 16;
            float s2v = *(const float*)((const char*)x1A2 + (size_t)(unsigned)srcL * (PBS * 2) + 400);
            float sr = srel[r1];
            if (r2u != 0xFFFFu) sr += srel[r2u];
            float z = s1n + s2v + sr;
            w = expf(-(z > 0.f ? z : 0.2f * z));
            rsl += w;
        }
        // ---- phase B: per-edge feature FMA; 4-edge-batched feature loads
        for (int e0 = 0; e0 < cnt; e0 += 4) {
            int ec = min(4, cnt - e0);
            unsigned xw0[4], xw1[4];
#pragma unroll
            for (int u = 0; u < 4; u++) {
                if (u < ec) {
                    int s = __builtin_amdgcn_readlane(srcL, e0 + u);
                    const __hip_bfloat16* xs = x1A2 + (size_t)(unsigned)s * PBS;
                    xw0[u] = *(const unsigned*)(xs + j0);
                    xw1[u] = *(const unsigned*)(xs + j1);
                }
            }
#pragma unroll
            for (int u = 0; u < 4; u++) {
                if (u < ec) {
                    int ey = __builtin_amdgcn_readlane(eyL, e0 + u);
                    int r1 = ey & 0xFFFF;
                    unsigned r2u = (unsigned)ey >> 16;
                    float we = readlaneF(w, e0 + u);
                    const float* q1 = rpf + (unsigned)r1 * 200;
                    float2 q1a = *(const float2*)(q1 + j0);
                    float2 q1b = *(const float2*)(q1 + j1);
                    float v0x = bfLo(xw0[u]) + q1a.x;
                    float v0y = bfHi(xw0[u]) + q1a.y;
                    float v1x = bfLo(xw1[u]) + q1b.x;
                    float v1y = bfHi(xw1[u]) + q1b.y;
                    if (r2u != 0xFFFFu) {
                        const float* q2 = rpf + r2u * 200;
                        float2 q2a = *(const float2*)(q2 + j0);
                        float2 q2b = *(const float2*)(q2 + j1);
                        v0x += q2a.x; v0y += q2a.y;
                        v1x += q2b.x; v1y += q2b.y;
                    }
                    a0.x += we * v0x; a0.y += we * v0y;
                    a1.x += we * v1x; a1.y += we * v1y;
                }
            }
        }
    }

#pragma unroll
    for (int o = 1; o < 64; o <<= 1) rsl += __shfl_xor(rsl, o);
    float inv = rsl > 0.f ? 1.f / rsl : 0.f;
    float mk = maskf[n];
    float* orow = outent + (size_t)n * 200;
    const __hip_bfloat16* ew = x1A2 + (size_t)n * PBS + 224;  // own dst row's entW

    float2 o0 = *(const float2*)(orow + j0);
    unsigned e0b = *(const unsigned*)(ew + j0);
    float h0x = rsl > 0.f ? o0.x + a0.x * inv : 0.f;
    float h0y = rsl > 0.f ? o0.y + a0.y * inv : 0.f;
    float v0x = mk * (h0x > 0.f ? h0x : expf(h0x) - 1.f) + bfLo(e0b);
    float v0y = mk * (h0y > 0.f ? h0y : expf(h0y) - 1.f) + bfHi(e0b);
    float ssq = v0x * v0x + v0y * v0y;
    float v1x = 0.f, v1y = 0.f;
    if (j1ok) {
        float2 o1 = *(const float2*)(orow + j1);
        unsigned e1b = *(const unsigned*)(ew + j1);
        float h1x = rsl > 0.f ? o1.x + a1.x * inv : 0.f;
        float h1y = rsl > 0.f ? o1.y + a1.y * inv : 0.f;
        v1x = mk * (h1x > 0.f ? h1x : expf(h1x) - 1.f) + bfLo(e1b);
        v1y = mk * (h1y > 0.f ? h1y : expf(h1y) - 1.f) + bfHi(e1b);
        ssq += v1x * v1x + v1y * v1y;
    }
#pragma unroll
    for (int o = 1; o < 64; o <<= 1) ssq += __shfl_xor(ssq, o);
    float sc = 1.f / fmaxf(sqrtf(ssq), 1e-12f);
    float2 r0; r0.x = v0x * sc; r0.y = v0y * sc;
    *(float2*)(orow + j0) = r0;
    if (j1ok) {
        float2 r1; r1.x = v1x * sc; r1.y = v1y * sc;
        *(float2*)(orow + j1) = r1;
    }
}

__global__ void scatter_mask_k(const int* __restrict__ batch, int NB,
                               float* __restrict__ masko)
{
    int i = blockIdx.x * blockDim.x + threadIdx.x;
    if (i >= NB) return;
    masko[batch[i]] = 1.0f;
}

extern "C" void kernel_launch(void* const* d_in, const int* in_sizes, int n_in,
                              void* d_out, int out_size, void* d_ws, size_t ws_size,
                              hipStream_t stream)
{
    const float* ent      = (const float*)d_in[0];
    const float* rel      = (const float*)d_in[1];
    const float* W_ent    = (const float*)d_in[2];
    const float* W_gat    = (const float*)d_in[3];
    const float* a_heads  = (const float*)d_in[4];
    const float* a2_heads = (const float*)d_in[5];
    const float* a_out    = (const float*)d_in[6];
    const float* a2_out   = (const float*)d_in[7];
    const int* batch = (const int*)d_in[8];
    const int* el    = (const int*)d_in[9];
    const int* etype = (const int*)d_in[10];
    const int* tin   = (const int*)d_in[11];

    const int N   = in_sizes[0] / DD;   // 50000
    const int R   = in_sizes[1] / DD;   // 500
    const int NB  = in_sizes[8];        // 20000
    const int E   = in_sizes[9] / 2;    // 150000
    const int ENH = in_sizes[11] / 4;   // 30000
    const int Etot = E + ENH;

    // ---- workspace (~70 MB) ----
    char* ws = (char*)d_ws;
    size_t off = 0;
    auto take = [&](size_t bytes) { size_t o = off; off += (bytes + 255) & ~(size_t)255; return o; };
    size_t o_R1   = take((size_t)N * KP * 2);     // x1 bf16 [N][KP]
    size_t o_R2   = take((size_t)N * PBS * 2);    // pB/x1A2 [N][PBS] + s2 + entW
    size_t o_rpf  = take((size_t)2 * R * 100 * 4);// rpf2 [R][100][2] / layer2 rpf [R][200]
    size_t o_bt1  = take((size_t)400 * KP * 2);   // l1 panel (179200 B, 256-mult)
    size_t o_btf  = take((size_t)208 * KP * 2);   // W_ent panel: ADJACENT to bt1
    size_t o_bt2  = take((size_t)400 * KP * 2);
    size_t o_nsc  = take((size_t)N * 4);
    size_t o_s1   = take((size_t)2 * N * 4);      // aliased by cnt during CSR build
    size_t o_srel = take((size_t)2 * R * 4);      // [R][2] layer1 / [R] layer2
    size_t o_csr  = take((size_t)Etot * 8);
    size_t o_str  = take((size_t)(N + 1) * 4);
    size_t o_aux  = take((size_t)64 * 4);

    __hip_bfloat16* x1   = (__hip_bfloat16*)(ws + o_R1);
    __hip_bfloat16* pB   = (__hip_bfloat16*)(ws + o_R2);
    __hip_bfloat16* x1A2 = (__hip_bfloat16*)(ws + o_R2);
    float* rpf2   = (float*)(ws + o_rpf);
    __hip_bfloat16* bt1 = (__hip_bfloat16*)(ws + o_bt1);  // [608][KP] combined w/ btf
    __hip_bfloat16* btf = (__hip_bfloat16*)(ws + o_btf);
    __hip_bfloat16* bt2 = (__hip_bfloat16*)(ws + o_bt2);
    float* nscale = (float*)(ws + o_nsc);
    float* s1     = (float*)(ws + o_s1);
    float* srel2  = (float*)(ws + o_srel);
    int2*  csr    = (int2*)(ws + o_csr);
    int*   cnt    = (int*)(ws + o_s1);   // CSR-build scratch; dead before l1_both_k writes s1
    int*   startA = (int*)(ws + o_str);
    int*   aux    = (int*)(ws + o_aux);

    float* out       = (float*)d_out;
    float* out_ent   = out;                                     // [N,200]
    float* out_rel_o = out + (size_t)N * OD;                    // [500,200]
    float* out_mask  = out + (size_t)N * OD + (size_t)R * OD;   // [N]

    const int nblk2 = cdiv(N, 128);
    const int nbScan = cdiv(N, 1024);

    // A. prep: norms, B panels (bt1+btf contiguous -> 608-row combined panel)
    rownorm_inv_k<<<cdiv(N, 4), 256, 0, stream>>>(ent, nscale, N, DD);
    prep_bt_l1<<<400, 256, 0, stream>>>(a_heads, bt1);
    prep_bt_fin<<<208, 256, 0, stream>>>(W_ent, btf);
    prep_bt_l2<<<400, 256, 0, stream>>>(a_out, bt2);
    gemm_mfma_k<false, float, float><<<dim3(cdiv(OD, 64), cdiv(R, 64)), 256, 0, stream>>>(
        rel, DD, nullptr, W_gat, OD, 0, out_rel_o, OD, 1, 0, R, OD, DD);

    // A2. CSR build (dst-grouped edge lists)
    hipMemsetAsync(cnt, 0, (size_t)N * 4, stream);
    hist_k<<<cdiv(Etot, 256), 256, 0, stream>>>(el, E, etype, tin, Etot, cnt);
    scan1_k<<<nbScan, 1024, 0, stream>>>(cnt, startA, aux, N);
    scan2_k<<<1, 64, 0, stream>>>(aux, nbScan);
    scan3_k<<<nbScan, 1024, 0, stream>>>(startA, aux, N, Etot);
    hipMemsetAsync(cnt, 0, (size_t)N * 4, stream);
    fill_k<<<cdiv(Etot, 256), 256, 0, stream>>>(el, E, etype, tin, Etot, startA, cnt, csr);

    // B. layer-1 projections: y=0 blocks = l1 heads (+x1 pad), y=1 = entW
    l1_both_k<<<dim3(nblk2, 2), 512, 0, stream>>>(ent, nscale, bt1, a2_heads, x1, pB, s1, N);
    for (int h = 0; h < 2; h++) {
        const float* ah  = a_heads + (size_t)h * NHID * 600;
        const float* a2h = a2_heads + (size_t)h * NHID;
        gemm_mfma_k<true, float, float><<<dim3(cdiv(NHID, 64), cdiv(R, 64)), 256, 0, stream>>>(
            rel, DD, nullptr, ah, 600, 400, rpf2, 200, 2, h, R, NHID, DD);
        rowdot_k<float><<<cdiv(R, 4), 256, 0, stream>>>(
            rpf2, 200, h, 2, a2h, srel2, 2, h, R, NHID);
    }
    gather_l1_k<<<cdiv(N, 4), 256, 0, stream>>>(
        startA, csr, s1, srel2, pB, rpf2, x1, N);
    // pB feats dead; R2 rows become x1A2 (entW at shorts 224.. survives).

    // C. layer-2 projection + rel side
    l2_proj_k<<<nblk2, 512, 0, stream>>>(x1, bt2, a2_out, out_ent, x1A2, s1, N);
    gemm_mfma_k<true, float, float><<<dim3(cdiv(OD, 64), cdiv(R, 64)), 256, 0, stream>>>(
        out_rel_o, OD, nullptr, a_out, 600, 400, rpf2, OD, 1, 0, R, OD, OD);
    rowdot_k<float><<<cdiv(R, 4), 256, 0, stream>>>(rpf2, OD, 0, 1, a2_out, srel2, 1, 0, R, OD);

    // D. mask; layer-2 gather (fused combine + entW + l2norm -> final out_ent)
    hipMemsetAsync(out_mask, 0, (size_t)N * 4, stream);
    scatter_mask_k<<<cdiv(NB, 256), 256, 0, stream>>>(batch, NB, out_mask);
    gather_l2_k<<<cdiv(N, 4), 256, 0, stream>>>(
        startA, csr, s1, srel2, x1A2, rpf2, out_mask, out_ent, N);
}

// Round 11
// 444.712 us; speedup vs baseline: 1.3875x; 1.0135x over previous
//
#include <hip/hip_runtime.h>
#include <hip/hip_bf16.h>
#include <math.h>

// SpKBGAT: N=50000, D=200, R=500, NHID=100, H=2, OD=200, E=150000, ENH=30000.
// R19: l1_both stuck at 66us, 21% busy, 2 blocks/CU (VGPR=100 -> 5 waves/SIMD).
// Fix: flavor-split so no branch needs acc[25]. Bt panels reordered into
// 208-row groups (13 tiles each, 8 zero-pad cols): l1_both = 3 flavors
// (y0: x1+s1, y1: pB+s2, y2: entW), l2_proj = 2 flavors; each acc[13]
// (~52 VGPR) -> target <=85 VGPR -> 6 waves/SIMD -> 3 blocks/CU.
// Per-flavor weight collapses to a2h[cc]/a2o[cc]; no cross-flavor reductions.
#define DD   200
#define NHID 100
#define OD   200
#define KP   224   // padded K (7 chunks of 32)
#define PBS  448   // row stride (bf16) for pB / x1A2 / entW: 896 B
                   // [0..199]: pB [k][h0,h1] pairs (l1) / x1A2 feats (l2)
                   // bytes 400..407: s2 floats;  shorts [224..423]: entW bf16
#define LDSW 40    // LDS row stride in shorts (80 B)

typedef __attribute__((ext_vector_type(8))) short short8;
typedef __attribute__((ext_vector_type(4))) float f32x4;

static inline int cdiv(int a, int b) { return (a + b - 1) / b; }

__device__ inline float toF(float x) { return x; }
__device__ inline float toF(__hip_bfloat16 x) { return __bfloat162float(x); }
__device__ inline void storeC(float v, float* p) { *p = v; }
__device__ inline void storeC(float v, __hip_bfloat16* p) { *p = __float2bfloat16(v); }
__device__ inline short bf16s(float f) {
    __hip_bfloat16 h = __float2bfloat16(f);
    short s; __builtin_memcpy(&s, &h, 2); return s;
}
__device__ inline float bfLo(unsigned u) { return __uint_as_float(u << 16); }
__device__ inline float bfHi(unsigned u) { return __uint_as_float(u & 0xFFFF0000u); }
__device__ inline float readlaneF(float v, int l) {
    return __uint_as_float((unsigned)__builtin_amdgcn_readlane((int)__float_as_uint(v), l));
}

// -------- per-row inverse L2 norm (f32), wave per row --------
__global__ __launch_bounds__(256)
void rownorm_inv_k(const float* __restrict__ in, float* __restrict__ sc, int M, int Dd)
{
    int wave = (blockIdx.x * blockDim.x + threadIdx.x) >> 6;
    int lane = threadIdx.x & 63;
    if (wave >= M) return;
    float ss = 0.f;
    for (int k = lane; k < Dd; k += 64) {
        float x = in[(size_t)wave * Dd + k];
        ss += x * x;
    }
    for (int o = 32; o > 0; o >>= 1) ss += __shfl_down(ss, o);
    if (lane == 0) sc[wave] = 1.f / fmaxf(sqrtf(ss), 1e-12f);
}

// -------- B-panel prep --------
// l1 panel, 416 rows: group g = row/208; cc = row-208g in [0,208);
// valid cc<200: s = 2g + (cc>=100), h=s&1, off=(s>>1)*200.
__global__ void prep_bt_l1(const float* __restrict__ ah, __hip_bfloat16* __restrict__ Bt)
{
    int c = blockIdx.x, k = threadIdx.x;
    if (k >= KP) return;
    int g = (c >= 208) ? 1 : 0;
    int cc = c - g * 208;
    float v = 0.f;
    if (cc < 200 && k < 200) {
        int hh = (cc >= 100) ? 1 : 0;
        int idx = cc - hh * 100;
        v = ah[(size_t)(hh * 100 + idx) * 600 + g * 200 + k];
    }
    Bt[(size_t)c * KP + k] = __float2bfloat16(v);
}
// l2 panel, 416 rows: g = row/208; cc = row-208g; valid cc<200:
// v = ao[cc*600 + g*200 + k]
__global__ void prep_bt_l2(const float* __restrict__ ao, __hip_bfloat16* __restrict__ Bt)
{
    int c = blockIdx.x, k = threadIdx.x;
    if (k >= KP) return;
    int g = (c >= 208) ? 1 : 0;
    int cc = c - g * 208;
    float v = (cc < 200 && k < 200) ? ao[(size_t)cc * 600 + g * 200 + k] : 0.f;
    Bt[(size_t)c * KP + k] = __float2bfloat16(v);
}
__global__ void prep_bt_fin(const float* __restrict__ W, __hip_bfloat16* __restrict__ Bt)
{
    int c = blockIdx.x, k = threadIdx.x;
    if (k >= KP) return;
    float v = (c < 200 && k < 200) ? W[(size_t)k * 200 + c] : 0.f;
    Bt[(size_t)c * KP + k] = __float2bfloat16(v);
}

// ---- layer-1: 512 thr / 128 rows; flavor y: 0=x1+s1, 1=pB+s2, 2=entW -----
__global__ __launch_bounds__(512)
void l1_both_k(const float* __restrict__ ent, const float* __restrict__ nscale,
               const __hip_bfloat16* __restrict__ Bt,  // [624][KP]: 2x208 l1 + 208 W_ent
               const float* __restrict__ a2h,          // [200] (= [2][100])
               __hip_bfloat16* __restrict__ x1,        // [N][KP]
               __hip_bfloat16* __restrict__ pB,        // [N][PBS]: pB + s2 + entW
               float* __restrict__ s1,                 // [2][N]
               int M)
{
    __shared__ __align__(16) __hip_bfloat16 Bs[208 * LDSW];  // 16.6 KB
    int tid = threadIdx.x, wave = tid >> 6, lane = tid & 63;
    int quad = lane >> 4, l16 = lane & 15;
    int f = blockIdx.y;                 // flavor
    int rowbase = f * 208;
    int m0 = blockIdx.x * 128;
    int arow = m0 + wave * 16 + l16;
    bool rok = arow < M;
    float nsc = rok ? nscale[arow] : 0.f;
    const float* arp = ent + (size_t)arow * DD;
    int orow = m0 + wave * 16 + quad * 4;
    const __hip_bfloat16* Bsrc = Bt + (size_t)rowbase * KP;

    f32x4 acc[13];
#pragma unroll
    for (int t = 0; t < 13; t++) acc[t] = (f32x4){0.f, 0.f, 0.f, 0.f};

    short8 stg[2];
#pragma unroll
    for (int i = 0; i < 2; i++) {
        int idx = tid + i * 512;
        if (idx < 832) {
            int r = idx >> 2, c8 = idx & 3;
            stg[i] = *(const short8*)(Bsrc + (size_t)r * KP + c8 * 8);
        }
    }
    for (int ch = 0; ch < 7; ch++) {
        // issue A-row slice load early: overlaps LDS-write + barrier
        int kb = ch * 32 + quad * 8;
        float av[8];
        if (rok && kb + 8 <= DD) {
            const float4* p = (const float4*)(arp + kb);
            float4 u0 = p[0], u1 = p[1];
            av[0] = u0.x; av[1] = u0.y; av[2] = u0.z; av[3] = u0.w;
            av[4] = u1.x; av[5] = u1.y; av[6] = u1.z; av[7] = u1.w;
        } else {
#pragma unroll
            for (int j = 0; j < 8; j++) av[j] = (rok && kb + j < DD) ? arp[kb + j] : 0.f;
        }
#pragma unroll
        for (int i = 0; i < 2; i++) {
            int idx = tid + i * 512;
            if (idx < 832) {
                int r = idx >> 2, c8 = idx & 3;
                *(short8*)(Bs + r * LDSW + c8 * 8) = stg[i];
            }
        }
        __syncthreads();
        if (ch < 6) {
            int kb2 = (ch + 1) * 32;
#pragma unroll
            for (int i = 0; i < 2; i++) {
                int idx = tid + i * 512;
                if (idx < 832) {
                    int r = idx >> 2, c8 = idx & 3;
                    stg[i] = *(const short8*)(Bsrc + (size_t)r * KP + kb2 + c8 * 8);
                }
            }
        }
        short8 a;
#pragma unroll
        for (int j = 0; j < 8; j++) a[j] = bf16s(av[j] * nsc);
        const __hip_bfloat16* bp = Bs + (size_t)l16 * LDSW + quad * 8;
#pragma unroll
        for (int t = 0; t < 13; t++) {
            short8 b = *(const short8*)(bp + (size_t)t * 16 * LDSW);
            acc[t] = __builtin_amdgcn_mfma_f32_16x16x32_bf16(a, b, acc[t], 0, 0, 0);
        }
        __syncthreads();
    }

    // ---- flavor epilogues ----
    if (f == 2) {
        // entW -> pB row pad shorts [224..423]
#pragma unroll
        for (int t = 0; t < 13; t++) {
            int cc = t * 16 + l16;
#pragma unroll
            for (int i = 0; i < 4; i++) {
                int gm = orow + i;
                if (cc < OD && gm < M)
                    pB[(size_t)gm * PBS + 224 + cc] = __float2bfloat16(acc[t][i]);
            }
        }
        return;
    }

    float dLo[4] = {0,0,0,0}, dHi[4] = {0,0,0,0};
#pragma unroll
    for (int t = 0; t < 13; t++) {
        int cc = t * 16 + l16;
        bool cok = cc < 200;
        float w = cok ? a2h[cc] : 0.f;
#pragma unroll
        for (int i = 0; i < 4; i++) {
            float v = acc[t][i];
            float vw = v * w;
            if (cc < 100) dLo[i] += vw;
            else if (cok) dHi[i] += vw;
            int gm = orow + i;
            if (cok && gm < M) {
                if (f == 0) x1[(size_t)gm * KP + cc] = __float2bfloat16(v);
                else {
                    int hh = (cc >= 100) ? 1 : 0;
                    pB[(size_t)gm * PBS + (cc - hh * 100) * 2 + hh] = __float2bfloat16(v);
                }
            }
        }
    }
    if (f == 0) {
        // x1 pad zeros (cols 200-223): replaces the memset
        if (l16 < 12)
#pragma unroll
            for (int i = 0; i < 4; i++) {
                int gm = orow + i;
                if (gm < M) *(unsigned*)(x1 + (size_t)gm * KP + 200 + 2 * l16) = 0u;
            }
    }
#pragma unroll
    for (int msk = 1; msk < 16; msk <<= 1)
#pragma unroll
        for (int i = 0; i < 4; i++) {
            dLo[i] += __shfl_xor(dLo[i], msk);
            dHi[i] += __shfl_xor(dHi[i], msk);
        }
    if (l16 == 0)
#pragma unroll
        for (int i = 0; i < 4; i++) {
            int gm = orow + i;
            if (gm < M) {
                if (f == 0) { s1[gm] = dLo[i]; s1[M + gm] = dHi[i]; }
                else {
                    float2 sv; sv.x = dLo[i]; sv.y = dHi[i];
                    *(float2*)((char*)pB + (size_t)gm * (PBS * 2) + 400) = sv;
                }
            }
        }
}

// ---- layer-2: 512 thr / 128 rows; flavor y: 0=x1A1+s1, 1=x1A2+s2 ---------
__global__ __launch_bounds__(512)
void l2_proj_k(const __hip_bfloat16* __restrict__ x1,  // [N][KP]
               const __hip_bfloat16* __restrict__ Bt,  // [416][KP]
               const float* __restrict__ a2o,          // [200]
               float* __restrict__ x1A1,               // [N][200] (out_ent)
               __hip_bfloat16* __restrict__ x1A2,      // [N][PBS], s2 in pad
               float* __restrict__ s1, int M)
{
    __shared__ __align__(16) __hip_bfloat16 Bs[208 * LDSW];  // 16.6 KB
    int tid = threadIdx.x, wave = tid >> 6, lane = tid & 63;
    int quad = lane >> 4, l16 = lane & 15;
    int f = blockIdx.y;
    int rowbase = f * 208;
    int m0 = blockIdx.x * 128;
    int arow = m0 + wave * 16 + l16;
    bool rok = arow < M;
    const __hip_bfloat16* arp = x1 + (size_t)arow * KP;
    const __hip_bfloat16* Bsrc = Bt + (size_t)rowbase * KP;

    f32x4 acc[13];
#pragma unroll
    for (int t = 0; t < 13; t++) acc[t] = (f32x4){0.f, 0.f, 0.f, 0.f};

    short8 stg[2];
#pragma unroll
    for (int i = 0; i < 2; i++) {
        int idx = tid + i * 512;
        if (idx < 832) {
            int r = idx >> 2, c8 = idx & 3;
            stg[i] = *(const short8*)(Bsrc + (size_t)r * KP + c8 * 8);
        }
    }
    for (int ch = 0; ch < 7; ch++) {
        short8 a = (short8){0,0,0,0,0,0,0,0};
        if (rok) a = *(const short8*)(arp + ch * 32 + quad * 8);
#pragma unroll
        for (int i = 0; i < 2; i++) {
            int idx = tid + i * 512;
            if (idx < 832) {
                int r = idx >> 2, c8 = idx & 3;
                *(short8*)(Bs + r * LDSW + c8 * 8) = stg[i];
            }
        }
        __syncthreads();
        if (ch < 6) {
            int kb2 = (ch + 1) * 32;
#pragma unroll
            for (int i = 0; i < 2; i++) {
                int idx = tid + i * 512;
                if (idx < 832) {
                    int r = idx >> 2, c8 = idx & 3;
                    stg[i] = *(const short8*)(Bsrc + (size_t)r * KP + kb2 + c8 * 8);
                }
            }
        }
        const __hip_bfloat16* bp = Bs + (size_t)l16 * LDSW + quad * 8;
#pragma unroll
        for (int t = 0; t < 13; t++) {
            short8 b = *(const short8*)(bp + (size_t)t * 16 * LDSW);
            acc[t] = __builtin_amdgcn_mfma_f32_16x16x32_bf16(a, b, acc[t], 0, 0, 0);
        }
        __syncthreads();
    }

    int orow = m0 + wave * 16 + quad * 4;
    float d[4] = {0,0,0,0};
#pragma unroll
    for (int t = 0; t < 13; t++) {
        int cc = t * 16 + l16;
        bool cok = cc < 200;
        float w = cok ? a2o[cc] : 0.f;
#pragma unroll
        for (int i = 0; i < 4; i++) {
            float v = acc[t][i];
            d[i] += v * w;
            int gm = orow + i;
            if (cok && gm < M) {
                if (f == 0) x1A1[(size_t)gm * OD + cc] = v;
                else x1A2[(size_t)gm * PBS + cc] = __float2bfloat16(v);
            }
        }
    }
#pragma unroll
    for (int msk = 1; msk < 16; msk <<= 1)
#pragma unroll
        for (int i = 0; i < 4; i++) d[i] += __shfl_xor(d[i], msk);
    if (l16 == 0)
#pragma unroll
        for (int i = 0; i < 4; i++) {
            int gm = orow + i;
            if (gm < M) {
                if (f == 0) s1[gm] = d[i];
                else *(float*)((char*)x1A2 + (size_t)gm * (PBS * 2) + 400) = d[i];
            }
        }
}

// -------- generic MFMA GEMM (small R-sized matmuls); cs/co = C col-stride --
#define KPAD 48
template<bool BTr, typename AT, typename CT>
__global__ __launch_bounds__(256)
void gemm_mfma_k(const AT* __restrict__ A, int lda, const float* __restrict__ ascale,
                 const float* __restrict__ B, int ldb, int colOff,
                 CT* __restrict__ C, int ldc, int cs, int co,
                 int M, int Nc, int K)
{
    __shared__ __align__(16) __hip_bfloat16 As[64][KPAD];
    __shared__ __align__(16) __hip_bfloat16 Bs[64][KPAD];
    int tid  = threadIdx.x;
    int wave = tid >> 6, lane = tid & 63;
    int quad = lane >> 4, l16 = lane & 15;
    int n0 = blockIdx.x * 64, m0 = blockIdx.y * 64;
    f32x4 acc[4];
#pragma unroll
    for (int t = 0; t < 4; t++) acc[t] = (f32x4){0.f, 0.f, 0.f, 0.f};

    for (int k0 = 0; k0 < K; k0 += 32) {
        {
            int m = tid >> 2, kc = (tid & 3) * 8;
            int gm = m0 + m;
            float scale = (ascale && gm < M) ? ascale[gm] : 1.f;
#pragma unroll
            for (int j = 0; j < 8; j++) {
                int gk = k0 + kc + j;
                float v = 0.f;
                if (gm < M && gk < K) v = toF(A[(size_t)gm * lda + gk]) * scale;
                As[m][kc + j] = __float2bfloat16(v);
            }
        }
        if (BTr) {
            int n = tid >> 2, kc = (tid & 3) * 8;
            int gn = n0 + n;
#pragma unroll
            for (int j = 0; j < 8; j++) {
                int gk = k0 + kc + j;
                float v = 0.f;
                if (gn < Nc && gk < K) v = B[(size_t)gn * ldb + colOff + gk];
                Bs[n][kc + j] = __float2bfloat16(v);
            }
        } else {
            int n = tid & 63, kq = tid >> 6;
            int gn = n0 + n;
#pragma unroll
            for (int j = 0; j < 8; j++) {
                int gk = k0 + kq * 8 + j;
                float v = 0.f;
                if (gn < Nc && gk < K) v = B[(size_t)gk * ldb + gn];
                Bs[n][kq * 8 + j] = __float2bfloat16(v);
            }
        }
        __syncthreads();
        short8 a = *(const short8*)&As[wave * 16 + l16][quad * 8];
#pragma unroll
        for (int t = 0; t < 4; t++) {
            short8 b = *(const short8*)&Bs[t * 16 + l16][quad * 8];
            acc[t] = __builtin_amdgcn_mfma_f32_16x16x32_bf16(a, b, acc[t], 0, 0, 0);
        }
        __syncthreads();
    }
#pragma unroll
    for (int t = 0; t < 4; t++) {
        int gn = n0 + t * 16 + l16;
        if (gn >= Nc) continue;
#pragma unroll
        for (int i = 0; i < 4; i++) {
            int gm = m0 + wave * 16 + quad * 4 + i;
            if (gm < M) storeC(acc[t][i], &C[(size_t)gm * ldc + (size_t)gn * cs + co]);
        }
    }
}

// -------- row-dot (srel); ks = k-stride in mat, os/oo = output stride ------
template<typename T>
__global__ __launch_bounds__(256)
void rowdot_k(const T* __restrict__ mat, int ld, int coff, int ks,
              const float* __restrict__ vec,
              float* __restrict__ outp, int os, int oo, int M, int Dd)
{
    int wave = (blockIdx.x * blockDim.x + threadIdx.x) >> 6;
    int lane = threadIdx.x & 63;
    if (wave >= M) return;
    float s = 0.f;
    for (int k = lane; k < Dd; k += 64)
        s += toF(mat[(size_t)wave * ld + coff + (size_t)k * ks]) * vec[k];
    for (int o = 32; o > 0; o >>= 1) s += __shfl_down(s, o);
    if (lane == 0) outp[wave * os + oo] = s;
}

// -------- CSR build --------
__device__ inline void decode_edge(const int* __restrict__ el, int E,
                                   const int* __restrict__ etype,
                                   const int* __restrict__ tin, int e,
                                   int& dst, int& src, int& r1, int& r2)
{
    if (e < E) { dst = el[e]; src = el[E + e]; r1 = etype[e]; r2 = -1; }
    else {
        int j = e - E;
        dst = tin[j * 4 + 3]; src = tin[j * 4 + 0];
        r1 = tin[j * 4 + 1];  r2 = tin[j * 4 + 2];
    }
}

__global__ void hist_k(const int* __restrict__ el, int E, const int* __restrict__ etype,
                       const int* __restrict__ tin, int Etot, int* __restrict__ cnt)
{
    int e = blockIdx.x * blockDim.x + threadIdx.x;
    if (e >= Etot) return;
    int dst, src, r1, r2; decode_edge(el, E, etype, tin, e, dst, src, r1, r2);
    atomicAdd(&cnt[dst], 1);
}

__global__ __launch_bounds__(1024)
void scan1_k(const int* __restrict__ cnt, int* __restrict__ start,
             int* __restrict__ aux, int n)
{
    __shared__ int tmp[1024];
    int i = blockIdx.x * 1024 + threadIdx.x;
    int v = (i < n) ? cnt[i] : 0;
    tmp[threadIdx.x] = v;
    __syncthreads();
    for (int o = 1; o < 1024; o <<= 1) {
        int t = (threadIdx.x >= (unsigned)o) ? tmp[threadIdx.x - o] : 0;
        __syncthreads();
        tmp[threadIdx.x] += t;
        __syncthreads();
    }
    if (i < n) start[i] = tmp[threadIdx.x] - v;
    if (threadIdx.x == 1023) aux[blockIdx.x] = tmp[1023];
}

__global__ void scan2_k(int* __restrict__ aux, int nb)
{
    if (threadIdx.x == 0 && blockIdx.x == 0) {
        int s = 0;
        for (int i = 0; i < nb; i++) { int v = aux[i]; aux[i] = s; s += v; }
    }
}

__global__ __launch_bounds__(1024)
void scan3_k(int* __restrict__ start, const int* __restrict__ aux, int n, int Etot)
{
    int i = blockIdx.x * 1024 + threadIdx.x;
    if (i < n) start[i] += aux[blockIdx.x];
    if (i == 0) start[n] = Etot;
}

// csr entry: .x = src, .y = r1 | (r2s<<16), r2s==0xFFFF means "no r2"
__global__ void fill_k(const int* __restrict__ el, int E, const int* __restrict__ etype,
                       const int* __restrict__ tin, int Etot,
                       const int* __restrict__ start, int* __restrict__ fill,
                       int2* __restrict__ csr)
{
    int e = blockIdx.x * blockDim.x + threadIdx.x;
    if (e >= Etot) return;
    int dst, src, r1, r2; decode_edge(el, E, etype, tin, e, dst, src, r1, r2);
    int p = start[dst] + atomicAdd(&fill[dst], 1);
    unsigned r2s = (r2 >= 0) ? (unsigned)r2 : 0xFFFFu;
    csr[p] = make_int2(src, (int)((r2s << 16) | (unsigned)r1));
}

// -------- layer-1 gather: wave/dst, two-phase (lane-parallel scalars) ------
__global__ __launch_bounds__(256)
void gather_l1_k(const int* __restrict__ start, const int2* __restrict__ csr,
                 const float* __restrict__ s1,        // [2][N] dst-side
                 const float* __restrict__ srel2,     // [R][2]
                 const __hip_bfloat16* __restrict__ pB,   // [N][PBS] interleaved
                 const float* __restrict__ rpf2,      // [R][100][2]
                 __hip_bfloat16* __restrict__ x1, int N)  // [N][KP]
{
    int n = (blockIdx.x * blockDim.x + threadIdx.x) >> 6;
    int lane = threadIdx.x & 63;
    if (n >= N) return;
    int b0 = __builtin_amdgcn_readfirstlane(start[n]);
    int b1 = __builtin_amdgcn_readfirstlane(start[n + 1]);
    float s1h0 = s1[n], s1h1 = s1[N + n];
    float rsl0 = 0.f, rsl1 = 0.f;        // per-lane partial rowsums
    float2 acc0 = {0.f, 0.f};            // k0: (h0, h1)
    float2 acc1 = {0.f, 0.f};            // k1
    int k0 = lane;
    bool k1ok = lane < 36;
    int k1c = k1ok ? (lane + 64) : 0;

    for (int c0 = b0; c0 < b1; c0 += 64) {
        int cnt = min(64, b1 - c0);
        // ---- phase A: lane e computes edge (c0+e)'s scalars; all loads in flight
        float w0 = 0.f, w1 = 0.f;
        int srcL = 0, eyL = 0;
        if (lane < cnt) {
            int2 eg = csr[c0 + lane];
            srcL = eg.x; eyL = eg.y;
            int r1 = eyL & 0xFFFF;
            unsigned r2u = (unsigned)eyL >> 16;
            float2 sA = *(const float2*)((const char*)pB + (size_t)(unsigned)srcL * (PBS * 2) + 400);
            float2 sr = *(const float2*)(srel2 + r1 * 2);
            float z0 = s1h0 + sA.x + sr.x;
            float z1 = s1h1 + sA.y + sr.y;
            if (r2u != 0xFFFFu) {
                float2 sr2v = *(const float2*)(srel2 + r2u * 2);
                z0 += sr2v.x; z1 += sr2v.y;
            }
            w0 = expf(-(z0 > 0.f ? z0 : 0.2f * z0));
            w1 = expf(-(z1 > 0.f ? z1 : 0.2f * z1));
            rsl0 += w0; rsl1 += w1;
        }
        // ---- phase B: per-edge feature FMA; 4-edge-batched pB loads
        for (int e0 = 0; e0 < cnt; e0 += 4) {
            int ec = min(4, cnt - e0);
            unsigned pw0[4], pw1[4];
#pragma unroll
            for (int u = 0; u < 4; u++) {
                if (u < ec) {
                    int s = __builtin_amdgcn_readlane(srcL, e0 + u);
                    const __hip_bfloat16* rA = pB + (size_t)(unsigned)s * PBS;
                    pw0[u] = *(const unsigned*)(rA + 2 * k0);
                    pw1[u] = *(const unsigned*)(rA + 2 * k1c);
                }
            }
#pragma unroll
            for (int u = 0; u < 4; u++) {
                if (u < ec) {
                    int ey = __builtin_amdgcn_readlane(eyL, e0 + u);
                    int r1 = ey & 0xFFFF;
                    unsigned r2u = (unsigned)ey >> 16;
                    float we0 = readlaneF(w0, e0 + u);
                    float we1 = readlaneF(w1, e0 + u);
                    const float2* q1 = (const float2*)(rpf2 + (unsigned)r1 * 200);
                    float2 q1a = q1[k0], q1b = q1[k1c];
                    float v00 = bfLo(pw0[u]) + q1a.x;
                    float v01 = bfHi(pw0[u]) + q1a.y;
                    float v10 = bfLo(pw1[u]) + q1b.x;
                    float v11 = bfHi(pw1[u]) + q1b.y;
                    if (r2u != 0xFFFFu) {
                        const float2* q2 = (const float2*)(rpf2 + r2u * 200);
                        float2 q2a = q2[k0], q2b = q2[k1c];
                        v00 += q2a.x; v01 += q2a.y;
                        v10 += q2b.x; v11 += q2b.y;
                    }
                    acc0.x += we0 * v00; acc0.y += we1 * v01;
                    acc1.x += we0 * v10; acc1.y += we1 * v11;
                }
            }
        }
    }

    // wave-reduce rowsums (butterfly -> all lanes)
#pragma unroll
    for (int o = 1; o < 64; o <<= 1) {
        rsl0 += __shfl_xor(rsl0, o);
        rsl1 += __shfl_xor(rsl1, o);
    }
    float i0 = rsl0 > 0.f ? 1.f / rsl0 : 0.f;
    float i1 = rsl1 > 0.f ? 1.f / rsl1 : 0.f;
    __hip_bfloat16* xr = x1 + (size_t)n * KP;
    float hp;
    hp = rsl0 > 0.f ? toF(xr[k0]) + acc0.x * i0 : 0.f;
    xr[k0] = __float2bfloat16(hp > 0.f ? hp : expf(hp) - 1.f);
    hp = rsl1 > 0.f ? toF(xr[100 + k0]) + acc0.y * i1 : 0.f;
    xr[100 + k0] = __float2bfloat16(hp > 0.f ? hp : expf(hp) - 1.f);
    if (k1ok) {
        int k1 = lane + 64;
        hp = rsl0 > 0.f ? toF(xr[k1]) + acc1.x * i0 : 0.f;
        xr[k1] = __float2bfloat16(hp > 0.f ? hp : expf(hp) - 1.f);
        hp = rsl1 > 0.f ? toF(xr[100 + k1]) + acc1.y * i1 : 0.f;
        xr[100 + k1] = __float2bfloat16(hp > 0.f ? hp : expf(hp) - 1.f);
    }
}

// -------- layer-2 gather: wave/dst, two-phase; fused +entW + l2norm -------
__global__ __launch_bounds__(256)
void gather_l2_k(const int* __restrict__ start, const int2* __restrict__ csr,
                 const float* __restrict__ s1,
                 const float* __restrict__ srel,          // [R]
                 const __hip_bfloat16* __restrict__ x1A2, // [N][PBS]: feats+s2+entW
                 const float* __restrict__ rpf,           // [R][200]
                 const float* __restrict__ maskf,
                 float* __restrict__ outent, int N)       // [N][200], holds x1A1
{
    int n = (blockIdx.x * blockDim.x + threadIdx.x) >> 6;
    int lane = threadIdx.x & 63;
    if (n >= N) return;
    int b0 = __builtin_amdgcn_readfirstlane(start[n]);
    int b1 = __builtin_amdgcn_readfirstlane(start[n + 1]);
    float s1n = s1[n];
    float rsl = 0.f;
    float2 a0 = {0.f, 0.f};   // k = 2*lane, 2*lane+1
    float2 a1 = {0.f, 0.f};   // k = 128+2*lane, +1 (lane<36)
    int j0 = 2 * lane;
    bool j1ok = lane < 36;
    int j1 = j1ok ? (128 + 2 * lane) : 0;

    for (int c0 = b0; c0 < b1; c0 += 64) {
        int cnt = min(64, b1 - c0);
        // ---- phase A: lane-parallel per-edge scalars
        float w = 0.f;
        int srcL = 0, eyL = 0;
        if (lane < cnt) {
            int2 eg = csr[c0 + lane];
            srcL = eg.x; eyL = eg.y;
            int r1 = eyL & 0xFFFF;
            unsigned r2u = (unsigned)eyL >> 16;
            float s2v = *(const float*)((const char*)x1A2 + (size_t)(unsigned)srcL * (PBS * 2) + 400);
            float sr = srel[r1];
            if (r2u != 0xFFFFu) sr += srel[r2u];
            float z = s1n + s2v + sr;
            w = expf(-(z > 0.f ? z : 0.2f * z));
            rsl += w;
        }
        // ---- phase B: per-edge feature FMA; 4-edge-batched feature loads
        for (int e0 = 0; e0 < cnt; e0 += 4) {
            int ec = min(4, cnt - e0);
            unsigned xw0[4], xw1[4];
#pragma unroll
            for (int u = 0; u < 4; u++) {
                if (u < ec) {
                    int s = __builtin_amdgcn_readlane(srcL, e0 + u);
                    const __hip_bfloat16* xs = x1A2 + (size_t)(unsigned)s * PBS;
                    xw0[u] = *(const unsigned*)(xs + j0);
                    xw1[u] = *(const unsigned*)(xs + j1);
                }
            }
#pragma unroll
            for (int u = 0; u < 4; u++) {
                if (u < ec) {
                    int ey = __builtin_amdgcn_readlane(eyL, e0 + u);
                    int r1 = ey & 0xFFFF;
                    unsigned r2u = (unsigned)ey >> 16;
                    float we = readlaneF(w, e0 + u);
                    const float* q1 = rpf + (unsigned)r1 * 200;
                    float2 q1a = *(const float2*)(q1 + j0);
                    float2 q1b = *(const float2*)(q1 + j1);
                    float v0x = bfLo(xw0[u]) + q1a.x;
                    float v0y = bfHi(xw0[u]) + q1a.y;
                    float v1x = bfLo(xw1[u]) + q1b.x;
                    float v1y = bfHi(xw1[u]) + q1b.y;
                    if (r2u != 0xFFFFu) {
                        const float* q2 = rpf + r2u * 200;
                        float2 q2a = *(const float2*)(q2 + j0);
                        float2 q2b = *(const float2*)(q2 + j1);
                        v0x += q2a.x; v0y += q2a.y;
                        v1x += q2b.x; v1y += q2b.y;
                    }
                    a0.x += we * v0x; a0.y += we * v0y;
                    a1.x += we * v1x; a1.y += we * v1y;
                }
            }
        }
    }

#pragma unroll
    for (int o = 1; o < 64; o <<= 1) rsl += __shfl_xor(rsl, o);
    float inv = rsl > 0.f ? 1.f / rsl : 0.f;
    float mk = maskf[n];
    float* orow = outent + (size_t)n * 200;
    const __hip_bfloat16* ew = x1A2 + (size_t)n * PBS + 224;  // own dst row's entW

    float2 o0 = *(const float2*)(orow + j0);
    unsigned e0b = *(const unsigned*)(ew + j0);
    float h0x = rsl > 0.f ? o0.x + a0.x * inv : 0.f;
    float h0y = rsl > 0.f ? o0.y + a0.y * inv : 0.f;
    float v0x = mk * (h0x > 0.f ? h0x : expf(h0x) - 1.f) + bfLo(e0b);
    float v0y = mk * (h0y > 0.f ? h0y : expf(h0y) - 1.f) + bfHi(e0b);
    float ssq = v0x * v0x + v0y * v0y;
    float v1x = 0.f, v1y = 0.f;
    if (j1ok) {
        float2 o1 = *(const float2*)(orow + j1);
        unsigned e1b = *(const unsigned*)(ew + j1);
        float h1x = rsl > 0.f ? o1.x + a1.x * inv : 0.f;
        float h1y = rsl > 0.f ? o1.y + a1.y * inv : 0.f;
        v1x = mk * (h1x > 0.f ? h1x : expf(h1x) - 1.f) + bfLo(e1b);
        v1y = mk * (h1y > 0.f ? h1y : expf(h1y) - 1.f) + bfHi(e1b);
        ssq += v1x * v1x + v1y * v1y;
    }
#pragma unroll
    for (int o = 1; o < 64; o <<= 1) ssq += __shfl_xor(ssq, o);
    float sc = 1.f / fmaxf(sqrtf(ssq), 1e-12f);
    float2 r0; r0.x = v0x * sc; r0.y = v0y * sc;
    *(float2*)(orow + j0) = r0;
    if (j1ok) {
        float2 r1; r1.x = v1x * sc; r1.y = v1y * sc;
        *(float2*)(orow + j1) = r1;
    }
}

__global__ void scatter_mask_k(const int* __restrict__ batch, int NB,
                               float* __restrict__ masko)
{
    int i = blockIdx.x * blockDim.x + threadIdx.x;
    if (i >= NB) return;
    masko[batch[i]] = 1.0f;
}

extern "C" void kernel_launch(void* const* d_in, const int* in_sizes, int n_in,
                              void* d_out, int out_size, void* d_ws, size_t ws_size,
                              hipStream_t stream)
{
    const float* ent      = (const float*)d_in[0];
    const float* rel      = (const float*)d_in[1];
    const float* W_ent    = (const float*)d_in[2];
    const float* W_gat    = (const float*)d_in[3];
    const float* a_heads  = (const float*)d_in[4];
    const float* a2_heads = (const float*)d_in[5];
    const float* a_out    = (const float*)d_in[6];
    const float* a2_out   = (const float*)d_in[7];
    const int* batch = (const int*)d_in[8];
    const int* el    = (const int*)d_in[9];
    const int* etype = (const int*)d_in[10];
    const int* tin   = (const int*)d_in[11];

    const int N   = in_sizes[0] / DD;   // 50000
    const int R   = in_sizes[1] / DD;   // 500
    const int NB  = in_sizes[8];        // 20000
    const int E   = in_sizes[9] / 2;    // 150000
    const int ENH = in_sizes[11] / 4;   // 30000
    const int Etot = E + ENH;

    // ---- workspace (~70 MB) ----
    char* ws = (char*)d_ws;
    size_t off = 0;
    auto take = [&](size_t bytes) { size_t o = off; off += (bytes + 255) & ~(size_t)255; return o; };
    size_t o_R1   = take((size_t)N * KP * 2);     // x1 bf16 [N][KP]
    size_t o_R2   = take((size_t)N * PBS * 2);    // pB/x1A2 [N][PBS] + s2 + entW
    size_t o_rpf  = take((size_t)2 * R * 100 * 4);// rpf2 [R][100][2] / layer2 rpf [R][200]
    size_t o_bt1  = take((size_t)416 * KP * 2);   // l1 panel (186368 B, 256-mult)
    size_t o_btf  = take((size_t)208 * KP * 2);   // W_ent panel: ADJACENT to bt1
    size_t o_bt2  = take((size_t)416 * KP * 2);
    size_t o_nsc  = take((size_t)N * 4);
    size_t o_s1   = take((size_t)2 * N * 4);      // aliased by cnt during CSR build
    size_t o_srel = take((size_t)2 * R * 4);      // [R][2] layer1 / [R] layer2
    size_t o_csr  = take((size_t)Etot * 8);
    size_t o_str  = take((size_t)(N + 1) * 4);
    size_t o_aux  = take((size_t)64 * 4);

    __hip_bfloat16* x1   = (__hip_bfloat16*)(ws + o_R1);
    __hip_bfloat16* pB   = (__hip_bfloat16*)(ws + o_R2);
    __hip_bfloat16* x1A2 = (__hip_bfloat16*)(ws + o_R2);
    float* rpf2   = (float*)(ws + o_rpf);
    __hip_bfloat16* bt1 = (__hip_bfloat16*)(ws + o_bt1);  // [624][KP] combined w/ btf
    __hip_bfloat16* btf = (__hip_bfloat16*)(ws + o_btf);
    __hip_bfloat16* bt2 = (__hip_bfloat16*)(ws + o_bt2);
    float* nscale = (float*)(ws + o_nsc);
    float* s1     = (float*)(ws + o_s1);
    float* srel2  = (float*)(ws + o_srel);
    int2*  csr    = (int2*)(ws + o_csr);
    int*   cnt    = (int*)(ws + o_s1);   // CSR-build scratch; dead before l1_both_k writes s1
    int*   startA = (int*)(ws + o_str);
    int*   aux    = (int*)(ws + o_aux);

    float* out       = (float*)d_out;
    float* out_ent   = out;                                     // [N,200]
    float* out_rel_o = out + (size_t)N * OD;                    // [500,200]
    float* out_mask  = out + (size_t)N * OD + (size_t)R * OD;   // [N]

    const int nblk2 = cdiv(N, 128);
    const int nbScan = cdiv(N, 1024);

    // A. prep: norms, B panels (bt1[416] + btf[208] contiguous -> 624 rows)
    rownorm_inv_k<<<cdiv(N, 4), 256, 0, stream>>>(ent, nscale, N, DD);
    prep_bt_l1<<<416, 256, 0, stream>>>(a_heads, bt1);
    prep_bt_fin<<<208, 256, 0, stream>>>(W_ent, btf);
    prep_bt_l2<<<416, 256, 0, stream>>>(a_out, bt2);
    gemm_mfma_k<false, float, float><<<dim3(cdiv(OD, 64), cdiv(R, 64)), 256, 0, stream>>>(
        rel, DD, nullptr, W_gat, OD, 0, out_rel_o, OD, 1, 0, R, OD, DD);

    // A2. CSR build (dst-grouped edge lists)
    hipMemsetAsync(cnt, 0, (size_t)N * 4, stream);
    hist_k<<<cdiv(Etot, 256), 256, 0, stream>>>(el, E, etype, tin, Etot, cnt);
    scan1_k<<<nbScan, 1024, 0, stream>>>(cnt, startA, aux, N);
    scan2_k<<<1, 64, 0, stream>>>(aux, nbScan);
    scan3_k<<<nbScan, 1024, 0, stream>>>(startA, aux, N, Etot);
    hipMemsetAsync(cnt, 0, (size_t)N * 4, stream);
    fill_k<<<cdiv(Etot, 256), 256, 0, stream>>>(el, E, etype, tin, Etot, startA, cnt, csr);

    // B. layer-1 projections: flavors y0=x1+s1, y1=pB+s2, y2=entW
    l1_both_k<<<dim3(nblk2, 3), 512, 0, stream>>>(ent, nscale, bt1, a2_heads, x1, pB, s1, N);
    for (int h = 0; h < 2; h++) {
        const float* ah  = a_heads + (size_t)h * NHID * 600;
        const float* a2h = a2_heads + (size_t)h * NHID;
        gemm_mfma_k<true, float, float><<<dim3(cdiv(NHID, 64), cdiv(R, 64)), 256, 0, stream>>>(
            rel, DD, nullptr, ah, 600, 400, rpf2, 200, 2, h, R, NHID, DD);
        rowdot_k<float><<<cdiv(R, 4), 256, 0, stream>>>(
            rpf2, 200, h, 2, a2h, srel2, 2, h, R, NHID);
    }
    gather_l1_k<<<cdiv(N, 4), 256, 0, stream>>>(
        startA, csr, s1, srel2, pB, rpf2, x1, N);
    // pB feats dead; R2 rows become x1A2 (entW at shorts 224.. survives).

    // C. layer-2 projection (flavors y0=x1A1+s1, y1=x1A2+s2) + rel side
    l2_proj_k<<<dim3(nblk2, 2), 512, 0, stream>>>(x1, bt2, a2_out, out_ent, x1A2, s1, N);
    gemm_mfma_k<true, float, float><<<dim3(cdiv(OD, 64), cdiv(R, 64)), 256, 0, stream>>>(
        out_rel_o, OD, nullptr, a_out, 600, 400, rpf2, OD, 1, 0, R, OD, OD);
    rowdot_k<float><<<cdiv(R, 4), 256, 0, stream>>>(rpf2, OD, 0, 1, a2_out, srel2, 1, 0, R, OD);

    // D. mask; layer-2 gather (fused combine + entW + l2norm -> final out_ent)
    hipMemsetAsync(out_mask, 0, (size_t)N * 4, stream);
    scatter_mask_k<<<cdiv(NB, 256), 256, 0, stream>>>(batch, NB, out_mask);
    gather_l2_k<<<cdiv(N, 4), 256, 0, stream>>>(
        startA, csr, s1, srel2, x1A2, rpf2, out_mask, out_ent, N);
}

// Round 12
// 432.481 us; speedup vs baseline: 1.4268x; 1.0283x over previous
//
#include <hip/hip_runtime.h>
#include <hip/hip_bf16.h>
#include <math.h>

// SpKBGAT: N=50000, D=200, R=500, NHID=100, H=2, OD=200, E=150000, ENH=30000.
// R20: gathers were VALU-bound (40%) from double-issued narrow feature rounds
// (j0 64 lanes + j1 36 lanes). Fix: 4-value-per-lane layout (lane<50) --
// 1 uint2 + 1 float4 load per edge per lane, every unpack/add/FMA issued once.
// q1 loads batched with xw (24 dw live / 4-edge batch). Epilogues use paired
// bf16 dword writes (x1) / float4 (out_ent). Everything else = R19 (444.7us).
#define DD   200
#define NHID 100
#define OD   200
#define KP   224   // padded K (7 chunks of 32)
#define PBS  448   // row stride (bf16) for pB / x1A2 / entW: 896 B
                   // [0..199]: pB [k][h0,h1] pairs (l1) / x1A2 feats (l2)
                   // bytes 400..407: s2 floats;  shorts [224..423]: entW bf16
#define LDSW 40    // LDS row stride in shorts (80 B)

typedef __attribute__((ext_vector_type(8))) short short8;
typedef __attribute__((ext_vector_type(4))) float f32x4;

static inline int cdiv(int a, int b) { return (a + b - 1) / b; }

__device__ inline float toF(float x) { return x; }
__device__ inline float toF(__hip_bfloat16 x) { return __bfloat162float(x); }
__device__ inline void storeC(float v, float* p) { *p = v; }
__device__ inline void storeC(float v, __hip_bfloat16* p) { *p = __float2bfloat16(v); }
__device__ inline short bf16s(float f) {
    __hip_bfloat16 h = __float2bfloat16(f);
    short s; __builtin_memcpy(&s, &h, 2); return s;
}
__device__ inline float bfLo(unsigned u) { return __uint_as_float(u << 16); }
__device__ inline float bfHi(unsigned u) { return __uint_as_float(u & 0xFFFF0000u); }
__device__ inline unsigned packbf(float a, float b) {
    unsigned lo = (unsigned)(unsigned short)bf16s(a);
    unsigned hi = (unsigned)(unsigned short)bf16s(b);
    return lo | (hi << 16);
}
__device__ inline float readlaneF(float v, int l) {
    return __uint_as_float((unsigned)__builtin_amdgcn_readlane((int)__float_as_uint(v), l));
}

// -------- per-row inverse L2 norm (f32), wave per row --------
__global__ __launch_bounds__(256)
void rownorm_inv_k(const float* __restrict__ in, float* __restrict__ sc, int M, int Dd)
{
    int wave = (blockIdx.x * blockDim.x + threadIdx.x) >> 6;
    int lane = threadIdx.x & 63;
    if (wave >= M) return;
    float ss = 0.f;
    for (int k = lane; k < Dd; k += 64) {
        float x = in[(size_t)wave * Dd + k];
        ss += x * x;
    }
    for (int o = 32; o > 0; o >>= 1) ss += __shfl_down(ss, o);
    if (lane == 0) sc[wave] = 1.f / fmaxf(sqrtf(ss), 1e-12f);
}

// -------- B-panel prep --------
__global__ void prep_bt_l1(const float* __restrict__ ah, __hip_bfloat16* __restrict__ Bt)
{
    int c = blockIdx.x, k = threadIdx.x;
    if (k >= KP) return;
    int g = (c >= 208) ? 1 : 0;
    int cc = c - g * 208;
    float v = 0.f;
    if (cc < 200 && k < 200) {
        int hh = (cc >= 100) ? 1 : 0;
        int idx = cc - hh * 100;
        v = ah[(size_t)(hh * 100 + idx) * 600 + g * 200 + k];
    }
    Bt[(size_t)c * KP + k] = __float2bfloat16(v);
}
__global__ void prep_bt_l2(const float* __restrict__ ao, __hip_bfloat16* __restrict__ Bt)
{
    int c = blockIdx.x, k = threadIdx.x;
    if (k >= KP) return;
    int g = (c >= 208) ? 1 : 0;
    int cc = c - g * 208;
    float v = (cc < 200 && k < 200) ? ao[(size_t)cc * 600 + g * 200 + k] : 0.f;
    Bt[(size_t)c * KP + k] = __float2bfloat16(v);
}
__global__ void prep_bt_fin(const float* __restrict__ W, __hip_bfloat16* __restrict__ Bt)
{
    int c = blockIdx.x, k = threadIdx.x;
    if (k >= KP) return;
    float v = (c < 200 && k < 200) ? W[(size_t)k * 200 + c] : 0.f;
    Bt[(size_t)c * KP + k] = __float2bfloat16(v);
}

// ---- layer-1: 512 thr / 128 rows; flavor y: 0=x1+s1, 1=pB+s2, 2=entW -----
__global__ __launch_bounds__(512)
void l1_both_k(const float* __restrict__ ent, const float* __restrict__ nscale,
               const __hip_bfloat16* __restrict__ Bt,  // [624][KP]: 2x208 l1 + 208 W_ent
               const float* __restrict__ a2h,          // [200] (= [2][100])
               __hip_bfloat16* __restrict__ x1,        // [N][KP]
               __hip_bfloat16* __restrict__ pB,        // [N][PBS]: pB + s2 + entW
               float* __restrict__ s1,                 // [2][N]
               int M)
{
    __shared__ __align__(16) __hip_bfloat16 Bs[208 * LDSW];  // 16.6 KB
    int tid = threadIdx.x, wave = tid >> 6, lane = tid & 63;
    int quad = lane >> 4, l16 = lane & 15;
    int f = blockIdx.y;                 // flavor
    int rowbase = f * 208;
    int m0 = blockIdx.x * 128;
    int arow = m0 + wave * 16 + l16;
    bool rok = arow < M;
    float nsc = rok ? nscale[arow] : 0.f;
    const float* arp = ent + (size_t)arow * DD;
    int orow = m0 + wave * 16 + quad * 4;
    const __hip_bfloat16* Bsrc = Bt + (size_t)rowbase * KP;

    f32x4 acc[13];
#pragma unroll
    for (int t = 0; t < 13; t++) acc[t] = (f32x4){0.f, 0.f, 0.f, 0.f};

    short8 stg[2];
#pragma unroll
    for (int i = 0; i < 2; i++) {
        int idx = tid + i * 512;
        if (idx < 832) {
            int r = idx >> 2, c8 = idx & 3;
            stg[i] = *(const short8*)(Bsrc + (size_t)r * KP + c8 * 8);
        }
    }
    for (int ch = 0; ch < 7; ch++) {
        int kb = ch * 32 + quad * 8;
        float av[8];
        if (rok && kb + 8 <= DD) {
            const float4* p = (const float4*)(arp + kb);
            float4 u0 = p[0], u1 = p[1];
            av[0] = u0.x; av[1] = u0.y; av[2] = u0.z; av[3] = u0.w;
            av[4] = u1.x; av[5] = u1.y; av[6] = u1.z; av[7] = u1.w;
        } else {
#pragma unroll
            for (int j = 0; j < 8; j++) av[j] = (rok && kb + j < DD) ? arp[kb + j] : 0.f;
        }
#pragma unroll
        for (int i = 0; i < 2; i++) {
            int idx = tid + i * 512;
            if (idx < 832) {
                int r = idx >> 2, c8 = idx & 3;
                *(short8*)(Bs + r * LDSW + c8 * 8) = stg[i];
            }
        }
        __syncthreads();
        if (ch < 6) {
            int kb2 = (ch + 1) * 32;
#pragma unroll
            for (int i = 0; i < 2; i++) {
                int idx = tid + i * 512;
                if (idx < 832) {
                    int r = idx >> 2, c8 = idx & 3;
                    stg[i] = *(const short8*)(Bsrc + (size_t)r * KP + kb2 + c8 * 8);
                }
            }
        }
        short8 a;
#pragma unroll
        for (int j = 0; j < 8; j++) a[j] = bf16s(av[j] * nsc);
        const __hip_bfloat16* bp = Bs + (size_t)l16 * LDSW + quad * 8;
#pragma unroll
        for (int t = 0; t < 13; t++) {
            short8 b = *(const short8*)(bp + (size_t)t * 16 * LDSW);
            acc[t] = __builtin_amdgcn_mfma_f32_16x16x32_bf16(a, b, acc[t], 0, 0, 0);
        }
        __syncthreads();
    }

    // ---- flavor epilogues ----
    if (f == 2) {
#pragma unroll
        for (int t = 0; t < 13; t++) {
            int cc = t * 16 + l16;
#pragma unroll
            for (int i = 0; i < 4; i++) {
                int gm = orow + i;
                if (cc < OD && gm < M)
                    pB[(size_t)gm * PBS + 224 + cc] = __float2bfloat16(acc[t][i]);
            }
        }
        return;
    }

    float dLo[4] = {0,0,0,0}, dHi[4] = {0,0,0,0};
#pragma unroll
    for (int t = 0; t < 13; t++) {
        int cc = t * 16 + l16;
        bool cok = cc < 200;
        float w = cok ? a2h[cc] : 0.f;
#pragma unroll
        for (int i = 0; i < 4; i++) {
            float v = acc[t][i];
            float vw = v * w;
            if (cc < 100) dLo[i] += vw;
            else if (cok) dHi[i] += vw;
            int gm = orow + i;
            if (cok && gm < M) {
                if (f == 0) x1[(size_t)gm * KP + cc] = __float2bfloat16(v);
                else {
                    int hh = (cc >= 100) ? 1 : 0;
                    pB[(size_t)gm * PBS + (cc - hh * 100) * 2 + hh] = __float2bfloat16(v);
                }
            }
        }
    }
    if (f == 0) {
        if (l16 < 12)
#pragma unroll
            for (int i = 0; i < 4; i++) {
                int gm = orow + i;
                if (gm < M) *(unsigned*)(x1 + (size_t)gm * KP + 200 + 2 * l16) = 0u;
            }
    }
#pragma unroll
    for (int msk = 1; msk < 16; msk <<= 1)
#pragma unroll
        for (int i = 0; i < 4; i++) {
            dLo[i] += __shfl_xor(dLo[i], msk);
            dHi[i] += __shfl_xor(dHi[i], msk);
        }
    if (l16 == 0)
#pragma unroll
        for (int i = 0; i < 4; i++) {
            int gm = orow + i;
            if (gm < M) {
                if (f == 0) { s1[gm] = dLo[i]; s1[M + gm] = dHi[i]; }
                else {
                    float2 sv; sv.x = dLo[i]; sv.y = dHi[i];
                    *(float2*)((char*)pB + (size_t)gm * (PBS * 2) + 400) = sv;
                }
            }
        }
}

// ---- layer-2: 512 thr / 128 rows; flavor y: 0=x1A1+s1, 1=x1A2+s2 ---------
__global__ __launch_bounds__(512)
void l2_proj_k(const __hip_bfloat16* __restrict__ x1,  // [N][KP]
               const __hip_bfloat16* __restrict__ Bt,  // [416][KP]
               const float* __restrict__ a2o,          // [200]
               float* __restrict__ x1A1,               // [N][200] (out_ent)
               __hip_bfloat16* __restrict__ x1A2,      // [N][PBS], s2 in pad
               float* __restrict__ s1, int M)
{
    __shared__ __align__(16) __hip_bfloat16 Bs[208 * LDSW];  // 16.6 KB
    int tid = threadIdx.x, wave = tid >> 6, lane = tid & 63;
    int quad = lane >> 4, l16 = lane & 15;
    int f = blockIdx.y;
    int rowbase = f * 208;
    int m0 = blockIdx.x * 128;
    int arow = m0 + wave * 16 + l16;
    bool rok = arow < M;
    const __hip_bfloat16* arp = x1 + (size_t)arow * KP;
    const __hip_bfloat16* Bsrc = Bt + (size_t)rowbase * KP;

    f32x4 acc[13];
#pragma unroll
    for (int t = 0; t < 13; t++) acc[t] = (f32x4){0.f, 0.f, 0.f, 0.f};

    short8 stg[2];
#pragma unroll
    for (int i = 0; i < 2; i++) {
        int idx = tid + i * 512;
        if (idx < 832) {
            int r = idx >> 2, c8 = idx & 3;
            stg[i] = *(const short8*)(Bsrc + (size_t)r * KP + c8 * 8);
        }
    }
    for (int ch = 0; ch < 7; ch++) {
        short8 a = (short8){0,0,0,0,0,0,0,0};
        if (rok) a = *(const short8*)(arp + ch * 32 + quad * 8);
#pragma unroll
        for (int i = 0; i < 2; i++) {
            int idx = tid + i * 512;
            if (idx < 832) {
                int r = idx >> 2, c8 = idx & 3;
                *(short8*)(Bs + r * LDSW + c8 * 8) = stg[i];
            }
        }
        __syncthreads();
        if (ch < 6) {
            int kb2 = (ch + 1) * 32;
#pragma unroll
            for (int i = 0; i < 2; i++) {
                int idx = tid + i * 512;
                if (idx < 832) {
                    int r = idx >> 2, c8 = idx & 3;
                    stg[i] = *(const short8*)(Bsrc + (size_t)r * KP + kb2 + c8 * 8);
                }
            }
        }
        const __hip_bfloat16* bp = Bs + (size_t)l16 * LDSW + quad * 8;
#pragma unroll
        for (int t = 0; t < 13; t++) {
            short8 b = *(const short8*)(bp + (size_t)t * 16 * LDSW);
            acc[t] = __builtin_amdgcn_mfma_f32_16x16x32_bf16(a, b, acc[t], 0, 0, 0);
        }
        __syncthreads();
    }

    int orow = m0 + wave * 16 + quad * 4;
    float d[4] = {0,0,0,0};
#pragma unroll
    for (int t = 0; t < 13; t++) {
        int cc = t * 16 + l16;
        bool cok = cc < 200;
        float w = cok ? a2o[cc] : 0.f;
#pragma unroll
        for (int i = 0; i < 4; i++) {
            float v = acc[t][i];
            d[i] += v * w;
            int gm = orow + i;
            if (cok && gm < M) {
                if (f == 0) x1A1[(size_t)gm * OD + cc] = v;
                else x1A2[(size_t)gm * PBS + cc] = __float2bfloat16(v);
            }
        }
    }
#pragma unroll
    for (int msk = 1; msk < 16; msk <<= 1)
#pragma unroll
        for (int i = 0; i < 4; i++) d[i] += __shfl_xor(d[i], msk);
    if (l16 == 0)
#pragma unroll
        for (int i = 0; i < 4; i++) {
            int gm = orow + i;
            if (gm < M) {
                if (f == 0) s1[gm] = d[i];
                else *(float*)((char*)x1A2 + (size_t)gm * (PBS * 2) + 400) = d[i];
            }
        }
}

// -------- generic MFMA GEMM (small R-sized matmuls); cs/co = C col-stride --
#define KPAD 48
template<bool BTr, typename AT, typename CT>
__global__ __launch_bounds__(256)
void gemm_mfma_k(const AT* __restrict__ A, int lda, const float* __restrict__ ascale,
                 const float* __restrict__ B, int ldb, int colOff,
                 CT* __restrict__ C, int ldc, int cs, int co,
                 int M, int Nc, int K)
{
    __shared__ __align__(16) __hip_bfloat16 As[64][KPAD];
    __shared__ __align__(16) __hip_bfloat16 Bs[64][KPAD];
    int tid  = threadIdx.x;
    int wave = tid >> 6, lane = tid & 63;
    int quad = lane >> 4, l16 = lane & 15;
    int n0 = blockIdx.x * 64, m0 = blockIdx.y * 64;
    f32x4 acc[4];
#pragma unroll
    for (int t = 0; t < 4; t++) acc[t] = (f32x4){0.f, 0.f, 0.f, 0.f};

    for (int k0 = 0; k0 < K; k0 += 32) {
        {
            int m = tid >> 2, kc = (tid & 3) * 8;
            int gm = m0 + m;
            float scale = (ascale && gm < M) ? ascale[gm] : 1.f;
#pragma unroll
            for (int j = 0; j < 8; j++) {
                int gk = k0 + kc + j;
                float v = 0.f;
                if (gm < M && gk < K) v = toF(A[(size_t)gm * lda + gk]) * scale;
                As[m][kc + j] = __float2bfloat16(v);
            }
        }
        if (BTr) {
            int n = tid >> 2, kc = (tid & 3) * 8;
            int gn = n0 + n;
#pragma unroll
            for (int j = 0; j < 8; j++) {
                int gk = k0 + kc + j;
                float v = 0.f;
                if (gn < Nc && gk < K) v = B[(size_t)gn * ldb + colOff + gk];
                Bs[n][kc + j] = __float2bfloat16(v);
            }
        } else {
            int n = tid & 63, kq = tid >> 6;
            int gn = n0 + n;
#pragma unroll
            for (int j = 0; j < 8; j++) {
                int gk = k0 + kq * 8 + j;
                float v = 0.f;
                if (gn < Nc && gk < K) v = B[(size_t)gk * ldb + gn];
                Bs[n][kq * 8 + j] = __float2bfloat16(v);
            }
        }
        __syncthreads();
        short8 a = *(const short8*)&As[wave * 16 + l16][quad * 8];
#pragma unroll
        for (int t = 0; t < 4; t++) {
            short8 b = *(const short8*)&Bs[t * 16 + l16][quad * 8];
            acc[t] = __builtin_amdgcn_mfma_f32_16x16x32_bf16(a, b, acc[t], 0, 0, 0);
        }
        __syncthreads();
    }
#pragma unroll
    for (int t = 0; t < 4; t++) {
        int gn = n0 + t * 16 + l16;
        if (gn >= Nc) continue;
#pragma unroll
        for (int i = 0; i < 4; i++) {
            int gm = m0 + wave * 16 + quad * 4 + i;
            if (gm < M) storeC(acc[t][i], &C[(size_t)gm * ldc + (size_t)gn * cs + co]);
        }
    }
}

// -------- row-dot (srel); ks = k-stride in mat, os/oo = output stride ------
template<typename T>
__global__ __launch_bounds__(256)
void rowdot_k(const T* __restrict__ mat, int ld, int coff, int ks,
              const float* __restrict__ vec,
              float* __restrict__ outp, int os, int oo, int M, int Dd)
{
    int wave = (blockIdx.x * blockDim.x + threadIdx.x) >> 6;
    int lane = threadIdx.x & 63;
    if (wave >= M) return;
    float s = 0.f;
    for (int k = lane; k < Dd; k += 64)
        s += toF(mat[(size_t)wave * ld + coff + (size_t)k * ks]) * vec[k];
    for (int o = 32; o > 0; o >>= 1) s += __shfl_down(s, o);
    if (lane == 0) outp[wave * os + oo] = s;
}

// -------- CSR build --------
__device__ inline void decode_edge(const int* __restrict__ el, int E,
                                   const int* __restrict__ etype,
                                   const int* __restrict__ tin, int e,
                                   int& dst, int& src, int& r1, int& r2)
{
    if (e < E) { dst = el[e]; src = el[E + e]; r1 = etype[e]; r2 = -1; }
    else {
        int j = e - E;
        dst = tin[j * 4 + 3]; src = tin[j * 4 + 0];
        r1 = tin[j * 4 + 1];  r2 = tin[j * 4 + 2];
    }
}

__global__ void hist_k(const int* __restrict__ el, int E, const int* __restrict__ etype,
                       const int* __restrict__ tin, int Etot, int* __restrict__ cnt)
{
    int e = blockIdx.x * blockDim.x + threadIdx.x;
    if (e >= Etot) return;
    int dst, src, r1, r2; decode_edge(el, E, etype, tin, e, dst, src, r1, r2);
    atomicAdd(&cnt[dst], 1);
}

__global__ __launch_bounds__(1024)
void scan1_k(const int* __restrict__ cnt, int* __restrict__ start,
             int* __restrict__ aux, int n)
{
    __shared__ int tmp[1024];
    int i = blockIdx.x * 1024 + threadIdx.x;
    int v = (i < n) ? cnt[i] : 0;
    tmp[threadIdx.x] = v;
    __syncthreads();
    for (int o = 1; o < 1024; o <<= 1) {
        int t = (threadIdx.x >= (unsigned)o) ? tmp[threadIdx.x - o] : 0;
        __syncthreads();
        tmp[threadIdx.x] += t;
        __syncthreads();
    }
    if (i < n) start[i] = tmp[threadIdx.x] - v;
    if (threadIdx.x == 1023) aux[blockIdx.x] = tmp[1023];
}

__global__ void scan2_k(int* __restrict__ aux, int nb)
{
    if (threadIdx.x == 0 && blockIdx.x == 0) {
        int s = 0;
        for (int i = 0; i < nb; i++) { int v = aux[i]; aux[i] = s; s += v; }
    }
}

__global__ __launch_bounds__(1024)
void scan3_k(int* __restrict__ start, const int* __restrict__ aux, int n, int Etot)
{
    int i = blockIdx.x * 1024 + threadIdx.x;
    if (i < n) start[i] += aux[blockIdx.x];
    if (i == 0) start[n] = Etot;
}

// csr entry: .x = src, .y = r1 | (r2s<<16), r2s==0xFFFF means "no r2"
__global__ void fill_k(const int* __restrict__ el, int E, const int* __restrict__ etype,
                       const int* __restrict__ tin, int Etot,
                       const int* __restrict__ start, int* __restrict__ fill,
                       int2* __restrict__ csr)
{
    int e = blockIdx.x * blockDim.x + threadIdx.x;
    if (e >= Etot) return;
    int dst, src, r1, r2; decode_edge(el, E, etype, tin, e, dst, src, r1, r2);
    int p = start[dst] + atomicAdd(&fill[dst], 1);
    unsigned r2s = (r2 >= 0) ? (unsigned)r2 : 0xFFFFu;
    csr[p] = make_int2(src, (int)((r2s << 16) | (unsigned)r1));
}

// -------- layer-1 gather: wave/dst, 2-feature/lane (lane<50), wide loads ---
__global__ __launch_bounds__(256)
void gather_l1_k(const int* __restrict__ start, const int2* __restrict__ csr,
                 const float* __restrict__ s1,        // [2][N] dst-side
                 const float* __restrict__ srel2,     // [R][2]
                 const __hip_bfloat16* __restrict__ pB,   // [N][PBS] interleaved
                 const float* __restrict__ rpf2,      // [R][100][2]
                 __hip_bfloat16* __restrict__ x1, int N)  // [N][KP]
{
    int n = (blockIdx.x * blockDim.x + threadIdx.x) >> 6;
    int lane = threadIdx.x & 63;
    if (n >= N) return;
    int b0 = __builtin_amdgcn_readfirstlane(start[n]);
    int b1 = __builtin_amdgcn_readfirstlane(start[n + 1]);
    float s1h0 = s1[n], s1h1 = s1[N + n];
    float rsl0 = 0.f, rsl1 = 0.f;        // per-lane partial rowsums
    bool fok = lane < 50;
    int f2 = fok ? 2 * lane : 0;         // features f2, f2+1
    float4 acc = {0.f, 0.f, 0.f, 0.f};   // (f2,h0) (f2,h1) (f2+1,h0) (f2+1,h1)

    for (int c0 = b0; c0 < b1; c0 += 64) {
        int cnt = min(64, b1 - c0);
        // ---- phase A: lane-parallel per-edge scalars
        float w0 = 0.f, w1 = 0.f;
        int srcL = 0, eyL = 0;
        if (lane < cnt) {
            int2 eg = csr[c0 + lane];
            srcL = eg.x; eyL = eg.y;
            int r1 = eyL & 0xFFFF;
            unsigned r2u = (unsigned)eyL >> 16;
            float2 sA = *(const float2*)((const char*)pB + (size_t)(unsigned)srcL * (PBS * 2) + 400);
            float2 sr = *(const float2*)(srel2 + r1 * 2);
            float z0 = s1h0 + sA.x + sr.x;
            float z1 = s1h1 + sA.y + sr.y;
            if (r2u != 0xFFFFu) {
                float2 sr2v = *(const float2*)(srel2 + r2u * 2);
                z0 += sr2v.x; z1 += sr2v.y;
            }
            w0 = expf(-(z0 > 0.f ? z0 : 0.2f * z0));
            w1 = expf(-(z1 > 0.f ? z1 : 0.2f * z1));
            rsl0 += w0; rsl1 += w1;
        }
        // ---- phase B: 4-edge batches; wide loads batched up front
        for (int e0 = 0; e0 < cnt; e0 += 4) {
            int ec = min(4, cnt - e0);
            uint2 pw[4]; float4 q1v[4]; unsigned r2s[4];
#pragma unroll
            for (int u = 0; u < 4; u++) {
                if (u < ec) {
                    int s = __builtin_amdgcn_readlane(srcL, e0 + u);
                    int ey = __builtin_amdgcn_readlane(eyL, e0 + u);
                    int r1 = ey & 0xFFFF;
                    r2s[u] = (unsigned)ey >> 16;
                    pw[u] = *(const uint2*)(pB + (size_t)(unsigned)s * PBS + 2 * f2);
                    q1v[u] = *(const float4*)(rpf2 + (unsigned)r1 * 200 + 2 * f2);
                }
            }
#pragma unroll
            for (int u = 0; u < 4; u++) {
                if (u < ec) {
                    float we0 = readlaneF(w0, e0 + u);
                    float we1 = readlaneF(w1, e0 + u);
                    float v00 = bfLo(pw[u].x) + q1v[u].x;   // f2,   h0
                    float v01 = bfHi(pw[u].x) + q1v[u].y;   // f2,   h1
                    float v10 = bfLo(pw[u].y) + q1v[u].z;   // f2+1, h0
                    float v11 = bfHi(pw[u].y) + q1v[u].w;   // f2+1, h1
                    if (r2s[u] != 0xFFFFu) {
                        float4 q2v = *(const float4*)(rpf2 + r2s[u] * 200 + 2 * f2);
                        v00 += q2v.x; v01 += q2v.y; v10 += q2v.z; v11 += q2v.w;
                    }
                    acc.x += we0 * v00; acc.y += we1 * v01;
                    acc.z += we0 * v10; acc.w += we1 * v11;
                }
            }
        }
    }

    // wave-reduce rowsums (butterfly -> all lanes)
#pragma unroll
    for (int o = 1; o < 64; o <<= 1) {
        rsl0 += __shfl_xor(rsl0, o);
        rsl1 += __shfl_xor(rsl1, o);
    }
    float i0 = rsl0 > 0.f ? 1.f / rsl0 : 0.f;
    float i1 = rsl1 > 0.f ? 1.f / rsl1 : 0.f;
    if (!fok) return;
    __hip_bfloat16* xr = x1 + (size_t)n * KP;
    // h0 pair (cols f2, f2+1)
    unsigned u0 = *(const unsigned*)(xr + f2);
    float h0a = rsl0 > 0.f ? bfLo(u0) + acc.x * i0 : 0.f;
    float h0b = rsl0 > 0.f ? bfHi(u0) + acc.z * i0 : 0.f;
    h0a = h0a > 0.f ? h0a : expf(h0a) - 1.f;
    h0b = h0b > 0.f ? h0b : expf(h0b) - 1.f;
    *(unsigned*)(xr + f2) = packbf(h0a, h0b);
    // h1 pair (cols 100+f2, 100+f2+1)
    unsigned u1 = *(const unsigned*)(xr + 100 + f2);
    float h1a = rsl1 > 0.f ? bfLo(u1) + acc.y * i1 : 0.f;
    float h1b = rsl1 > 0.f ? bfHi(u1) + acc.w * i1 : 0.f;
    h1a = h1a > 0.f ? h1a : expf(h1a) - 1.f;
    h1b = h1b > 0.f ? h1b : expf(h1b) - 1.f;
    *(unsigned*)(xr + 100 + f2) = packbf(h1a, h1b);
}

// -------- layer-2 gather: wave/dst, 4-col/lane (lane<50), wide loads -------
__global__ __launch_bounds__(256)
void gather_l2_k(const int* __restrict__ start, const int2* __restrict__ csr,
                 const float* __restrict__ s1,
                 const float* __restrict__ srel,          // [R]
                 const __hip_bfloat16* __restrict__ x1A2, // [N][PBS]: feats+s2+entW
                 const float* __restrict__ rpf,           // [R][200]
                 const float* __restrict__ maskf,
                 float* __restrict__ outent, int N)       // [N][200], holds x1A1
{
    int n = (blockIdx.x * blockDim.x + threadIdx.x) >> 6;
    int lane = threadIdx.x & 63;
    if (n >= N) return;
    int b0 = __builtin_amdgcn_readfirstlane(start[n]);
    int b1 = __builtin_amdgcn_readfirstlane(start[n + 1]);
    float s1n = s1[n];
    float rsl = 0.f;
    bool fok = lane < 50;
    int c4 = fok ? 4 * lane : 0;         // cols c4 .. c4+3
    float4 acc = {0.f, 0.f, 0.f, 0.f};

    for (int c0 = b0; c0 < b1; c0 += 64) {
        int cnt = min(64, b1 - c0);
        // ---- phase A: lane-parallel per-edge scalars
        float w = 0.f;
        int srcL = 0, eyL = 0;
        if (lane < cnt) {
            int2 eg = csr[c0 + lane];
            srcL = eg.x; eyL = eg.y;
            int r1 = eyL & 0xFFFF;
            unsigned r2u = (unsigned)eyL >> 16;
            float s2v = *(const float*)((const char*)x1A2 + (size_t)(unsigned)srcL * (PBS * 2) + 400);
            float sr = srel[r1];
            if (r2u != 0xFFFFu) sr += srel[r2u];
            float z = s1n + s2v + sr;
            w = expf(-(z > 0.f ? z : 0.2f * z));
            rsl += w;
        }
        // ---- phase B: 4-edge batches; wide loads batched up front
        for (int e0 = 0; e0 < cnt; e0 += 4) {
            int ec = min(4, cnt - e0);
            uint2 xw[4]; float4 q1v[4]; unsigned r2s[4];
#pragma unroll
            for (int u = 0; u < 4; u++) {
                if (u < ec) {
                    int s = __builtin_amdgcn_readlane(srcL, e0 + u);
                    int ey = __builtin_amdgcn_readlane(eyL, e0 + u);
                    int r1 = ey & 0xFFFF;
                    r2s[u] = (unsigned)ey >> 16;
                    xw[u] = *(const uint2*)(x1A2 + (size_t)(unsigned)s * PBS + c4);
                    q1v[u] = *(const float4*)(rpf + (unsigned)r1 * 200 + c4);
                }
            }
#pragma unroll
            for (int u = 0; u < 4; u++) {
                if (u < ec) {
                    float we = readlaneF(w, e0 + u);
                    float v0 = bfLo(xw[u].x) + q1v[u].x;
                    float v1 = bfHi(xw[u].x) + q1v[u].y;
                    float v2 = bfLo(xw[u].y) + q1v[u].z;
                    float v3 = bfHi(xw[u].y) + q1v[u].w;
                    if (r2s[u] != 0xFFFFu) {
                        float4 q2v = *(const float4*)(rpf + r2s[u] * 200 + c4);
                        v0 += q2v.x; v1 += q2v.y; v2 += q2v.z; v3 += q2v.w;
                    }
                    acc.x += we * v0; acc.y += we * v1;
                    acc.z += we * v2; acc.w += we * v3;
                }
            }
        }
    }

#pragma unroll
    for (int o = 1; o < 64; o <<= 1) rsl += __shfl_xor(rsl, o);
    float inv = rsl > 0.f ? 1.f / rsl : 0.f;
    float mk = maskf[n];
    float* orow = outent + (size_t)n * 200;
    const __hip_bfloat16* ew = x1A2 + (size_t)n * PBS + 224;  // own dst row's entW

    float v0 = 0.f, v1 = 0.f, v2 = 0.f, v3 = 0.f;
    if (fok) {
        float4 o4 = *(const float4*)(orow + c4);
        uint2 eb = *(const uint2*)(ew + c4);
        float h0 = rsl > 0.f ? o4.x + acc.x * inv : 0.f;
        float h1 = rsl > 0.f ? o4.y + acc.y * inv : 0.f;
        float h2 = rsl > 0.f ? o4.z + acc.z * inv : 0.f;
        float h3 = rsl > 0.f ? o4.w + acc.w * inv : 0.f;
        v0 = mk * (h0 > 0.f ? h0 : expf(h0) - 1.f) + bfLo(eb.x);
        v1 = mk * (h1 > 0.f ? h1 : expf(h1) - 1.f) + bfHi(eb.x);
        v2 = mk * (h2 > 0.f ? h2 : expf(h2) - 1.f) + bfLo(eb.y);
        v3 = mk * (h3 > 0.f ? h3 : expf(h3) - 1.f) + bfHi(eb.y);
    }
    float ssq = v0 * v0 + v1 * v1 + v2 * v2 + v3 * v3;
#pragma unroll
    for (int o = 1; o < 64; o <<= 1) ssq += __shfl_xor(ssq, o);
    float sc = 1.f / fmaxf(sqrtf(ssq), 1e-12f);
    if (fok) {
        float4 r; r.x = v0 * sc; r.y = v1 * sc; r.z = v2 * sc; r.w = v3 * sc;
        *(float4*)(orow + c4) = r;
    }
}

__global__ void scatter_mask_k(const int* __restrict__ batch, int NB,
                               float* __restrict__ masko)
{
    int i = blockIdx.x * blockDim.x + threadIdx.x;
    if (i >= NB) return;
    masko[batch[i]] = 1.0f;
}

extern "C" void kernel_launch(void* const* d_in, const int* in_sizes, int n_in,
                              void* d_out, int out_size, void* d_ws, size_t ws_size,
                              hipStream_t stream)
{
    const float* ent      = (const float*)d_in[0];
    const float* rel      = (const float*)d_in[1];
    const float* W_ent    = (const float*)d_in[2];
    const float* W_gat    = (const float*)d_in[3];
    const float* a_heads  = (const float*)d_in[4];
    const float* a2_heads = (const float*)d_in[5];
    const float* a_out    = (const float*)d_in[6];
    const float* a2_out   = (const float*)d_in[7];
    const int* batch = (const int*)d_in[8];
    const int* el    = (const int*)d_in[9];
    const int* etype = (const int*)d_in[10];
    const int* tin   = (const int*)d_in[11];

    const int N   = in_sizes[0] / DD;   // 50000
    const int R   = in_sizes[1] / DD;   // 500
    const int NB  = in_sizes[8];        // 20000
    const int E   = in_sizes[9] / 2;    // 150000
    const int ENH = in_sizes[11] / 4;   // 30000
    const int Etot = E + ENH;

    // ---- workspace (~70 MB) ----
    char* ws = (char*)d_ws;
    size_t off = 0;
    auto take = [&](size_t bytes) { size_t o = off; off += (bytes + 255) & ~(size_t)255; return o; };
    size_t o_R1   = take((size_t)N * KP * 2);     // x1 bf16 [N][KP]
    size_t o_R2   = take((size_t)N * PBS * 2);    // pB/x1A2 [N][PBS] + s2 + entW
    size_t o_rpf  = take((size_t)2 * R * 100 * 4);// rpf2 [R][100][2] / layer2 rpf [R][200]
    size_t o_bt1  = take((size_t)416 * KP * 2);   // l1 panel
    size_t o_btf  = take((size_t)208 * KP * 2);   // W_ent panel: ADJACENT to bt1
    size_t o_bt2  = take((size_t)416 * KP * 2);
    size_t o_nsc  = take((size_t)N * 4);
    size_t o_s1   = take((size_t)2 * N * 4);      // aliased by cnt during CSR build
    size_t o_srel = take((size_t)2 * R * 4);      // [R][2] layer1 / [R] layer2
    size_t o_csr  = take((size_t)Etot * 8);
    size_t o_str  = take((size_t)(N + 1) * 4);
    size_t o_aux  = take((size_t)64 * 4);

    __hip_bfloat16* x1   = (__hip_bfloat16*)(ws + o_R1);
    __hip_bfloat16* pB   = (__hip_bfloat16*)(ws + o_R2);
    __hip_bfloat16* x1A2 = (__hip_bfloat16*)(ws + o_R2);
    float* rpf2   = (float*)(ws + o_rpf);
    __hip_bfloat16* bt1 = (__hip_bfloat16*)(ws + o_bt1);  // [624][KP] combined w/ btf
    __hip_bfloat16* btf = (__hip_bfloat16*)(ws + o_btf);
    __hip_bfloat16* bt2 = (__hip_bfloat16*)(ws + o_bt2);
    float* nscale = (float*)(ws + o_nsc);
    float* s1     = (float*)(ws + o_s1);
    float* srel2  = (float*)(ws + o_srel);
    int2*  csr    = (int2*)(ws + o_csr);
    int*   cnt    = (int*)(ws + o_s1);   // CSR-build scratch; dead before l1_both_k writes s1
    int*   startA = (int*)(ws + o_str);
    int*   aux    = (int*)(ws + o_aux);

    float* out       = (float*)d_out;
    float* out_ent   = out;                                     // [N,200]
    float* out_rel_o = out + (size_t)N * OD;                    // [500,200]
    float* out_mask  = out + (size_t)N * OD + (size_t)R * OD;   // [N]

    const int nblk2 = cdiv(N, 128);
    const int nbScan = cdiv(N, 1024);

    // A. prep: norms, B panels (bt1[416] + btf[208] contiguous -> 624 rows)
    rownorm_inv_k<<<cdiv(N, 4), 256, 0, stream>>>(ent, nscale, N, DD);
    prep_bt_l1<<<416, 256, 0, stream>>>(a_heads, bt1);
    prep_bt_fin<<<208, 256, 0, stream>>>(W_ent, btf);
    prep_bt_l2<<<416, 256, 0, stream>>>(a_out, bt2);
    gemm_mfma_k<false, float, float><<<dim3(cdiv(OD, 64), cdiv(R, 64)), 256, 0, stream>>>(
        rel, DD, nullptr, W_gat, OD, 0, out_rel_o, OD, 1, 0, R, OD, DD);

    // A2. CSR build (dst-grouped edge lists)
    hipMemsetAsync(cnt, 0, (size_t)N * 4, stream);
    hist_k<<<cdiv(Etot, 256), 256, 0, stream>>>(el, E, etype, tin, Etot, cnt);
    scan1_k<<<nbScan, 1024, 0, stream>>>(cnt, startA, aux, N);
    scan2_k<<<1, 64, 0, stream>>>(aux, nbScan);
    scan3_k<<<nbScan, 1024, 0, stream>>>(startA, aux, N, Etot);
    hipMemsetAsync(cnt, 0, (size_t)N * 4, stream);
    fill_k<<<cdiv(Etot, 256), 256, 0, stream>>>(el, E, etype, tin, Etot, startA, cnt, csr);

    // B. layer-1 projections: flavors y0=x1+s1, y1=pB+s2, y2=entW
    l1_both_k<<<dim3(nblk2, 3), 512, 0, stream>>>(ent, nscale, bt1, a2_heads, x1, pB, s1, N);
    for (int h = 0; h < 2; h++) {
        const float* ah  = a_heads + (size_t)h * NHID * 600;
        const float* a2h = a2_heads + (size_t)h * NHID;
        gemm_mfma_k<true, float, float><<<dim3(cdiv(NHID, 64), cdiv(R, 64)), 256, 0, stream>>>(
            rel, DD, nullptr, ah, 600, 400, rpf2, 200, 2, h, R, NHID, DD);
        rowdot_k<float><<<cdiv(R, 4), 256, 0, stream>>>(
            rpf2, 200, h, 2, a2h, srel2, 2, h, R, NHID);
    }
    gather_l1_k<<<cdiv(N, 4), 256, 0, stream>>>(
        startA, csr, s1, srel2, pB, rpf2, x1, N);
    // pB feats dead; R2 rows become x1A2 (entW at shorts 224.. survives).

    // C. layer-2 projection (flavors y0=x1A1+s1, y1=x1A2+s2) + rel side
    l2_proj_k<<<dim3(nblk2, 2), 512, 0, stream>>>(x1, bt2, a2_out, out_ent, x1A2, s1, N);
    gemm_mfma_k<true, float, float><<<dim3(cdiv(OD, 64), cdiv(R, 64)), 256, 0, stream>>>(
        out_rel_o, OD, nullptr, a_out, 600, 400, rpf2, OD, 1, 0, R, OD, OD);
    rowdot_k<float><<<cdiv(R, 4), 256, 0, stream>>>(rpf2, OD, 0, 1, a2_out, srel2, 1, 0, R, OD);

    // D. mask; layer-2 gather (fused combine + entW + l2norm -> final out_ent)
    hipMemsetAsync(out_mask, 0, (size_t)N * 4, stream);
    scatter_mask_k<<<cdiv(NB, 256), 256, 0, stream>>>(batch, NB, out_mask);
    gather_l2_k<<<cdiv(N, 4), 256, 0, stream>>>(
        startA, csr, s1, srel2, x1A2, rpf2, out_mask, out_ent, N);
}

// Round 13
// 425.557 us; speedup vs baseline: 1.4500x; 1.0163x over previous
//
#include <hip/hip_runtime.h>
#include <hip/hip_bf16.h>
#include <math.h>

// SpKBGAT: N=50000, D=200, R=500, NHID=100, H=2, OD=200, E=150000, ENH=30000.
// R21: l1_both's 3 flavors each re-read 40MB f32 ent + redo x-nscale + bf16
// conversion (40% of its VALU, ~20MB extra FETCH each). Fix: rownorm fused
// with bf16 normalization -> entb[N][KP] (zero-padded); all l1 flavors load
// A as one short8 (same as l2_proj). nscale buffer deleted.
#define DD   200
#define NHID 100
#define OD   200
#define KP   224   // padded K (7 chunks of 32)
#define PBS  448   // row stride (bf16) for pB / x1A2 / entW: 896 B
                   // [0..199]: pB [k][h0,h1] pairs (l1) / x1A2 feats (l2)
                   // bytes 400..407: s2 floats;  shorts [224..423]: entW bf16
#define LDSW 40    // LDS row stride in shorts (80 B)

typedef __attribute__((ext_vector_type(8))) short short8;
typedef __attribute__((ext_vector_type(4))) float f32x4;

static inline int cdiv(int a, int b) { return (a + b - 1) / b; }

__device__ inline float toF(float x) { return x; }
__device__ inline float toF(__hip_bfloat16 x) { return __bfloat162float(x); }
__device__ inline void storeC(float v, float* p) { *p = v; }
__device__ inline void storeC(float v, __hip_bfloat16* p) { *p = __float2bfloat16(v); }
__device__ inline short bf16s(float f) {
    __hip_bfloat16 h = __float2bfloat16(f);
    short s; __builtin_memcpy(&s, &h, 2); return s;
}
__device__ inline float bfLo(unsigned u) { return __uint_as_float(u << 16); }
__device__ inline float bfHi(unsigned u) { return __uint_as_float(u & 0xFFFF0000u); }
__device__ inline unsigned packbf(float a, float b) {
    unsigned lo = (unsigned)(unsigned short)bf16s(a);
    unsigned hi = (unsigned)(unsigned short)bf16s(b);
    return lo | (hi << 16);
}
__device__ inline float readlaneF(float v, int l) {
    return __uint_as_float((unsigned)__builtin_amdgcn_readlane((int)__float_as_uint(v), l));
}

// -------- fused: per-row inverse L2 norm + bf16 store [N][KP], padded -----
__global__ __launch_bounds__(256)
void rownorm_bf16_k(const float* __restrict__ in, __hip_bfloat16* __restrict__ outb,
                    int M)
{
    int wave = (blockIdx.x * blockDim.x + threadIdx.x) >> 6;
    int lane = threadIdx.x & 63;
    if (wave >= M) return;
    const float* row = in + (size_t)wave * DD;
    bool fok = lane < 50;
    float4 v = {0.f, 0.f, 0.f, 0.f};
    if (fok) v = *(const float4*)(row + 4 * lane);
    float ss = v.x * v.x + v.y * v.y + v.z * v.z + v.w * v.w;
#pragma unroll
    for (int o = 1; o < 64; o <<= 1) ss += __shfl_xor(ss, o);
    float inv = 1.f / fmaxf(sqrtf(ss), 1e-12f);
    __hip_bfloat16* ob = outb + (size_t)wave * KP;
    if (fok) {
        uint2 p;
        p.x = packbf(v.x * inv, v.y * inv);
        p.y = packbf(v.z * inv, v.w * inv);
        *(uint2*)(ob + 4 * lane) = p;
    } else if (lane < 56) {
        *(unsigned*)(ob + 200 + 2 * (lane - 50)) = 0u;
    }
}

// -------- B-panel prep --------
__global__ void prep_bt_l1(const float* __restrict__ ah, __hip_bfloat16* __restrict__ Bt)
{
    int c = blockIdx.x, k = threadIdx.x;
    if (k >= KP) return;
    int g = (c >= 208) ? 1 : 0;
    int cc = c - g * 208;
    float v = 0.f;
    if (cc < 200 && k < 200) {
        int hh = (cc >= 100) ? 1 : 0;
        int idx = cc - hh * 100;
        v = ah[(size_t)(hh * 100 + idx) * 600 + g * 200 + k];
    }
    Bt[(size_t)c * KP + k] = __float2bfloat16(v);
}
__global__ void prep_bt_l2(const float* __restrict__ ao, __hip_bfloat16* __restrict__ Bt)
{
    int c = blockIdx.x, k = threadIdx.x;
    if (k >= KP) return;
    int g = (c >= 208) ? 1 : 0;
    int cc = c - g * 208;
    float v = (cc < 200 && k < 200) ? ao[(size_t)cc * 600 + g * 200 + k] : 0.f;
    Bt[(size_t)c * KP + k] = __float2bfloat16(v);
}
__global__ void prep_bt_fin(const float* __restrict__ W, __hip_bfloat16* __restrict__ Bt)
{
    int c = blockIdx.x, k = threadIdx.x;
    if (k >= KP) return;
    float v = (c < 200 && k < 200) ? W[(size_t)k * 200 + c] : 0.f;
    Bt[(size_t)c * KP + k] = __float2bfloat16(v);
}

// ---- layer-1: 512 thr / 128 rows; flavor y: 0=x1+s1, 1=pB+s2, 2=entW -----
__global__ __launch_bounds__(512)
void l1_both_k(const __hip_bfloat16* __restrict__ entb,  // [N][KP] normalized bf16
               const __hip_bfloat16* __restrict__ Bt,  // [624][KP]: 2x208 l1 + 208 W_ent
               const float* __restrict__ a2h,          // [200] (= [2][100])
               __hip_bfloat16* __restrict__ x1,        // [N][KP]
               __hip_bfloat16* __restrict__ pB,        // [N][PBS]: pB + s2 + entW
               float* __restrict__ s1,                 // [2][N]
               int M)
{
    __shared__ __align__(16) __hip_bfloat16 Bs[208 * LDSW];  // 16.6 KB
    int tid = threadIdx.x, wave = tid >> 6, lane = tid & 63;
    int quad = lane >> 4, l16 = lane & 15;
    int f = blockIdx.y;                 // flavor
    int rowbase = f * 208;
    int m0 = blockIdx.x * 128;
    int arow = m0 + wave * 16 + l16;
    bool rok = arow < M;
    const __hip_bfloat16* arp = entb + (size_t)arow * KP;
    int orow = m0 + wave * 16 + quad * 4;
    const __hip_bfloat16* Bsrc = Bt + (size_t)rowbase * KP;

    f32x4 acc[13];
#pragma unroll
    for (int t = 0; t < 13; t++) acc[t] = (f32x4){0.f, 0.f, 0.f, 0.f};

    short8 stg[2];
#pragma unroll
    for (int i = 0; i < 2; i++) {
        int idx = tid + i * 512;
        if (idx < 832) {
            int r = idx >> 2, c8 = idx & 3;
            stg[i] = *(const short8*)(Bsrc + (size_t)r * KP + c8 * 8);
        }
    }
    for (int ch = 0; ch < 7; ch++) {
        // issue A load early: overlaps LDS-write + barrier
        short8 a = (short8){0,0,0,0,0,0,0,0};
        if (rok) a = *(const short8*)(arp + ch * 32 + quad * 8);
#pragma unroll
        for (int i = 0; i < 2; i++) {
            int idx = tid + i * 512;
            if (idx < 832) {
                int r = idx >> 2, c8 = idx & 3;
                *(short8*)(Bs + r * LDSW + c8 * 8) = stg[i];
            }
        }
        __syncthreads();
        if (ch < 6) {
            int kb2 = (ch + 1) * 32;
#pragma unroll
            for (int i = 0; i < 2; i++) {
                int idx = tid + i * 512;
                if (idx < 832) {
                    int r = idx >> 2, c8 = idx & 3;
                    stg[i] = *(const short8*)(Bsrc + (size_t)r * KP + kb2 + c8 * 8);
                }
            }
        }
        const __hip_bfloat16* bp = Bs + (size_t)l16 * LDSW + quad * 8;
#pragma unroll
        for (int t = 0; t < 13; t++) {
            short8 b = *(const short8*)(bp + (size_t)t * 16 * LDSW);
            acc[t] = __builtin_amdgcn_mfma_f32_16x16x32_bf16(a, b, acc[t], 0, 0, 0);
        }
        __syncthreads();
    }

    // ---- flavor epilogues ----
    if (f == 2) {
#pragma unroll
        for (int t = 0; t < 13; t++) {
            int cc = t * 16 + l16;
#pragma unroll
            for (int i = 0; i < 4; i++) {
                int gm = orow + i;
                if (cc < OD && gm < M)
                    pB[(size_t)gm * PBS + 224 + cc] = __float2bfloat16(acc[t][i]);
            }
        }
        return;
    }

    float dLo[4] = {0,0,0,0}, dHi[4] = {0,0,0,0};
#pragma unroll
    for (int t = 0; t < 13; t++) {
        int cc = t * 16 + l16;
        bool cok = cc < 200;
        float w = cok ? a2h[cc] : 0.f;
#pragma unroll
        for (int i = 0; i < 4; i++) {
            float v = acc[t][i];
            float vw = v * w;
            if (cc < 100) dLo[i] += vw;
            else if (cok) dHi[i] += vw;
            int gm = orow + i;
            if (cok && gm < M) {
                if (f == 0) x1[(size_t)gm * KP + cc] = __float2bfloat16(v);
                else {
                    int hh = (cc >= 100) ? 1 : 0;
                    pB[(size_t)gm * PBS + (cc - hh * 100) * 2 + hh] = __float2bfloat16(v);
                }
            }
        }
    }
    if (f == 0) {
        if (l16 < 12)
#pragma unroll
            for (int i = 0; i < 4; i++) {
                int gm = orow + i;
                if (gm < M) *(unsigned*)(x1 + (size_t)gm * KP + 200 + 2 * l16) = 0u;
            }
    }
#pragma unroll
    for (int msk = 1; msk < 16; msk <<= 1)
#pragma unroll
        for (int i = 0; i < 4; i++) {
            dLo[i] += __shfl_xor(dLo[i], msk);
            dHi[i] += __shfl_xor(dHi[i], msk);
        }
    if (l16 == 0)
#pragma unroll
        for (int i = 0; i < 4; i++) {
            int gm = orow + i;
            if (gm < M) {
                if (f == 0) { s1[gm] = dLo[i]; s1[M + gm] = dHi[i]; }
                else {
                    float2 sv; sv.x = dLo[i]; sv.y = dHi[i];
                    *(float2*)((char*)pB + (size_t)gm * (PBS * 2) + 400) = sv;
                }
            }
        }
}

// ---- layer-2: 512 thr / 128 rows; flavor y: 0=x1A1+s1, 1=x1A2+s2 ---------
__global__ __launch_bounds__(512)
void l2_proj_k(const __hip_bfloat16* __restrict__ x1,  // [N][KP]
               const __hip_bfloat16* __restrict__ Bt,  // [416][KP]
               const float* __restrict__ a2o,          // [200]
               float* __restrict__ x1A1,               // [N][200] (out_ent)
               __hip_bfloat16* __restrict__ x1A2,      // [N][PBS], s2 in pad
               float* __restrict__ s1, int M)
{
    __shared__ __align__(16) __hip_bfloat16 Bs[208 * LDSW];  // 16.6 KB
    int tid = threadIdx.x, wave = tid >> 6, lane = tid & 63;
    int quad = lane >> 4, l16 = lane & 15;
    int f = blockIdx.y;
    int rowbase = f * 208;
    int m0 = blockIdx.x * 128;
    int arow = m0 + wave * 16 + l16;
    bool rok = arow < M;
    const __hip_bfloat16* arp = x1 + (size_t)arow * KP;
    const __hip_bfloat16* Bsrc = Bt + (size_t)rowbase * KP;

    f32x4 acc[13];
#pragma unroll
    for (int t = 0; t < 13; t++) acc[t] = (f32x4){0.f, 0.f, 0.f, 0.f};

    short8 stg[2];
#pragma unroll
    for (int i = 0; i < 2; i++) {
        int idx = tid + i * 512;
        if (idx < 832) {
            int r = idx >> 2, c8 = idx & 3;
            stg[i] = *(const short8*)(Bsrc + (size_t)r * KP + c8 * 8);
        }
    }
    for (int ch = 0; ch < 7; ch++) {
        short8 a = (short8){0,0,0,0,0,0,0,0};
        if (rok) a = *(const short8*)(arp + ch * 32 + quad * 8);
#pragma unroll
        for (int i = 0; i < 2; i++) {
            int idx = tid + i * 512;
            if (idx < 832) {
                int r = idx >> 2, c8 = idx & 3;
                *(short8*)(Bs + r * LDSW + c8 * 8) = stg[i];
            }
        }
        __syncthreads();
        if (ch < 6) {
            int kb2 = (ch + 1) * 32;
#pragma unroll
            for (int i = 0; i < 2; i++) {
                int idx = tid + i * 512;
                if (idx < 832) {
                    int r = idx >> 2, c8 = idx & 3;
                    stg[i] = *(const short8*)(Bsrc + (size_t)r * KP + kb2 + c8 * 8);
                }
            }
        }
        const __hip_bfloat16* bp = Bs + (size_t)l16 * LDSW + quad * 8;
#pragma unroll
        for (int t = 0; t < 13; t++) {
            short8 b = *(const short8*)(bp + (size_t)t * 16 * LDSW);
            acc[t] = __builtin_amdgcn_mfma_f32_16x16x32_bf16(a, b, acc[t], 0, 0, 0);
        }
        __syncthreads();
    }

    int orow = m0 + wave * 16 + quad * 4;
    float d[4] = {0,0,0,0};
#pragma unroll
    for (int t = 0; t < 13; t++) {
        int cc = t * 16 + l16;
        bool cok = cc < 200;
        float w = cok ? a2o[cc] : 0.f;
#pragma unroll
        for (int i = 0; i < 4; i++) {
            float v = acc[t][i];
            d[i] += v * w;
            int gm = orow + i;
            if (cok && gm < M) {
                if (f == 0) x1A1[(size_t)gm * OD + cc] = v;
                else x1A2[(size_t)gm * PBS + cc] = __float2bfloat16(v);
            }
        }
    }
#pragma unroll
    for (int msk = 1; msk < 16; msk <<= 1)
#pragma unroll
        for (int i = 0; i < 4; i++) d[i] += __shfl_xor(d[i], msk);
    if (l16 == 0)
#pragma unroll
        for (int i = 0; i < 4; i++) {
            int gm = orow + i;
            if (gm < M) {
                if (f == 0) s1[gm] = d[i];
                else *(float*)((char*)x1A2 + (size_t)gm * (PBS * 2) + 400) = d[i];
            }
        }
}

// -------- generic MFMA GEMM (small R-sized matmuls); cs/co = C col-stride --
#define KPAD 48
template<bool BTr, typename AT, typename CT>
__global__ __launch_bounds__(256)
void gemm_mfma_k(const AT* __restrict__ A, int lda, const float* __restrict__ ascale,
                 const float* __restrict__ B, int ldb, int colOff,
                 CT* __restrict__ C, int ldc, int cs, int co,
                 int M, int Nc, int K)
{
    __shared__ __align__(16) __hip_bfloat16 As[64][KPAD];
    __shared__ __align__(16) __hip_bfloat16 Bs[64][KPAD];
    int tid  = threadIdx.x;
    int wave = tid >> 6, lane = tid & 63;
    int quad = lane >> 4, l16 = lane & 15;
    int n0 = blockIdx.x * 64, m0 = blockIdx.y * 64;
    f32x4 acc[4];
#pragma unroll
    for (int t = 0; t < 4; t++) acc[t] = (f32x4){0.f, 0.f, 0.f, 0.f};

    for (int k0 = 0; k0 < K; k0 += 32) {
        {
            int m = tid >> 2, kc = (tid & 3) * 8;
            int gm = m0 + m;
            float scale = (ascale && gm < M) ? ascale[gm] : 1.f;
#pragma unroll
            for (int j = 0; j < 8; j++) {
                int gk = k0 + kc + j;
                float v = 0.f;
                if (gm < M && gk < K) v = toF(A[(size_t)gm * lda + gk]) * scale;
                As[m][kc + j] = __float2bfloat16(v);
            }
        }
        if (BTr) {
            int n = tid >> 2, kc = (tid & 3) * 8;
            int gn = n0 + n;
#pragma unroll
            for (int j = 0; j < 8; j++) {
                int gk = k0 + kc + j;
                float v = 0.f;
                if (gn < Nc && gk < K) v = B[(size_t)gn * ldb + colOff + gk];
                Bs[n][kc + j] = __float2bfloat16(v);
            }
        } else {
            int n = tid & 63, kq = tid >> 6;
            int gn = n0 + n;
#pragma unroll
            for (int j = 0; j < 8; j++) {
                int gk = k0 + kq * 8 + j;
                float v = 0.f;
                if (gn < Nc && gk < K) v = B[(size_t)gk * ldb + gn];
                Bs[n][kq * 8 + j] = __float2bfloat16(v);
            }
        }
        __syncthreads();
        short8 a = *(const short8*)&As[wave * 16 + l16][quad * 8];
#pragma unroll
        for (int t = 0; t < 4; t++) {
            short8 b = *(const short8*)&Bs[t * 16 + l16][quad * 8];
            acc[t] = __builtin_amdgcn_mfma_f32_16x16x32_bf16(a, b, acc[t], 0, 0, 0);
        }
        __syncthreads();
    }
#pragma unroll
    for (int t = 0; t < 4; t++) {
        int gn = n0 + t * 16 + l16;
        if (gn >= Nc) continue;
#pragma unroll
        for (int i = 0; i < 4; i++) {
            int gm = m0 + wave * 16 + quad * 4 + i;
            if (gm < M) storeC(acc[t][i], &C[(size_t)gm * ldc + (size_t)gn * cs + co]);
        }
    }
}

// -------- row-dot (srel); ks = k-stride in mat, os/oo = output stride ------
template<typename T>
__global__ __launch_bounds__(256)
void rowdot_k(const T* __restrict__ mat, int ld, int coff, int ks,
              const float* __restrict__ vec,
              float* __restrict__ outp, int os, int oo, int M, int Dd)
{
    int wave = (blockIdx.x * blockDim.x + threadIdx.x) >> 6;
    int lane = threadIdx.x & 63;
    if (wave >= M) return;
    float s = 0.f;
    for (int k = lane; k < Dd; k += 64)
        s += toF(mat[(size_t)wave * ld + coff + (size_t)k * ks]) * vec[k];
    for (int o = 32; o > 0; o >>= 1) s += __shfl_down(s, o);
    if (lane == 0) outp[wave * os + oo] = s;
}

// -------- CSR build --------
__device__ inline void decode_edge(const int* __restrict__ el, int E,
                                   const int* __restrict__ etype,
                                   const int* __restrict__ tin, int e,
                                   int& dst, int& src, int& r1, int& r2)
{
    if (e < E) { dst = el[e]; src = el[E + e]; r1 = etype[e]; r2 = -1; }
    else {
        int j = e - E;
        dst = tin[j * 4 + 3]; src = tin[j * 4 + 0];
        r1 = tin[j * 4 + 1];  r2 = tin[j * 4 + 2];
    }
}

__global__ void hist_k(const int* __restrict__ el, int E, const int* __restrict__ etype,
                       const int* __restrict__ tin, int Etot, int* __restrict__ cnt)
{
    int e = blockIdx.x * blockDim.x + threadIdx.x;
    if (e >= Etot) return;
    int dst, src, r1, r2; decode_edge(el, E, etype, tin, e, dst, src, r1, r2);
    atomicAdd(&cnt[dst], 1);
}

__global__ __launch_bounds__(1024)
void scan1_k(const int* __restrict__ cnt, int* __restrict__ start,
             int* __restrict__ aux, int n)
{
    __shared__ int tmp[1024];
    int i = blockIdx.x * 1024 + threadIdx.x;
    int v = (i < n) ? cnt[i] : 0;
    tmp[threadIdx.x] = v;
    __syncthreads();
    for (int o = 1; o < 1024; o <<= 1) {
        int t = (threadIdx.x >= (unsigned)o) ? tmp[threadIdx.x - o] : 0;
        __syncthreads();
        tmp[threadIdx.x] += t;
        __syncthreads();
    }
    if (i < n) start[i] = tmp[threadIdx.x] - v;
    if (threadIdx.x == 1023) aux[blockIdx.x] = tmp[1023];
}

__global__ void scan2_k(int* __restrict__ aux, int nb)
{
    if (threadIdx.x == 0 && blockIdx.x == 0) {
        int s = 0;
        for (int i = 0; i < nb; i++) { int v = aux[i]; aux[i] = s; s += v; }
    }
}

__global__ __launch_bounds__(1024)
void scan3_k(int* __restrict__ start, const int* __restrict__ aux, int n, int Etot)
{
    int i = blockIdx.x * 1024 + threadIdx.x;
    if (i < n) start[i] += aux[blockIdx.x];
    if (i == 0) start[n] = Etot;
}

// csr entry: .x = src, .y = r1 | (r2s<<16), r2s==0xFFFF means "no r2"
__global__ void fill_k(const int* __restrict__ el, int E, const int* __restrict__ etype,
                       const int* __restrict__ tin, int Etot,
                       const int* __restrict__ start, int* __restrict__ fill,
                       int2* __restrict__ csr)
{
    int e = blockIdx.x * blockDim.x + threadIdx.x;
    if (e >= Etot) return;
    int dst, src, r1, r2; decode_edge(el, E, etype, tin, e, dst, src, r1, r2);
    int p = start[dst] + atomicAdd(&fill[dst], 1);
    unsigned r2s = (r2 >= 0) ? (unsigned)r2 : 0xFFFFu;
    csr[p] = make_int2(src, (int)((r2s << 16) | (unsigned)r1));
}

// -------- layer-1 gather: wave/dst, 2-feature/lane (lane<50), wide loads ---
__global__ __launch_bounds__(256)
void gather_l1_k(const int* __restrict__ start, const int2* __restrict__ csr,
                 const float* __restrict__ s1,        // [2][N] dst-side
                 const float* __restrict__ srel2,     // [R][2]
                 const __hip_bfloat16* __restrict__ pB,   // [N][PBS] interleaved
                 const float* __restrict__ rpf2,      // [R][100][2]
                 __hip_bfloat16* __restrict__ x1, int N)  // [N][KP]
{
    int n = (blockIdx.x * blockDim.x + threadIdx.x) >> 6;
    int lane = threadIdx.x & 63;
    if (n >= N) return;
    int b0 = __builtin_amdgcn_readfirstlane(start[n]);
    int b1 = __builtin_amdgcn_readfirstlane(start[n + 1]);
    float s1h0 = s1[n], s1h1 = s1[N + n];
    float rsl0 = 0.f, rsl1 = 0.f;        // per-lane partial rowsums
    bool fok = lane < 50;
    int f2 = fok ? 2 * lane : 0;         // features f2, f2+1
    float4 acc = {0.f, 0.f, 0.f, 0.f};   // (f2,h0) (f2,h1) (f2+1,h0) (f2+1,h1)

    for (int c0 = b0; c0 < b1; c0 += 64) {
        int cnt = min(64, b1 - c0);
        // ---- phase A: lane-parallel per-edge scalars
        float w0 = 0.f, w1 = 0.f;
        int srcL = 0, eyL = 0;
        if (lane < cnt) {
            int2 eg = csr[c0 + lane];
            srcL = eg.x; eyL = eg.y;
            int r1 = eyL & 0xFFFF;
            unsigned r2u = (unsigned)eyL >> 16;
            float2 sA = *(const float2*)((const char*)pB + (size_t)(unsigned)srcL * (PBS * 2) + 400);
            float2 sr = *(const float2*)(srel2 + r1 * 2);
            float z0 = s1h0 + sA.x + sr.x;
            float z1 = s1h1 + sA.y + sr.y;
            if (r2u != 0xFFFFu) {
                float2 sr2v = *(const float2*)(srel2 + r2u * 2);
                z0 += sr2v.x; z1 += sr2v.y;
            }
            w0 = expf(-(z0 > 0.f ? z0 : 0.2f * z0));
            w1 = expf(-(z1 > 0.f ? z1 : 0.2f * z1));
            rsl0 += w0; rsl1 += w1;
        }
        // ---- phase B: 4-edge batches; wide loads batched up front
        for (int e0 = 0; e0 < cnt; e0 += 4) {
            int ec = min(4, cnt - e0);
            uint2 pw[4]; float4 q1v[4]; unsigned r2s[4];
#pragma unroll
            for (int u = 0; u < 4; u++) {
                if (u < ec) {
                    int s = __builtin_amdgcn_readlane(srcL, e0 + u);
                    int ey = __builtin_amdgcn_readlane(eyL, e0 + u);
                    int r1 = ey & 0xFFFF;
                    r2s[u] = (unsigned)ey >> 16;
                    pw[u] = *(const uint2*)(pB + (size_t)(unsigned)s * PBS + 2 * f2);
                    q1v[u] = *(const float4*)(rpf2 + (unsigned)r1 * 200 + 2 * f2);
                }
            }
#pragma unroll
            for (int u = 0; u < 4; u++) {
                if (u < ec) {
                    float we0 = readlaneF(w0, e0 + u);
                    float we1 = readlaneF(w1, e0 + u);
                    float v00 = bfLo(pw[u].x) + q1v[u].x;   // f2,   h0
                    float v01 = bfHi(pw[u].x) + q1v[u].y;   // f2,   h1
                    float v10 = bfLo(pw[u].y) + q1v[u].z;   // f2+1, h0
                    float v11 = bfHi(pw[u].y) + q1v[u].w;   // f2+1, h1
                    if (r2s[u] != 0xFFFFu) {
                        float4 q2v = *(const float4*)(rpf2 + r2s[u] * 200 + 2 * f2);
                        v00 += q2v.x; v01 += q2v.y; v10 += q2v.z; v11 += q2v.w;
                    }
                    acc.x += we0 * v00; acc.y += we1 * v01;
                    acc.z += we0 * v10; acc.w += we1 * v11;
                }
            }
        }
    }

    // wave-reduce rowsums (butterfly -> all lanes)
#pragma unroll
    for (int o = 1; o < 64; o <<= 1) {
        rsl0 += __shfl_xor(rsl0, o);
        rsl1 += __shfl_xor(rsl1, o);
    }
    float i0 = rsl0 > 0.f ? 1.f / rsl0 : 0.f;
    float i1 = rsl1 > 0.f ? 1.f / rsl1 : 0.f;
    if (!fok) return;
    __hip_bfloat16* xr = x1 + (size_t)n * KP;
    // h0 pair (cols f2, f2+1)
    unsigned u0 = *(const unsigned*)(xr + f2);
    float h0a = rsl0 > 0.f ? bfLo(u0) + acc.x * i0 : 0.f;
    float h0b = rsl0 > 0.f ? bfHi(u0) + acc.z * i0 : 0.f;
    h0a = h0a > 0.f ? h0a : expf(h0a) - 1.f;
    h0b = h0b > 0.f ? h0b : expf(h0b) - 1.f;
    *(unsigned*)(xr + f2) = packbf(h0a, h0b);
    // h1 pair (cols 100+f2, 100+f2+1)
    unsigned u1 = *(const unsigned*)(xr + 100 + f2);
    float h1a = rsl1 > 0.f ? bfLo(u1) + acc.y * i1 : 0.f;
    float h1b = rsl1 > 0.f ? bfHi(u1) + acc.w * i1 : 0.f;
    h1a = h1a > 0.f ? h1a : expf(h1a) - 1.f;
    h1b = h1b > 0.f ? h1b : expf(h1b) - 1.f;
    *(unsigned*)(xr + 100 + f2) = packbf(h1a, h1b);
}

// -------- layer-2 gather: wave/dst, 4-col/lane (lane<50), wide loads -------
__global__ __launch_bounds__(256)
void gather_l2_k(const int* __restrict__ start, const int2* __restrict__ csr,
                 const float* __restrict__ s1,
                 const float* __restrict__ srel,          // [R]
                 const __hip_bfloat16* __restrict__ x1A2, // [N][PBS]: feats+s2+entW
                 const float* __restrict__ rpf,           // [R][200]
                 const float* __restrict__ maskf,
                 float* __restrict__ outent, int N)       // [N][200], holds x1A1
{
    int n = (blockIdx.x * blockDim.x + threadIdx.x) >> 6;
    int lane = threadIdx.x & 63;
    if (n >= N) return;
    int b0 = __builtin_amdgcn_readfirstlane(start[n]);
    int b1 = __builtin_amdgcn_readfirstlane(start[n + 1]);
    float s1n = s1[n];
    float rsl = 0.f;
    bool fok = lane < 50;
    int c4 = fok ? 4 * lane : 0;         // cols c4 .. c4+3
    float4 acc = {0.f, 0.f, 0.f, 0.f};

    for (int c0 = b0; c0 < b1; c0 += 64) {
        int cnt = min(64, b1 - c0);
        // ---- phase A: lane-parallel per-edge scalars
        float w = 0.f;
        int srcL = 0, eyL = 0;
        if (lane < cnt) {
            int2 eg = csr[c0 + lane];
            srcL = eg.x; eyL = eg.y;
            int r1 = eyL & 0xFFFF;
            unsigned r2u = (unsigned)eyL >> 16;
            float s2v = *(const float*)((const char*)x1A2 + (size_t)(unsigned)srcL * (PBS * 2) + 400);
            float sr = srel[r1];
            if (r2u != 0xFFFFu) sr += srel[r2u];
            float z = s1n + s2v + sr;
            w = expf(-(z > 0.f ? z : 0.2f * z));
            rsl += w;
        }
        // ---- phase B: 4-edge batches; wide loads batched up front
        for (int e0 = 0; e0 < cnt; e0 += 4) {
            int ec = min(4, cnt - e0);
            uint2 xw[4]; float4 q1v[4]; unsigned r2s[4];
#pragma unroll
            for (int u = 0; u < 4; u++) {
                if (u < ec) {
                    int s = __builtin_amdgcn_readlane(srcL, e0 + u);
                    int ey = __builtin_amdgcn_readlane(eyL, e0 + u);
                    int r1 = ey & 0xFFFF;
                    r2s[u] = (unsigned)ey >> 16;
                    xw[u] = *(const uint2*)(x1A2 + (size_t)(unsigned)s * PBS + c4);
                    q1v[u] = *(const float4*)(rpf + (unsigned)r1 * 200 + c4);
                }
            }
#pragma unroll
            for (int u = 0; u < 4; u++) {
                if (u < ec) {
                    float we = readlaneF(w, e0 + u);
                    float v0 = bfLo(xw[u].x) + q1v[u].x;
                    float v1 = bfHi(xw[u].x) + q1v[u].y;
                    float v2 = bfLo(xw[u].y) + q1v[u].z;
                    float v3 = bfHi(xw[u].y) + q1v[u].w;
                    if (r2s[u] != 0xFFFFu) {
                        float4 q2v = *(const float4*)(rpf + r2s[u] * 200 + c4);
                        v0 += q2v.x; v1 += q2v.y; v2 += q2v.z; v3 += q2v.w;
                    }
                    acc.x += we * v0; acc.y += we * v1;
                    acc.z += we * v2; acc.w += we * v3;
                }
            }
        }
    }

#pragma unroll
    for (int o = 1; o < 64; o <<= 1) rsl += __shfl_xor(rsl, o);
    float inv = rsl > 0.f ? 1.f / rsl : 0.f;
    float mk = maskf[n];
    float* orow = outent + (size_t)n * 200;
    const __hip_bfloat16* ew = x1A2 + (size_t)n * PBS + 224;  // own dst row's entW

    float v0 = 0.f, v1 = 0.f, v2 = 0.f, v3 = 0.f;
    if (fok) {
        float4 o4 = *(const float4*)(orow + c4);
        uint2 eb = *(const uint2*)(ew + c4);
        float h0 = rsl > 0.f ? o4.x + acc.x * inv : 0.f;
        float h1 = rsl > 0.f ? o4.y + acc.y * inv : 0.f;
        float h2 = rsl > 0.f ? o4.z + acc.z * inv : 0.f;
        float h3 = rsl > 0.f ? o4.w + acc.w * inv : 0.f;
        v0 = mk * (h0 > 0.f ? h0 : expf(h0) - 1.f) + bfLo(eb.x);
        v1 = mk * (h1 > 0.f ? h1 : expf(h1) - 1.f) + bfHi(eb.x);
        v2 = mk * (h2 > 0.f ? h2 : expf(h2) - 1.f) + bfLo(eb.y);
        v3 = mk * (h3 > 0.f ? h3 : expf(h3) - 1.f) + bfHi(eb.y);
    }
    float ssq = v0 * v0 + v1 * v1 + v2 * v2 + v3 * v3;
#pragma unroll
    for (int o = 1; o < 64; o <<= 1) ssq += __shfl_xor(ssq, o);
    float sc = 1.f / fmaxf(sqrtf(ssq), 1e-12f);
    if (fok) {
        float4 r; r.x = v0 * sc; r.y = v1 * sc; r.z = v2 * sc; r.w = v3 * sc;
        *(float4*)(orow + c4) = r;
    }
}

__global__ void scatter_mask_k(const int* __restrict__ batch, int NB,
                               float* __restrict__ masko)
{
    int i = blockIdx.x * blockDim.x + threadIdx.x;
    if (i >= NB) return;
    masko[batch[i]] = 1.0f;
}

extern "C" void kernel_launch(void* const* d_in, const int* in_sizes, int n_in,
                              void* d_out, int out_size, void* d_ws, size_t ws_size,
                              hipStream_t stream)
{
    const float* ent      = (const float*)d_in[0];
    const float* rel      = (const float*)d_in[1];
    const float* W_ent    = (const float*)d_in[2];
    const float* W_gat    = (const float*)d_in[3];
    const float* a_heads  = (const float*)d_in[4];
    const float* a2_heads = (const float*)d_in[5];
    const float* a_out    = (const float*)d_in[6];
    const float* a2_out   = (const float*)d_in[7];
    const int* batch = (const int*)d_in[8];
    const int* el    = (const int*)d_in[9];
    const int* etype = (const int*)d_in[10];
    const int* tin   = (const int*)d_in[11];

    const int N   = in_sizes[0] / DD;   // 50000
    const int R   = in_sizes[1] / DD;   // 500
    const int NB  = in_sizes[8];        // 20000
    const int E   = in_sizes[9] / 2;    // 150000
    const int ENH = in_sizes[11] / 4;   // 30000
    const int Etot = E + ENH;

    // ---- workspace (~92 MB) ----
    char* ws = (char*)d_ws;
    size_t off = 0;
    auto take = [&](size_t bytes) { size_t o = off; off += (bytes + 255) & ~(size_t)255; return o; };
    size_t o_R1   = take((size_t)N * KP * 2);     // x1 bf16 [N][KP]
    size_t o_R2   = take((size_t)N * PBS * 2);    // pB/x1A2 [N][PBS] + s2 + entW
    size_t o_eb   = take((size_t)N * KP * 2);     // entb bf16 [N][KP] (normalized)
    size_t o_rpf  = take((size_t)2 * R * 100 * 4);// rpf2 [R][100][2] / layer2 rpf [R][200]
    size_t o_bt1  = take((size_t)416 * KP * 2);   // l1 panel
    size_t o_btf  = take((size_t)208 * KP * 2);   // W_ent panel: ADJACENT to bt1
    size_t o_bt2  = take((size_t)416 * KP * 2);
    size_t o_s1   = take((size_t)2 * N * 4);      // aliased by cnt during CSR build
    size_t o_srel = take((size_t)2 * R * 4);      // [R][2] layer1 / [R] layer2
    size_t o_csr  = take((size_t)Etot * 8);
    size_t o_str  = take((size_t)(N + 1) * 4);
    size_t o_aux  = take((size_t)64 * 4);

    __hip_bfloat16* x1   = (__hip_bfloat16*)(ws + o_R1);
    __hip_bfloat16* pB   = (__hip_bfloat16*)(ws + o_R2);
    __hip_bfloat16* x1A2 = (__hip_bfloat16*)(ws + o_R2);
    __hip_bfloat16* entb = (__hip_bfloat16*)(ws + o_eb);
    float* rpf2   = (float*)(ws + o_rpf);
    __hip_bfloat16* bt1 = (__hip_bfloat16*)(ws + o_bt1);  // [624][KP] combined w/ btf
    __hip_bfloat16* btf = (__hip_bfloat16*)(ws + o_btf);
    __hip_bfloat16* bt2 = (__hip_bfloat16*)(ws + o_bt2);
    float* s1     = (float*)(ws + o_s1);
    float* srel2  = (float*)(ws + o_srel);
    int2*  csr    = (int2*)(ws + o_csr);
    int*   cnt    = (int*)(ws + o_s1);   // CSR-build scratch; dead before l1_both_k writes s1
    int*   startA = (int*)(ws + o_str);
    int*   aux    = (int*)(ws + o_aux);

    float* out       = (float*)d_out;
    float* out_ent   = out;                                     // [N,200]
    float* out_rel_o = out + (size_t)N * OD;                    // [500,200]
    float* out_mask  = out + (size_t)N * OD + (size_t)R * OD;   // [N]

    const int nblk2 = cdiv(N, 128);
    const int nbScan = cdiv(N, 1024);

    // A. prep: fused norm->bf16, B panels (bt1[416]+btf[208] contiguous)
    rownorm_bf16_k<<<cdiv(N, 4), 256, 0, stream>>>(ent, entb, N);
    prep_bt_l1<<<416, 256, 0, stream>>>(a_heads, bt1);
    prep_bt_fin<<<208, 256, 0, stream>>>(W_ent, btf);
    prep_bt_l2<<<416, 256, 0, stream>>>(a_out, bt2);
    gemm_mfma_k<false, float, float><<<dim3(cdiv(OD, 64), cdiv(R, 64)), 256, 0, stream>>>(
        rel, DD, nullptr, W_gat, OD, 0, out_rel_o, OD, 1, 0, R, OD, DD);

    // A2. CSR build (dst-grouped edge lists)
    hipMemsetAsync(cnt, 0, (size_t)N * 4, stream);
    hist_k<<<cdiv(Etot, 256), 256, 0, stream>>>(el, E, etype, tin, Etot, cnt);
    scan1_k<<<nbScan, 1024, 0, stream>>>(cnt, startA, aux, N);
    scan2_k<<<1, 64, 0, stream>>>(aux, nbScan);
    scan3_k<<<nbScan, 1024, 0, stream>>>(startA, aux, N, Etot);
    hipMemsetAsync(cnt, 0, (size_t)N * 4, stream);
    fill_k<<<cdiv(Etot, 256), 256, 0, stream>>>(el, E, etype, tin, Etot, startA, cnt, csr);

    // B. layer-1 projections: flavors y0=x1+s1, y1=pB+s2, y2=entW
    l1_both_k<<<dim3(nblk2, 3), 512, 0, stream>>>(entb, bt1, a2_heads, x1, pB, s1, N);
    for (int h = 0; h < 2; h++) {
        const float* ah  = a_heads + (size_t)h * NHID * 600;
        const float* a2h = a2_heads + (size_t)h * NHID;
        gemm_mfma_k<true, float, float><<<dim3(cdiv(NHID, 64), cdiv(R, 64)), 256, 0, stream>>>(
            rel, DD, nullptr, ah, 600, 400, rpf2, 200, 2, h, R, NHID, DD);
        rowdot_k<float><<<cdiv(R, 4), 256, 0, stream>>>(
            rpf2, 200, h, 2, a2h, srel2, 2, h, R, NHID);
    }
    gather_l1_k<<<cdiv(N, 4), 256, 0, stream>>>(
        startA, csr, s1, srel2, pB, rpf2, x1, N);
    // pB feats dead; R2 rows become x1A2 (entW at shorts 224.. survives).

    // C. layer-2 projection (flavors y0=x1A1+s1, y1=x1A2+s2) + rel side
    l2_proj_k<<<dim3(nblk2, 2), 512, 0, stream>>>(x1, bt2, a2_out, out_ent, x1A2, s1, N);
    gemm_mfma_k<true, float, float><<<dim3(cdiv(OD, 64), cdiv(R, 64)), 256, 0, stream>>>(
        out_rel_o, OD, nullptr, a_out, 600, 400, rpf2, OD, 1, 0, R, OD, OD);
    rowdot_k<float><<<cdiv(R, 4), 256, 0, stream>>>(rpf2, OD, 0, 1, a2_out, srel2, 1, 0, R, OD);

    // D. mask; layer-2 gather (fused combine + entW + l2norm -> final out_ent)
    hipMemsetAsync(out_mask, 0, (size_t)N * 4, stream);
    scatter_mask_k<<<cdiv(NB, 256), 256, 0, stream>>>(batch, NB, out_mask);
    gather_l2_k<<<cdiv(N, 4), 256, 0, stream>>>(
        startA, csr, s1, srel2, x1A2, rpf2, out_mask, out_ent, N);
}